// Round 5
// baseline (669.443 us; speedup 1.0000x reference)
//
#include <hip/hip_runtime.h>
#include <hip/hip_fp16.h>
#include <math.h>

// GAT encoder: N=10000, E=160000 (+N self loops), H=8 heads, C=128, D=1024.
// CSR-by-dst built once; logits dst-sorted. Intermediates fp16; dense GEMMs on
// matrix cores. Aggregation is head-partitioned (blockIdx%8 == head) so each
// XCD's L2 holds one 2.5 MB head-panel of H16 resident.

#define THREADS 256

typedef _Float16 f16x8 __attribute__((ext_vector_type(8)));
typedef float f32x4 __attribute__((ext_vector_type(4)));

struct __align__(8) Half4 { __half2 a, b; };

__device__ __forceinline__ float gelu_exact(float x) {
  return 0.5f * x * (1.0f + erff(x * 0.70710678118654752f));
}

__device__ __forceinline__ float4 h4_to_f4(float2 raw) {
  __half2 h01 = *(__half2*)&raw.x;
  __half2 h23 = *(__half2*)&raw.y;
  float2 f01 = __half22float2(h01);
  float2 f23 = __half22float2(h23);
  return make_float4(f01.x, f01.y, f23.x, f23.y);
}

// ---------------- CSR build ----------------

__global__ void hist_kernel(const int* __restrict__ ei, int E, int ET, int* __restrict__ counts) {
  int e = blockIdx.x * THREADS + threadIdx.x;
  if (e >= ET) return;
  int d = (e < E) ? ei[E + e] : (e - E);
  atomicAdd(&counts[d], 1);
}

__global__ __launch_bounds__(1024) void scan_kernel(const int* __restrict__ counts,
                                                    int* __restrict__ offsets,
                                                    int* __restrict__ cursor, int n) {
  __shared__ int sums[1024];
  int t = threadIdx.x;
  int per = (n + 1023) >> 10;
  int start = t * per; if (start > n) start = n;
  int end = start + per; if (end > n) end = n;
  int local = 0;
  for (int i = start; i < end; ++i) local += counts[i];
  sums[t] = local;
  __syncthreads();
  for (int off = 1; off < 1024; off <<= 1) {
    int add = (t >= off) ? sums[t - off] : 0;
    __syncthreads();
    sums[t] += add;
    __syncthreads();
  }
  int run = (t == 0) ? 0 : sums[t - 1];
  for (int i = start; i < end; ++i) {
    offsets[i] = run; cursor[i] = run; run += counts[i];
  }
  if (t == 1023) offsets[n] = run;
}

__global__ void scatter_kernel(const int* __restrict__ ei, int E, int ET,
                               int* __restrict__ cursor,
                               int* __restrict__ srcs, int* __restrict__ dsts) {
  int e = blockIdx.x * THREADS + threadIdx.x;
  if (e >= ET) return;
  int s = (e < E) ? ei[e] : (e - E);
  int d = (e < E) ? ei[E + e] : (e - E);
  int pos = atomicAdd(&cursor[d], 1);
  srcs[pos] = s;
  dsts[pos] = d;
}

// ---------------- weight transpose + fp16 convert: W[K][Ncol] -> Wt[Ncol][K] ----------------

__global__ void wconv_kernel(const float* __restrict__ in, __half* __restrict__ out,
                             int K, int Ncol, int total) {
  int idx = blockIdx.x * THREADS + threadIdx.x;
  if (idx >= total) return;
  int c = idx / K, k = idx - c * K;
  out[idx] = __float2half_rn(in[(size_t)k * Ncol + c]);
}

// ---------------- layer 1 feature transform (K=4), fp16 out ----------------

__global__ void feat1_kernel(const float* __restrict__ x, const float* __restrict__ w,
                             __half* __restrict__ out, int total) {
  int idx = blockIdx.x * THREADS + threadIdx.x;
  if (idx >= total) return;
  int n = idx >> 10, d = idx & 1023;
  float4 xv = *(const float4*)&x[n * 4];
  float v = xv.x * w[d] + xv.y * w[1024 + d] + xv.z * w[2048 + d] + xv.w * w[3072 + d];
  out[idx] = __float2half_rn(v);
}

// ---------------- MFMA GEMM: P16[N,128] @ W[128,1024] -> A16[N,1024] fp16 ----------------
// First operand = Wt cols, second = P16 rows => acc[i] = C[r0+m][c0+quad*4+i],
// giving packed 8B stores per lane.

__global__ __launch_bounds__(256) void gemm128_mfma(const __half* __restrict__ P16,
                                                    const __half* __restrict__ Wt,
                                                    __half* __restrict__ A16) {
  int wave = threadIdx.x >> 6, lane = threadIdx.x & 63;
  int r0 = blockIdx.y * 16;
  int c0 = blockIdx.x * 64 + wave * 16;
  int m = lane & 15, quad = lane >> 4;
  const __half* pa = Wt + (size_t)(c0 + m) * 128 + quad * 8;
  const __half* pb = P16 + (size_t)(r0 + m) * 128 + quad * 8;
  f32x4 acc = {0.f, 0.f, 0.f, 0.f};
#pragma unroll
  for (int k = 0; k < 128; k += 32) {
    f16x8 a = *(const f16x8*)(pa + k);
    f16x8 b = *(const f16x8*)(pb + k);
    acc = __builtin_amdgcn_mfma_f32_16x16x32_f16(a, b, acc, 0, 0, 0);
  }
  Half4 p;
  p.a = __floats2half2_rn(acc[0], acc[1]);
  p.b = __floats2half2_rn(acc[2], acc[3]);
  *(Half4*)&A16[(size_t)(r0 + m) * 1024 + c0 + quad * 4] = p;
}

// ---------------- per-node head scores (fp16 in) ----------------

__global__ __launch_bounds__(256) void scores_kernel(const __half* __restrict__ H16,
                                                     const float* __restrict__ as,
                                                     const float* __restrict__ ad,
                                                     float* __restrict__ ssrc,
                                                     float* __restrict__ sdst, int N) {
  int n = blockIdx.x;
  int t = threadIdx.x;
  int head = t >> 5, lane = t & 31;
  float4 h4 = h4_to_f4(*(const float2*)&H16[(size_t)n * 1024 + head * 128 + lane * 4]);
  float4 a4 = *(const float4*)&as[head * 128 + lane * 4];
  float4 d4 = *(const float4*)&ad[head * 128 + lane * 4];
  float s1 = h4.x * a4.x + h4.y * a4.y + h4.z * a4.z + h4.w * a4.w;
  float s2 = h4.x * d4.x + h4.y * d4.y + h4.z * d4.z + h4.w * d4.w;
  for (int off = 16; off; off >>= 1) {
    s1 += __shfl_down(s1, off, 32);
    s2 += __shfl_down(s2, off, 32);
  }
  if (lane == 0) { ssrc[n * 8 + head] = s1; sdst[n * 8 + head] = s2; }
}

// ---------------- per-edge logits (pos-parallel, coalesced writes) ----------------

__global__ void elog_kernel(const int* __restrict__ srcs, const int* __restrict__ dsts,
                            const float* __restrict__ ssrc, const float* __restrict__ sdst,
                            float* __restrict__ elog, int ET) {
  int pos = blockIdx.x * THREADS + threadIdx.x;
  if (pos >= ET) return;
  int s = srcs[pos], d = dsts[pos];
  float4 sa = *(const float4*)&ssrc[s * 8];
  float4 sb = *(const float4*)&ssrc[s * 8 + 4];
  float4 da = *(const float4*)&sdst[d * 8];
  float4 db = *(const float4*)&sdst[d * 8 + 4];
  float v[8] = {sa.x + da.x, sa.y + da.y, sa.z + da.z, sa.w + da.w,
                sb.x + db.x, sb.y + db.y, sb.z + db.z, sb.w + db.w};
#pragma unroll
  for (int h = 0; h < 8; ++h) v[h] = (v[h] > 0.f) ? v[h] : 0.2f * v[h];
  float4* out = (float4*)&elog[(size_t)pos * 8];
  out[0] = make_float4(v[0], v[1], v[2], v[3]);
  out[1] = make_float4(v[4], v[5], v[6], v[7]);
}

// ---------------- softmax stats + normalized alpha per (edge, head) ----------------

__global__ __launch_bounds__(256) void msz_alpha_kernel(const float* __restrict__ elog,
                                                        const int* __restrict__ offsets,
                                                        float* __restrict__ alpha, int N) {
  int n = blockIdx.x;
  int t = threadIdx.x;
  int head = t >> 5, lane = t & 31;
  int start = offsets[n];
  int deg = offsets[n + 1] - start;
  __shared__ float sm[8], sz[8];
  float m = -1e30f, s = 0.f;
  for (int i = lane; i < deg; i += 32) {
    float v = elog[(size_t)(start + i) * 8 + head];
    if (v > m) { s = s * __expf(m - v) + 1.f; }
    else { s += __expf(v - m); }
    m = fmaxf(m, v);
  }
  for (int off = 16; off; off >>= 1) {
    float m2 = __shfl_down(m, off, 32);
    float s2 = __shfl_down(s, off, 32);
    float M = fmaxf(m, m2);
    s = s * __expf(m - M) + s2 * __expf(m2 - M);
    m = M;
  }
  if (lane == 0) { sm[head] = m; sz[head] = 1.f / s; }
  __syncthreads();
  for (int j = t; j < deg * 8; j += 256) {
    int e = j >> 3, h = j & 7;
    alpha[(size_t)(start + e) * 8 + h] =
        __expf(elog[(size_t)(start + e) * 8 + h] - sm[h]) * sz[h];
  }
}

// ---------------- head-panel aggregation + bias + GELU ----------------
// blockIdx.x = dst*8 + head; head = blockIdx.x & 7 -> XCD-pinned panel (heuristic).
// 256 threads: t&31 = channel group (4 ch, 8 B), t>>5 = edge sublane (8-way MLP).

__global__ __launch_bounds__(256) void aggh_kernel(const __half* __restrict__ H16,
                                                   const float* __restrict__ alpha,
                                                   const int* __restrict__ offsets,
                                                   const int* __restrict__ srcs,
                                                   const float* __restrict__ bias,
                                                   __half* __restrict__ G) {
  int bid = blockIdx.x;
  int head = bid & 7, n = bid >> 3;
  int t = threadIdx.x;
  int cg = t & 31, es = t >> 5;
  int start = offsets[n];
  int deg = offsets[n + 1] - start;
  int base = head * 128 + cg * 4;
  float4 acc = make_float4(0.f, 0.f, 0.f, 0.f);
  for (int i = es; i < deg; i += 8) {
    int sp = srcs[start + i];
    float a = alpha[(size_t)(start + i) * 8 + head];
    float4 f = h4_to_f4(*(const float2*)&H16[(size_t)sp * 1024 + base]);
    acc.x += a * f.x; acc.y += a * f.y; acc.z += a * f.z; acc.w += a * f.w;
  }
  __shared__ float4 part[8][32];
  part[es][cg] = acc;
  __syncthreads();
  if (t < 32) {
    float4 o = part[0][t];
#pragma unroll
    for (int e = 1; e < 8; ++e) {
      float4 p = part[e][t];
      o.x += p.x; o.y += p.y; o.z += p.z; o.w += p.w;
    }
    float4 b4 = *(const float4*)&bias[head * 128 + t * 4];
    float o0 = gelu_exact(o.x + b4.x);
    float o1 = gelu_exact(o.y + b4.y);
    float o2 = gelu_exact(o.z + b4.z);
    float o3 = gelu_exact(o.w + b4.w);
    Half4 p;
    p.a = __floats2half2_rn(o0, o1);
    p.b = __floats2half2_rn(o2, o3);
    *(Half4*)&G[(size_t)n * 1024 + head * 128 + t * 4] = p;
  }
}

// ---------------- MFMA proj: G[N,1024] @ W[1024,128] + bias -> C[N,128] ----------------
// Operand order as gemm128_mfma: acc[i] = C[r0+m][c0+quad*4+i]; packed stores.

template <typename OutT>
__global__ __launch_bounds__(256) void proj_mfma(const __half* __restrict__ G,
                                                 const __half* __restrict__ Wt,
                                                 const float* __restrict__ bias,
                                                 OutT* __restrict__ C) {
  int wave = threadIdx.x >> 6, lane = threadIdx.x & 63;
  int r0 = blockIdx.y * 16;
  int c0 = blockIdx.x * 64 + wave * 16;
  int m = lane & 15, quad = lane >> 4;
  const __half* pa = Wt + (size_t)(c0 + m) * 1024 + quad * 8;
  const __half* pb = G + (size_t)(r0 + m) * 1024 + quad * 8;
  f32x4 acc = {0.f, 0.f, 0.f, 0.f};
#pragma unroll 8
  for (int k = 0; k < 1024; k += 32) {
    f16x8 a = *(const f16x8*)(pa + k);
    f16x8 b = *(const f16x8*)(pb + k);
    acc = __builtin_amdgcn_mfma_f32_16x16x32_f16(a, b, acc, 0, 0, 0);
  }
  float4 b4 = *(const float4*)&bias[c0 + quad * 4];
  float v0 = acc[0] + b4.x, v1 = acc[1] + b4.y, v2 = acc[2] + b4.z, v3 = acc[3] + b4.w;
  if constexpr (__is_same(OutT, __half)) {
    Half4 p;
    p.a = __floats2half2_rn(v0, v1);
    p.b = __floats2half2_rn(v2, v3);
    *(Half4*)&C[(size_t)(r0 + m) * 128 + c0 + quad * 4] = p;
  } else {
    *(float4*)&C[(size_t)(r0 + m) * 128 + c0 + quad * 4] = make_float4(v0, v1, v2, v3);
  }
}

// ---------------- orchestration ----------------

extern "C" void kernel_launch(void* const* d_in, const int* in_sizes, int n_in,
                              void* d_out, int out_size, void* d_ws, size_t ws_size,
                              hipStream_t stream) {
  const float* x   = (const float*)d_in[0];
  const int*   ei  = (const int*)d_in[1];
  const float* w1  = (const float*)d_in[2];
  const float* as1 = (const float*)d_in[3];
  const float* ad1 = (const float*)d_in[4];
  const float* b1  = (const float*)d_in[5];
  const float* w2  = (const float*)d_in[6];
  const float* as2 = (const float*)d_in[7];
  const float* ad2 = (const float*)d_in[8];
  const float* b2  = (const float*)d_in[9];
  const float* w3  = (const float*)d_in[10];
  const float* as3 = (const float*)d_in[11];
  const float* ad3 = (const float*)d_in[12];
  const float* b3  = (const float*)d_in[13];
  const float* rw1 = (const float*)d_in[14];
  const float* rb1 = (const float*)d_in[15];
  const float* rw2 = (const float*)d_in[16];
  const float* rb2 = (const float*)d_in[17];
  const float* lw  = (const float*)d_in[18];
  const float* lb  = (const float*)d_in[19];

  int N = in_sizes[0] / 4;
  int E = in_sizes[1] / 2;
  int ET = E + N;
  (void)ws_size;

  char* wsb = (char*)d_ws;
  size_t off = 0;
  auto alloc = [&](size_t bytes) -> void* {
    void* p = wsb + off;
    off += (bytes + 255) & ~(size_t)255;
    return p;
  };
  __half* A16 = (__half*)alloc((size_t)N * 1024 * 2);  // h (pre-attention features)
  __half* G   = (__half*)alloc((size_t)N * 1024 * 2);  // gelu(GAT output)
  __half* P16 = (__half*)alloc((size_t)N * 128 * 2);   // projected features
  __half* wt2 = (__half*)alloc((size_t)1024 * 128 * 2);
  __half* wt3 = (__half*)alloc((size_t)1024 * 128 * 2);
  __half* rwt1 = (__half*)alloc((size_t)128 * 1024 * 2);
  __half* rwt2 = (__half*)alloc((size_t)128 * 1024 * 2);
  __half* lwt  = (__half*)alloc((size_t)128 * 1024 * 2);
  float* ssrc = (float*)alloc((size_t)N * 8 * 4);
  float* sdst = (float*)alloc((size_t)N * 8 * 4);
  float* elog = (float*)alloc((size_t)ET * 8 * 4);
  float* alpha = (float*)alloc((size_t)ET * 8 * 4);
  int* counts  = (int*)alloc((size_t)N * 4);
  int* offsets = (int*)alloc((size_t)(N + 1) * 4);
  int* cursor  = (int*)alloc((size_t)N * 4);
  int* srcs    = (int*)alloc((size_t)ET * 4);
  int* dsts    = (int*)alloc((size_t)ET * 4);

  dim3 blk(THREADS);
  int WT = 128 * 1024;
  dim3 gW((WT + THREADS - 1) / THREADS);

  // CSR build + weight conversions (graph/weights identical for all layers)
  hipMemsetAsync(counts, 0, (size_t)N * 4, stream);
  hist_kernel<<<dim3((ET + THREADS - 1) / THREADS), blk, 0, stream>>>(ei, E, ET, counts);
  wconv_kernel<<<gW, blk, 0, stream>>>(w2, wt2, 128, 1024, WT);
  wconv_kernel<<<gW, blk, 0, stream>>>(w3, wt3, 128, 1024, WT);
  wconv_kernel<<<gW, blk, 0, stream>>>(rw1, rwt1, 1024, 128, WT);
  wconv_kernel<<<gW, blk, 0, stream>>>(rw2, rwt2, 1024, 128, WT);
  wconv_kernel<<<gW, blk, 0, stream>>>(lw, lwt, 1024, 128, WT);
  scan_kernel<<<dim3(1), dim3(1024), 0, stream>>>(counts, offsets, cursor, N);
  scatter_kernel<<<dim3((ET + THREADS - 1) / THREADS), blk, 0, stream>>>(ei, E, ET, cursor, srcs, dsts);

  dim3 gEdge((ET + THREADS - 1) / THREADS);
  dim3 gNode(N);
  dim3 gAgg(N * 8);
  dim3 gGemm(16, N / 16);
  dim3 gProj(2, N / 16);

  // ---- layer 1 ----
  feat1_kernel<<<dim3((N * 1024 + THREADS - 1) / THREADS), blk, 0, stream>>>(x, w1, A16, N * 1024);
  scores_kernel<<<gNode, blk, 0, stream>>>(A16, as1, ad1, ssrc, sdst, N);
  elog_kernel<<<gEdge, blk, 0, stream>>>(srcs, dsts, ssrc, sdst, elog, ET);
  msz_alpha_kernel<<<gNode, blk, 0, stream>>>(elog, offsets, alpha, N);
  aggh_kernel<<<gAgg, blk, 0, stream>>>(A16, alpha, offsets, srcs, b1, G);
  proj_mfma<__half><<<gProj, blk, 0, stream>>>(G, rwt1, rb1, P16);

  // ---- layer 2 ----
  gemm128_mfma<<<gGemm, blk, 0, stream>>>(P16, wt2, A16);
  scores_kernel<<<gNode, blk, 0, stream>>>(A16, as2, ad2, ssrc, sdst, N);
  elog_kernel<<<gEdge, blk, 0, stream>>>(srcs, dsts, ssrc, sdst, elog, ET);
  msz_alpha_kernel<<<gNode, blk, 0, stream>>>(elog, offsets, alpha, N);
  aggh_kernel<<<gAgg, blk, 0, stream>>>(A16, alpha, offsets, srcs, b2, G);
  proj_mfma<__half><<<gProj, blk, 0, stream>>>(G, rwt2, rb2, P16);

  // ---- layer 3 ----
  gemm128_mfma<<<gGemm, blk, 0, stream>>>(P16, wt3, A16);
  scores_kernel<<<gNode, blk, 0, stream>>>(A16, as3, ad3, ssrc, sdst, N);
  elog_kernel<<<gEdge, blk, 0, stream>>>(srcs, dsts, ssrc, sdst, elog, ET);
  msz_alpha_kernel<<<gNode, blk, 0, stream>>>(elog, offsets, alpha, N);
  aggh_kernel<<<gAgg, blk, 0, stream>>>(A16, alpha, offsets, srcs, b3, G);
  proj_mfma<float><<<gProj, blk, 0, stream>>>(G, lwt, lb, (float*)d_out);
}

// Round 6
// 545.139 us; speedup vs baseline: 1.2280x; 1.2280x over previous
//
#include <hip/hip_runtime.h>
#include <hip/hip_fp16.h>
#include <math.h>

// GAT encoder: N=10000, E=160000 (+N self loops), H=8 heads, C=128, D=1024.
// CSR-by-dst built once; logits dst-sorted. Intermediates fp16; dense GEMMs on
// matrix cores. Aggregation head-partitioned (blockIdx%8 == head -> XCD-pinned
// 2.5 MB L2 panel), one wave per dst node (no barriers).

#define THREADS 256

typedef _Float16 f16x8 __attribute__((ext_vector_type(8)));
typedef float f32x4 __attribute__((ext_vector_type(4)));

struct __align__(8) Half4 { __half2 a, b; };

__device__ __forceinline__ float gelu_exact(float x) {
  return 0.5f * x * (1.0f + erff(x * 0.70710678118654752f));
}

__device__ __forceinline__ float4 h4_to_f4(float2 raw) {
  __half2 h01 = *(__half2*)&raw.x;
  __half2 h23 = *(__half2*)&raw.y;
  float2 f01 = __half22float2(h01);
  float2 f23 = __half22float2(h23);
  return make_float4(f01.x, f01.y, f23.x, f23.y);
}

// ---------------- CSR build ----------------

__global__ void hist_kernel(const int* __restrict__ ei, int E, int ET, int* __restrict__ counts) {
  int e = blockIdx.x * THREADS + threadIdx.x;
  if (e >= ET) return;
  int d = (e < E) ? ei[E + e] : (e - E);
  atomicAdd(&counts[d], 1);
}

__global__ __launch_bounds__(1024) void scan_kernel(const int* __restrict__ counts,
                                                    int* __restrict__ offsets,
                                                    int* __restrict__ cursor, int n) {
  __shared__ int sums[1024];
  int t = threadIdx.x;
  int per = (n + 1023) >> 10;
  int start = t * per; if (start > n) start = n;
  int end = start + per; if (end > n) end = n;
  int local = 0;
  for (int i = start; i < end; ++i) local += counts[i];
  sums[t] = local;
  __syncthreads();
  for (int off = 1; off < 1024; off <<= 1) {
    int add = (t >= off) ? sums[t - off] : 0;
    __syncthreads();
    sums[t] += add;
    __syncthreads();
  }
  int run = (t == 0) ? 0 : sums[t - 1];
  for (int i = start; i < end; ++i) {
    offsets[i] = run; cursor[i] = run; run += counts[i];
  }
  if (t == 1023) offsets[n] = run;
}

__global__ void scatter_kernel(const int* __restrict__ ei, int E, int ET,
                               int* __restrict__ cursor,
                               int* __restrict__ srcs, int* __restrict__ dsts) {
  int e = blockIdx.x * THREADS + threadIdx.x;
  if (e >= ET) return;
  int s = (e < E) ? ei[e] : (e - E);
  int d = (e < E) ? ei[E + e] : (e - E);
  int pos = atomicAdd(&cursor[d], 1);
  srcs[pos] = s;
  dsts[pos] = d;
}

// ---------------- weight transpose + fp16 convert (LDS-tiled) ----------------
// in: [K][Ncol] fp32 -> out: [Ncol][K] fp16. K, Ncol multiples of 32.

__global__ __launch_bounds__(256) void wconv_kernel(const float* __restrict__ in,
                                                    __half* __restrict__ out,
                                                    int K, int Ncol) {
  __shared__ float tile[32][33];
  int kb = blockIdx.y * 32, cb = blockIdx.x * 32;
  int t = threadIdx.x;
  int tc = t & 31, tr = t >> 5;
#pragma unroll
  for (int r = tr; r < 32; r += 8)
    tile[r][tc] = in[(size_t)(kb + r) * Ncol + cb + tc];
  __syncthreads();
#pragma unroll
  for (int r = tr; r < 32; r += 8)
    out[(size_t)(cb + r) * K + kb + tc] = __float2half_rn(tile[tc][r]);
}

// ---------------- layer 1 feature transform (K=4), fp16 out ----------------

__global__ void feat1_kernel(const float* __restrict__ x, const float* __restrict__ w,
                             __half* __restrict__ out, int total) {
  int idx = blockIdx.x * THREADS + threadIdx.x;
  if (idx >= total) return;
  int n = idx >> 10, d = idx & 1023;
  float4 xv = *(const float4*)&x[n * 4];
  float v = xv.x * w[d] + xv.y * w[1024 + d] + xv.z * w[2048 + d] + xv.w * w[3072 + d];
  out[idx] = __float2half_rn(v);
}

// ---------------- MFMA GEMM: P16[N,128] @ W[128,1024] -> A16[N,1024] fp16 ----------------

__global__ __launch_bounds__(256) void gemm128_mfma(const __half* __restrict__ P16,
                                                    const __half* __restrict__ Wt,
                                                    __half* __restrict__ A16) {
  int wave = threadIdx.x >> 6, lane = threadIdx.x & 63;
  int r0 = blockIdx.y * 16;
  int c0 = blockIdx.x * 64 + wave * 16;
  int m = lane & 15, quad = lane >> 4;
  const __half* pa = Wt + (size_t)(c0 + m) * 128 + quad * 8;
  const __half* pb = P16 + (size_t)(r0 + m) * 128 + quad * 8;
  f32x4 acc = {0.f, 0.f, 0.f, 0.f};
#pragma unroll
  for (int k = 0; k < 128; k += 32) {
    f16x8 a = *(const f16x8*)(pa + k);
    f16x8 b = *(const f16x8*)(pb + k);
    acc = __builtin_amdgcn_mfma_f32_16x16x32_f16(a, b, acc, 0, 0, 0);
  }
  Half4 p;
  p.a = __floats2half2_rn(acc[0], acc[1]);
  p.b = __floats2half2_rn(acc[2], acc[3]);
  *(Half4*)&A16[(size_t)(r0 + m) * 1024 + c0 + quad * 4] = p;
}

// ---------------- per-node head scores (8 nodes per block) ----------------

__global__ __launch_bounds__(256) void scores_kernel(const __half* __restrict__ H16,
                                                     const float* __restrict__ as,
                                                     const float* __restrict__ ad,
                                                     float* __restrict__ ssrc,
                                                     float* __restrict__ sdst, int N) {
  int t = threadIdx.x;
  int head = t >> 5, lane = t & 31;
  float4 a4 = *(const float4*)&as[head * 128 + lane * 4];
  float4 d4 = *(const float4*)&ad[head * 128 + lane * 4];
  int n0 = blockIdx.x * 8;
#pragma unroll
  for (int j = 0; j < 8; ++j) {
    int n = n0 + j;
    float4 h4 = h4_to_f4(*(const float2*)&H16[(size_t)n * 1024 + head * 128 + lane * 4]);
    float s1 = h4.x * a4.x + h4.y * a4.y + h4.z * a4.z + h4.w * a4.w;
    float s2 = h4.x * d4.x + h4.y * d4.y + h4.z * d4.z + h4.w * d4.w;
    for (int off = 16; off; off >>= 1) {
      s1 += __shfl_down(s1, off, 32);
      s2 += __shfl_down(s2, off, 32);
    }
    if (lane == 0) { ssrc[n * 8 + head] = s1; sdst[n * 8 + head] = s2; }
  }
}

// ---------------- per-edge logits (pos-parallel, coalesced writes) ----------------

__global__ void elog_kernel(const int* __restrict__ srcs, const int* __restrict__ dsts,
                            const float* __restrict__ ssrc, const float* __restrict__ sdst,
                            float* __restrict__ elog, int ET) {
  int pos = blockIdx.x * THREADS + threadIdx.x;
  if (pos >= ET) return;
  int s = srcs[pos], d = dsts[pos];
  float4 sa = *(const float4*)&ssrc[s * 8];
  float4 sb = *(const float4*)&ssrc[s * 8 + 4];
  float4 da = *(const float4*)&sdst[d * 8];
  float4 db = *(const float4*)&sdst[d * 8 + 4];
  float v[8] = {sa.x + da.x, sa.y + da.y, sa.z + da.z, sa.w + da.w,
                sb.x + db.x, sb.y + db.y, sb.z + db.z, sb.w + db.w};
#pragma unroll
  for (int h = 0; h < 8; ++h) v[h] = (v[h] > 0.f) ? v[h] : 0.2f * v[h];
  float4* out = (float4*)&elog[(size_t)pos * 8];
  out[0] = make_float4(v[0], v[1], v[2], v[3]);
  out[1] = make_float4(v[4], v[5], v[6], v[7]);
}

// ---------------- softmax stats + normalized alpha (one wave per node) ----------------
// lane&7 = head, lane>>3 = edge sublane. Coalesced elog/alpha access; no barriers.

__global__ __launch_bounds__(256) void msz_alpha_kernel(const float* __restrict__ elog,
                                                        const int* __restrict__ offsets,
                                                        float* __restrict__ alpha, int N) {
  int wave = threadIdx.x >> 6, lane = threadIdx.x & 63;
  int n = blockIdx.x * 4 + wave;
  int head = lane & 7, es = lane >> 3;
  int start = offsets[n];
  int deg = offsets[n + 1] - start;
  float m = -1e30f, s = 0.f;
  for (int i = es; i < deg; i += 8) {
    float v = elog[(size_t)(start + i) * 8 + head];
    if (v > m) { s = s * __expf(m - v) + 1.f; m = v; }
    else s += __expf(v - m);
  }
#pragma unroll
  for (int mask = 8; mask <= 32; mask <<= 1) {
    float m2 = __shfl_xor(m, mask);
    float s2 = __shfl_xor(s, mask);
    float M = fmaxf(m, m2);
    s = s * __expf(m - M) + s2 * __expf(m2 - M);
    m = M;
  }
  float zinv = 1.f / s;
  // j = lane + 64k => j&7 == head, so per-lane (m, zinv) match the element's head
  for (int j = lane; j < deg * 8; j += 64)
    alpha[(size_t)start * 8 + j] = __expf(elog[(size_t)start * 8 + j] - m) * zinv;
}

// ---------------- head-panel aggregation + bias + GELU (one wave per node) ----------------
// bid&7 = head (XCD-pinned panel); 4 waves/block, wave = one dst node.
// lane: cg = lane&31 (4 channels, 8 B), es = lane>>5 (2 edge sublanes).

__global__ __launch_bounds__(256) void aggh_kernel(const __half* __restrict__ H16,
                                                   const float* __restrict__ alpha,
                                                   const int* __restrict__ offsets,
                                                   const int* __restrict__ srcs,
                                                   const float* __restrict__ bias,
                                                   __half* __restrict__ G) {
  int bid = blockIdx.x;
  int head = bid & 7, ng = bid >> 3;
  int wave = threadIdx.x >> 6, lane = threadIdx.x & 63;
  int n = ng * 4 + wave;
  int cg = lane & 31, es = lane >> 5;
  int start = offsets[n];
  int deg = offsets[n + 1] - start;
  int base = head * 128 + cg * 4;
  float4 acc = make_float4(0.f, 0.f, 0.f, 0.f);
  int i = es;
  for (; i + 6 < deg; i += 8) {
    int sp[4]; float a[4]; float2 raw[4];
#pragma unroll
    for (int u = 0; u < 4; ++u) {
      sp[u] = srcs[start + i + 2 * u];
      a[u] = alpha[(size_t)(start + i + 2 * u) * 8 + head];
    }
#pragma unroll
    for (int u = 0; u < 4; ++u)
      raw[u] = *(const float2*)&H16[(size_t)sp[u] * 1024 + base];
#pragma unroll
    for (int u = 0; u < 4; ++u) {
      float4 f = h4_to_f4(raw[u]);
      acc.x += a[u] * f.x; acc.y += a[u] * f.y;
      acc.z += a[u] * f.z; acc.w += a[u] * f.w;
    }
  }
  for (; i < deg; i += 2) {
    int sp = srcs[start + i];
    float a = alpha[(size_t)(start + i) * 8 + head];
    float4 f = h4_to_f4(*(const float2*)&H16[(size_t)sp * 1024 + base]);
    acc.x += a * f.x; acc.y += a * f.y; acc.z += a * f.z; acc.w += a * f.w;
  }
  acc.x += __shfl_xor(acc.x, 32);
  acc.y += __shfl_xor(acc.y, 32);
  acc.z += __shfl_xor(acc.z, 32);
  acc.w += __shfl_xor(acc.w, 32);
  if (es == 0) {
    float4 b4 = *(const float4*)&bias[base];
    float o0 = gelu_exact(acc.x + b4.x);
    float o1 = gelu_exact(acc.y + b4.y);
    float o2 = gelu_exact(acc.z + b4.z);
    float o3 = gelu_exact(acc.w + b4.w);
    Half4 p;
    p.a = __floats2half2_rn(o0, o1);
    p.b = __floats2half2_rn(o2, o3);
    *(Half4*)&G[(size_t)n * 1024 + base] = p;
  }
}

// ---------------- MFMA proj: G[N,1024] @ W[1024,128] + bias -> C[N,128] ----------------

template <typename OutT>
__global__ __launch_bounds__(256) void proj_mfma(const __half* __restrict__ G,
                                                 const __half* __restrict__ Wt,
                                                 const float* __restrict__ bias,
                                                 OutT* __restrict__ C) {
  int wave = threadIdx.x >> 6, lane = threadIdx.x & 63;
  int r0 = blockIdx.y * 16;
  int c0 = blockIdx.x * 64 + wave * 16;
  int m = lane & 15, quad = lane >> 4;
  const __half* pa = Wt + (size_t)(c0 + m) * 1024 + quad * 8;
  const __half* pb = G + (size_t)(r0 + m) * 1024 + quad * 8;
  f32x4 acc = {0.f, 0.f, 0.f, 0.f};
#pragma unroll 8
  for (int k = 0; k < 1024; k += 32) {
    f16x8 a = *(const f16x8*)(pa + k);
    f16x8 b = *(const f16x8*)(pb + k);
    acc = __builtin_amdgcn_mfma_f32_16x16x32_f16(a, b, acc, 0, 0, 0);
  }
  float4 b4 = *(const float4*)&bias[c0 + quad * 4];
  float v0 = acc[0] + b4.x, v1 = acc[1] + b4.y, v2 = acc[2] + b4.z, v3 = acc[3] + b4.w;
  if constexpr (__is_same(OutT, __half)) {
    Half4 p;
    p.a = __floats2half2_rn(v0, v1);
    p.b = __floats2half2_rn(v2, v3);
    *(Half4*)&C[(size_t)(r0 + m) * 128 + c0 + quad * 4] = p;
  } else {
    *(float4*)&C[(size_t)(r0 + m) * 128 + c0 + quad * 4] = make_float4(v0, v1, v2, v3);
  }
}

// ---------------- orchestration ----------------

extern "C" void kernel_launch(void* const* d_in, const int* in_sizes, int n_in,
                              void* d_out, int out_size, void* d_ws, size_t ws_size,
                              hipStream_t stream) {
  const float* x   = (const float*)d_in[0];
  const int*   ei  = (const int*)d_in[1];
  const float* w1  = (const float*)d_in[2];
  const float* as1 = (const float*)d_in[3];
  const float* ad1 = (const float*)d_in[4];
  const float* b1  = (const float*)d_in[5];
  const float* w2  = (const float*)d_in[6];
  const float* as2 = (const float*)d_in[7];
  const float* ad2 = (const float*)d_in[8];
  const float* b2  = (const float*)d_in[9];
  const float* w3  = (const float*)d_in[10];
  const float* as3 = (const float*)d_in[11];
  const float* ad3 = (const float*)d_in[12];
  const float* b3  = (const float*)d_in[13];
  const float* rw1 = (const float*)d_in[14];
  const float* rb1 = (const float*)d_in[15];
  const float* rw2 = (const float*)d_in[16];
  const float* rb2 = (const float*)d_in[17];
  const float* lw  = (const float*)d_in[18];
  const float* lb  = (const float*)d_in[19];

  int N = in_sizes[0] / 4;
  int E = in_sizes[1] / 2;
  int ET = E + N;
  (void)ws_size;

  char* wsb = (char*)d_ws;
  size_t off = 0;
  auto alloc = [&](size_t bytes) -> void* {
    void* p = wsb + off;
    off += (bytes + 255) & ~(size_t)255;
    return p;
  };
  __half* A16 = (__half*)alloc((size_t)N * 1024 * 2);  // h (pre-attention features)
  __half* G   = (__half*)alloc((size_t)N * 1024 * 2);  // gelu(GAT output)
  __half* P16 = (__half*)alloc((size_t)N * 128 * 2);   // projected features
  __half* wt2 = (__half*)alloc((size_t)1024 * 128 * 2);
  __half* wt3 = (__half*)alloc((size_t)1024 * 128 * 2);
  __half* rwt1 = (__half*)alloc((size_t)128 * 1024 * 2);
  __half* rwt2 = (__half*)alloc((size_t)128 * 1024 * 2);
  __half* lwt  = (__half*)alloc((size_t)128 * 1024 * 2);
  float* ssrc = (float*)alloc((size_t)N * 8 * 4);
  float* sdst = (float*)alloc((size_t)N * 8 * 4);
  float* elog = (float*)alloc((size_t)ET * 8 * 4);
  float* alpha = (float*)alloc((size_t)ET * 8 * 4);
  int* counts  = (int*)alloc((size_t)N * 4);
  int* offsets = (int*)alloc((size_t)(N + 1) * 4);
  int* cursor  = (int*)alloc((size_t)N * 4);
  int* srcs    = (int*)alloc((size_t)ET * 4);
  int* dsts    = (int*)alloc((size_t)ET * 4);

  dim3 blk(THREADS);

  // CSR build + weight conversions (graph/weights identical for all layers)
  hipMemsetAsync(counts, 0, (size_t)N * 4, stream);
  hist_kernel<<<dim3((ET + THREADS - 1) / THREADS), blk, 0, stream>>>(ei, E, ET, counts);
  wconv_kernel<<<dim3(1024 / 32, 128 / 32), blk, 0, stream>>>(w2, wt2, 128, 1024);
  wconv_kernel<<<dim3(1024 / 32, 128 / 32), blk, 0, stream>>>(w3, wt3, 128, 1024);
  wconv_kernel<<<dim3(128 / 32, 1024 / 32), blk, 0, stream>>>(rw1, rwt1, 1024, 128);
  wconv_kernel<<<dim3(128 / 32, 1024 / 32), blk, 0, stream>>>(rw2, rwt2, 1024, 128);
  wconv_kernel<<<dim3(128 / 32, 1024 / 32), blk, 0, stream>>>(lw, lwt, 1024, 128);
  scan_kernel<<<dim3(1), dim3(1024), 0, stream>>>(counts, offsets, cursor, N);
  scatter_kernel<<<dim3((ET + THREADS - 1) / THREADS), blk, 0, stream>>>(ei, E, ET, cursor, srcs, dsts);

  dim3 gEdge((ET + THREADS - 1) / THREADS);
  dim3 gScores(N / 8);
  dim3 gMsz(N / 4);
  dim3 gAgg(N * 2);          // (N/4 node-groups) x 8 heads; bid&7 = head
  dim3 gGemm(16, N / 16);
  dim3 gProj(2, N / 16);

  // ---- layer 1 ----
  feat1_kernel<<<dim3((N * 1024 + THREADS - 1) / THREADS), blk, 0, stream>>>(x, w1, A16, N * 1024);
  scores_kernel<<<gScores, blk, 0, stream>>>(A16, as1, ad1, ssrc, sdst, N);
  elog_kernel<<<gEdge, blk, 0, stream>>>(srcs, dsts, ssrc, sdst, elog, ET);
  msz_alpha_kernel<<<gMsz, blk, 0, stream>>>(elog, offsets, alpha, N);
  aggh_kernel<<<gAgg, blk, 0, stream>>>(A16, alpha, offsets, srcs, b1, G);
  proj_mfma<__half><<<gProj, blk, 0, stream>>>(G, rwt1, rb1, P16);

  // ---- layer 2 ----
  gemm128_mfma<<<gGemm, blk, 0, stream>>>(P16, wt2, A16);
  scores_kernel<<<gScores, blk, 0, stream>>>(A16, as2, ad2, ssrc, sdst, N);
  elog_kernel<<<gEdge, blk, 0, stream>>>(srcs, dsts, ssrc, sdst, elog, ET);
  msz_alpha_kernel<<<gMsz, blk, 0, stream>>>(elog, offsets, alpha, N);
  aggh_kernel<<<gAgg, blk, 0, stream>>>(A16, alpha, offsets, srcs, b2, G);
  proj_mfma<__half><<<gProj, blk, 0, stream>>>(G, rwt2, rb2, P16);

  // ---- layer 3 ----
  gemm128_mfma<<<gGemm, blk, 0, stream>>>(P16, wt3, A16);
  scores_kernel<<<gScores, blk, 0, stream>>>(A16, as3, ad3, ssrc, sdst, N);
  elog_kernel<<<gEdge, blk, 0, stream>>>(srcs, dsts, ssrc, sdst, elog, ET);
  msz_alpha_kernel<<<gMsz, blk, 0, stream>>>(elog, offsets, alpha, N);
  aggh_kernel<<<gAgg, blk, 0, stream>>>(A16, alpha, offsets, srcs, b3, G);
  proj_mfma<float><<<gProj, blk, 0, stream>>>(G, lwt, lb, (float*)d_out);
}

// Round 7
// 541.221 us; speedup vs baseline: 1.2369x; 1.0072x over previous
//
#include <hip/hip_runtime.h>
#include <hip/hip_fp16.h>
#include <math.h>

// GAT encoder: N=10000, E=160000 (+N self loops), H=8 heads, C=128, D=1024.
// CSR-by-dst built once. Intermediates fp16; dense GEMMs on matrix cores with
// fused score epilogues (atomicAdd into zeroed ssrc/sdst). Attention softmax
// fused into one wave-per-node kernel. Aggregation head-partitioned
// (blockIdx%8 == head -> XCD-pinned 2.5 MB L2 panel), one wave per dst node.

#define THREADS 256

typedef _Float16 f16x8 __attribute__((ext_vector_type(8)));
typedef float f32x4 __attribute__((ext_vector_type(4)));

struct __align__(8) Half4 { __half2 a, b; };

__device__ __forceinline__ float gelu_exact(float x) {
  return 0.5f * x * (1.0f + erff(x * 0.70710678118654752f));
}

__device__ __forceinline__ float4 h4_to_f4(float2 raw) {
  __half2 h01 = *(__half2*)&raw.x;
  __half2 h23 = *(__half2*)&raw.y;
  float2 f01 = __half22float2(h01);
  float2 f23 = __half22float2(h23);
  return make_float4(f01.x, f01.y, f23.x, f23.y);
}

// ---------------- CSR build ----------------

__global__ void hist_kernel(const int* __restrict__ ei, int E, int ET, int* __restrict__ counts) {
  int e = blockIdx.x * THREADS + threadIdx.x;
  if (e >= ET) return;
  int d = (e < E) ? ei[E + e] : (e - E);
  atomicAdd(&counts[d], 1);
}

__global__ __launch_bounds__(1024) void scan_kernel(const int* __restrict__ counts,
                                                    int* __restrict__ offsets,
                                                    int* __restrict__ cursor, int n) {
  __shared__ int sums[1024];
  int t = threadIdx.x;
  int per = (n + 1023) >> 10;
  int start = t * per; if (start > n) start = n;
  int end = start + per; if (end > n) end = n;
  int local = 0;
  for (int i = start; i < end; ++i) local += counts[i];
  sums[t] = local;
  __syncthreads();
  for (int off = 1; off < 1024; off <<= 1) {
    int add = (t >= off) ? sums[t - off] : 0;
    __syncthreads();
    sums[t] += add;
    __syncthreads();
  }
  int run = (t == 0) ? 0 : sums[t - 1];
  for (int i = start; i < end; ++i) {
    offsets[i] = run; cursor[i] = run; run += counts[i];
  }
  if (t == 1023) offsets[n] = run;
}

__global__ void scatter_kernel(const int* __restrict__ ei, int E, int ET,
                               int* __restrict__ cursor, int* __restrict__ srcs) {
  int e = blockIdx.x * THREADS + threadIdx.x;
  if (e >= ET) return;
  int s = (e < E) ? ei[e] : (e - E);
  int d = (e < E) ? ei[E + e] : (e - E);
  int pos = atomicAdd(&cursor[d], 1);
  srcs[pos] = s;
}

// ---------------- batched weight transpose + fp16 convert ----------------
// z selects matrix. in [K][Ncol] fp32 -> out [Ncol][K] fp16.

__global__ __launch_bounds__(256) void wconv_all_kernel(
    const float* __restrict__ w2, const float* __restrict__ w3,
    const float* __restrict__ rw1, const float* __restrict__ rw2,
    const float* __restrict__ lw,
    __half* __restrict__ wt2, __half* __restrict__ wt3,
    __half* __restrict__ rwt1, __half* __restrict__ rwt2,
    __half* __restrict__ lwt) {
  const float* in; __half* out; int K, Ncol;
  switch (blockIdx.z) {
    case 0: in = w2;  out = wt2;  K = 128;  Ncol = 1024; break;
    case 1: in = w3;  out = wt3;  K = 128;  Ncol = 1024; break;
    case 2: in = rw1; out = rwt1; K = 1024; Ncol = 128;  break;
    case 3: in = rw2; out = rwt2; K = 1024; Ncol = 128;  break;
    default: in = lw; out = lwt;  K = 1024; Ncol = 128;  break;
  }
  int kb = blockIdx.y * 32, cb = blockIdx.x * 32;
  if (kb >= K || cb >= Ncol) return;
  __shared__ float tile[32][33];
  int t = threadIdx.x;
  int tc = t & 31, tr = t >> 5;
#pragma unroll
  for (int r = tr; r < 32; r += 8)
    tile[r][tc] = in[(size_t)(kb + r) * Ncol + cb + tc];
  __syncthreads();
#pragma unroll
  for (int r = tr; r < 32; r += 8)
    out[(size_t)(cb + r) * K + kb + tc] = __float2half_rn(tile[tc][r]);
}

// ---------------- layer 1 feature transform (K=4) + fused scores ----------------
// Block covers 256 consecutive d of one node. Wave = 64 d within one head.

__global__ void feat1_kernel(const float* __restrict__ x, const float* __restrict__ w,
                             const float* __restrict__ as, const float* __restrict__ ad,
                             __half* __restrict__ out,
                             float* __restrict__ ssrc, float* __restrict__ sdst, int total) {
  int idx = blockIdx.x * THREADS + threadIdx.x;
  if (idx >= total) return;
  int n = idx >> 10, d = idx & 1023;
  float4 xv = *(const float4*)&x[n * 4];
  float v = xv.x * w[d] + xv.y * w[1024 + d] + xv.z * w[2048 + d] + xv.w * w[3072 + d];
  out[idx] = __float2half_rn(v);
  float p1 = v * as[d];
  float p2 = v * ad[d];
#pragma unroll
  for (int mask = 1; mask <= 32; mask <<= 1) {
    p1 += __shfl_xor(p1, mask);
    p2 += __shfl_xor(p2, mask);
  }
  if ((d & 63) == 0) {
    int head = d >> 7;
    atomicAdd(&ssrc[n * 8 + head], p1);
    atomicAdd(&sdst[n * 8 + head], p2);
  }
}

// ---------------- MFMA GEMM: P16[N,128] @ W[128,1024] -> A16 fp16 + fused scores ----------------
// acc[i] = C[r0+m][c0+quad*4+i]; head = c0>>7 constant per wave; as/ad flat [1024].

__global__ __launch_bounds__(256) void gemm128_mfma(const __half* __restrict__ P16,
                                                    const __half* __restrict__ Wt,
                                                    const float* __restrict__ as,
                                                    const float* __restrict__ ad,
                                                    __half* __restrict__ A16,
                                                    float* __restrict__ ssrc,
                                                    float* __restrict__ sdst) {
  int wave = threadIdx.x >> 6, lane = threadIdx.x & 63;
  int r0 = blockIdx.y * 16;
  int c0 = blockIdx.x * 64 + wave * 16;
  int m = lane & 15, quad = lane >> 4;
  const __half* pa = Wt + (size_t)(c0 + m) * 128 + quad * 8;
  const __half* pb = P16 + (size_t)(r0 + m) * 128 + quad * 8;
  f32x4 acc = {0.f, 0.f, 0.f, 0.f};
#pragma unroll
  for (int k = 0; k < 128; k += 32) {
    f16x8 a = *(const f16x8*)(pa + k);
    f16x8 b = *(const f16x8*)(pb + k);
    acc = __builtin_amdgcn_mfma_f32_16x16x32_f16(a, b, acc, 0, 0, 0);
  }
  Half4 p;
  p.a = __floats2half2_rn(acc[0], acc[1]);
  p.b = __floats2half2_rn(acc[2], acc[3]);
  *(Half4*)&A16[(size_t)(r0 + m) * 1024 + c0 + quad * 4] = p;
  // fused score partials
  float4 asv = *(const float4*)&as[c0 + quad * 4];
  float4 adv = *(const float4*)&ad[c0 + quad * 4];
  float s1 = acc[0] * asv.x + acc[1] * asv.y + acc[2] * asv.z + acc[3] * asv.w;
  float s2 = acc[0] * adv.x + acc[1] * adv.y + acc[2] * adv.z + acc[3] * adv.w;
  s1 += __shfl_xor(s1, 16); s1 += __shfl_xor(s1, 32);
  s2 += __shfl_xor(s2, 16); s2 += __shfl_xor(s2, 32);
  if (quad == 0) {
    int head = c0 >> 7;
    atomicAdd(&ssrc[(r0 + m) * 8 + head], s1);
    atomicAdd(&sdst[(r0 + m) * 8 + head], s2);
  }
}

// ---------------- attention: logits + softmax + normalized alpha (one wave per node) ----------------
// lane&7 = head, lane>>3 = edge sublane. Two passes over edges, ssrc L2/L1-hot.

__global__ __launch_bounds__(256) void attn_kernel(const int* __restrict__ srcs,
                                                   const int* __restrict__ offsets,
                                                   const float* __restrict__ ssrc,
                                                   const float* __restrict__ sdst,
                                                   float* __restrict__ alpha) {
  int wave = threadIdx.x >> 6, lane = threadIdx.x & 63;
  int n = blockIdx.x * 4 + wave;
  int head = lane & 7, es = lane >> 3;
  int start = offsets[n];
  int deg = offsets[n + 1] - start;
  float sd = sdst[n * 8 + head];
  float m = -1e30f, s = 0.f;
  for (int i = es; i < deg; i += 8) {
    int sp = srcs[start + i];
    float v = ssrc[sp * 8 + head] + sd;
    v = (v > 0.f) ? v : 0.2f * v;
    if (v > m) { s = s * __expf(m - v) + 1.f; m = v; }
    else s += __expf(v - m);
  }
#pragma unroll
  for (int mask = 8; mask <= 32; mask <<= 1) {
    float m2 = __shfl_xor(m, mask);
    float s2 = __shfl_xor(s, mask);
    float M = fmaxf(m, m2);
    s = s * __expf(m - M) + s2 * __expf(m2 - M);
    m = M;
  }
  float zinv = 1.f / s;
  for (int i = es; i < deg; i += 8) {
    int sp = srcs[start + i];
    float v = ssrc[sp * 8 + head] + sd;
    v = (v > 0.f) ? v : 0.2f * v;
    alpha[(size_t)(start + i) * 8 + head] = __expf(v - m) * zinv;
  }
}

// ---------------- head-panel aggregation + bias + GELU (one wave per node) ----------------
// bid&7 = head (XCD-pinned panel); 4 waves/block. lane: cg = lane&15 (8 ch, 16 B),
// es = lane>>4 (4 edge sublanes). Unroll-2 -> 8 edges in flight per wave.

__global__ __launch_bounds__(256) void aggh_kernel(const __half* __restrict__ H16,
                                                   const float* __restrict__ alpha,
                                                   const int* __restrict__ offsets,
                                                   const int* __restrict__ srcs,
                                                   const float* __restrict__ bias,
                                                   __half* __restrict__ G) {
  int bid = blockIdx.x;
  int head = bid & 7, ng = bid >> 3;
  int wave = threadIdx.x >> 6, lane = threadIdx.x & 63;
  int n = ng * 4 + wave;
  int cg = lane & 15, es = lane >> 4;
  int start = offsets[n];
  int deg = offsets[n + 1] - start;
  int base = head * 128 + cg * 8;
  float acc[8] = {};
  int i = es;
  for (; i + 4 < deg; i += 8) {
    int e0 = start + i, e1 = start + i + 4;
    int sp0 = srcs[e0], sp1 = srcs[e1];
    float a0 = alpha[(size_t)e0 * 8 + head];
    float a1 = alpha[(size_t)e1 * 8 + head];
    float4 r0 = *(const float4*)&H16[(size_t)sp0 * 1024 + base];
    float4 r1 = *(const float4*)&H16[(size_t)sp1 * 1024 + base];
    float4 f0 = h4_to_f4(make_float2(r0.x, r0.y));
    float4 f1 = h4_to_f4(make_float2(r0.z, r0.w));
    float4 f2 = h4_to_f4(make_float2(r1.x, r1.y));
    float4 f3 = h4_to_f4(make_float2(r1.z, r1.w));
    acc[0] += a0 * f0.x; acc[1] += a0 * f0.y; acc[2] += a0 * f0.z; acc[3] += a0 * f0.w;
    acc[4] += a0 * f1.x; acc[5] += a0 * f1.y; acc[6] += a0 * f1.z; acc[7] += a0 * f1.w;
    acc[0] += a1 * f2.x; acc[1] += a1 * f2.y; acc[2] += a1 * f2.z; acc[3] += a1 * f2.w;
    acc[4] += a1 * f3.x; acc[5] += a1 * f3.y; acc[6] += a1 * f3.z; acc[7] += a1 * f3.w;
  }
  for (; i < deg; i += 4) {
    int e0 = start + i;
    int sp0 = srcs[e0];
    float a0 = alpha[(size_t)e0 * 8 + head];
    float4 r0 = *(const float4*)&H16[(size_t)sp0 * 1024 + base];
    float4 f0 = h4_to_f4(make_float2(r0.x, r0.y));
    float4 f1 = h4_to_f4(make_float2(r0.z, r0.w));
    acc[0] += a0 * f0.x; acc[1] += a0 * f0.y; acc[2] += a0 * f0.z; acc[3] += a0 * f0.w;
    acc[4] += a0 * f1.x; acc[5] += a0 * f1.y; acc[6] += a0 * f1.z; acc[7] += a0 * f1.w;
  }
#pragma unroll
  for (int u = 0; u < 8; ++u) {
    acc[u] += __shfl_xor(acc[u], 16);
    acc[u] += __shfl_xor(acc[u], 32);
  }
  if (es == 0) {
    float4 b0 = *(const float4*)&bias[base];
    float4 b1 = *(const float4*)&bias[base + 4];
    float o[8];
    o[0] = gelu_exact(acc[0] + b0.x); o[1] = gelu_exact(acc[1] + b0.y);
    o[2] = gelu_exact(acc[2] + b0.z); o[3] = gelu_exact(acc[3] + b0.w);
    o[4] = gelu_exact(acc[4] + b1.x); o[5] = gelu_exact(acc[5] + b1.y);
    o[6] = gelu_exact(acc[6] + b1.z); o[7] = gelu_exact(acc[7] + b1.w);
    __half2 p[4];
    p[0] = __floats2half2_rn(o[0], o[1]); p[1] = __floats2half2_rn(o[2], o[3]);
    p[2] = __floats2half2_rn(o[4], o[5]); p[3] = __floats2half2_rn(o[6], o[7]);
    *(float4*)&G[(size_t)n * 1024 + base] = *(float4*)p;
  }
}

// ---------------- MFMA proj: G[N,1024] @ W[1024,128] + bias -> C[N,128] ----------------

template <typename OutT>
__global__ __launch_bounds__(256) void proj_mfma(const __half* __restrict__ G,
                                                 const __half* __restrict__ Wt,
                                                 const float* __restrict__ bias,
                                                 OutT* __restrict__ C) {
  int wave = threadIdx.x >> 6, lane = threadIdx.x & 63;
  int r0 = blockIdx.y * 16;
  int c0 = blockIdx.x * 64 + wave * 16;
  int m = lane & 15, quad = lane >> 4;
  const __half* pa = Wt + (size_t)(c0 + m) * 1024 + quad * 8;
  const __half* pb = G + (size_t)(r0 + m) * 1024 + quad * 8;
  f32x4 acc = {0.f, 0.f, 0.f, 0.f};
#pragma unroll 8
  for (int k = 0; k < 1024; k += 32) {
    f16x8 a = *(const f16x8*)(pa + k);
    f16x8 b = *(const f16x8*)(pb + k);
    acc = __builtin_amdgcn_mfma_f32_16x16x32_f16(a, b, acc, 0, 0, 0);
  }
  float4 b4 = *(const float4*)&bias[c0 + quad * 4];
  float v0 = acc[0] + b4.x, v1 = acc[1] + b4.y, v2 = acc[2] + b4.z, v3 = acc[3] + b4.w;
  if constexpr (__is_same(OutT, __half)) {
    Half4 p;
    p.a = __floats2half2_rn(v0, v1);
    p.b = __floats2half2_rn(v2, v3);
    *(Half4*)&C[(size_t)(r0 + m) * 128 + c0 + quad * 4] = p;
  } else {
    *(float4*)&C[(size_t)(r0 + m) * 128 + c0 + quad * 4] = make_float4(v0, v1, v2, v3);
  }
}

// ---------------- orchestration ----------------

extern "C" void kernel_launch(void* const* d_in, const int* in_sizes, int n_in,
                              void* d_out, int out_size, void* d_ws, size_t ws_size,
                              hipStream_t stream) {
  const float* x   = (const float*)d_in[0];
  const int*   ei  = (const int*)d_in[1];
  const float* w1  = (const float*)d_in[2];
  const float* as1 = (const float*)d_in[3];
  const float* ad1 = (const float*)d_in[4];
  const float* b1  = (const float*)d_in[5];
  const float* w2  = (const float*)d_in[6];
  const float* as2 = (const float*)d_in[7];
  const float* ad2 = (const float*)d_in[8];
  const float* b2  = (const float*)d_in[9];
  const float* w3  = (const float*)d_in[10];
  const float* as3 = (const float*)d_in[11];
  const float* ad3 = (const float*)d_in[12];
  const float* b3  = (const float*)d_in[13];
  const float* rw1 = (const float*)d_in[14];
  const float* rb1 = (const float*)d_in[15];
  const float* rw2 = (const float*)d_in[16];
  const float* rb2 = (const float*)d_in[17];
  const float* lw  = (const float*)d_in[18];
  const float* lb  = (const float*)d_in[19];

  int N = in_sizes[0] / 4;
  int E = in_sizes[1] / 2;
  int ET = E + N;
  (void)ws_size;

  char* wsb = (char*)d_ws;
  size_t off = 0;
  auto alloc = [&](size_t bytes) -> void* {
    void* p = wsb + off;
    off += (bytes + 255) & ~(size_t)255;
    return p;
  };
  __half* A16 = (__half*)alloc((size_t)N * 1024 * 2);  // h (pre-attention features)
  __half* G   = (__half*)alloc((size_t)N * 1024 * 2);  // gelu(GAT output)
  __half* P16 = (__half*)alloc((size_t)N * 128 * 2);   // projected features
  __half* wt2 = (__half*)alloc((size_t)1024 * 128 * 2);
  __half* wt3 = (__half*)alloc((size_t)1024 * 128 * 2);
  __half* rwt1 = (__half*)alloc((size_t)128 * 1024 * 2);
  __half* rwt2 = (__half*)alloc((size_t)128 * 1024 * 2);
  __half* lwt  = (__half*)alloc((size_t)128 * 1024 * 2);
  float* ssrc = (float*)alloc((size_t)N * 8 * 4);      // contiguous with sdst:
  float* sdst = (float*)alloc((size_t)N * 8 * 4);      //  one memset covers both
  float* alpha = (float*)alloc((size_t)ET * 8 * 4);
  int* counts  = (int*)alloc((size_t)N * 4);
  int* offsets = (int*)alloc((size_t)(N + 1) * 4);
  int* cursor  = (int*)alloc((size_t)N * 4);
  int* srcs    = (int*)alloc((size_t)ET * 4);

  dim3 blk(THREADS);

  // CSR build + weight conversions (once; graph/weights identical for all layers)
  hipMemsetAsync(counts, 0, (size_t)N * 4, stream);
  hist_kernel<<<dim3((ET + THREADS - 1) / THREADS), blk, 0, stream>>>(ei, E, ET, counts);
  wconv_all_kernel<<<dim3(32, 32, 5), blk, 0, stream>>>(w2, w3, rw1, rw2, lw,
                                                        wt2, wt3, rwt1, rwt2, lwt);
  scan_kernel<<<dim3(1), dim3(1024), 0, stream>>>(counts, offsets, cursor, N);
  scatter_kernel<<<dim3((ET + THREADS - 1) / THREADS), blk, 0, stream>>>(ei, E, ET, cursor, srcs);

  dim3 gAttn(N / 4);
  dim3 gAgg(N * 2);          // (N/4 node-groups) x 8 heads; bid&7 = head
  dim3 gGemm(16, N / 16);
  dim3 gProj(2, N / 16);
  size_t scz_bytes = (size_t)N * 16 * 4;

  // ---- layer 1 ----
  hipMemsetAsync(ssrc, 0, scz_bytes, stream);
  feat1_kernel<<<dim3((N * 1024 + THREADS - 1) / THREADS), blk, 0, stream>>>(
      x, w1, as1, ad1, A16, ssrc, sdst, N * 1024);
  attn_kernel<<<gAttn, blk, 0, stream>>>(srcs, offsets, ssrc, sdst, alpha);
  aggh_kernel<<<gAgg, blk, 0, stream>>>(A16, alpha, offsets, srcs, b1, G);
  proj_mfma<__half><<<gProj, blk, 0, stream>>>(G, rwt1, rb1, P16);

  // ---- layer 2 ----
  hipMemsetAsync(ssrc, 0, scz_bytes, stream);
  gemm128_mfma<<<gGemm, blk, 0, stream>>>(P16, wt2, as2, ad2, A16, ssrc, sdst);
  attn_kernel<<<gAttn, blk, 0, stream>>>(srcs, offsets, ssrc, sdst, alpha);
  aggh_kernel<<<gAgg, blk, 0, stream>>>(A16, alpha, offsets, srcs, b2, G);
  proj_mfma<__half><<<gProj, blk, 0, stream>>>(G, rwt2, rb2, P16);

  // ---- layer 3 ----
  hipMemsetAsync(ssrc, 0, scz_bytes, stream);
  gemm128_mfma<<<gGemm, blk, 0, stream>>>(P16, wt3, as3, ad3, A16, ssrc, sdst);
  attn_kernel<<<gAttn, blk, 0, stream>>>(srcs, offsets, ssrc, sdst, alpha);
  aggh_kernel<<<gAgg, blk, 0, stream>>>(A16, alpha, offsets, srcs, b3, G);
  proj_mfma<float><<<gProj, blk, 0, stream>>>(G, lwt, lb, (float*)d_out);
}

// Round 8
// 530.811 us; speedup vs baseline: 1.2612x; 1.0196x over previous
//
#include <hip/hip_runtime.h>
#include <hip/hip_fp16.h>
#include <math.h>

// GAT encoder: N=10000, E=160000 (+N self loops), H=8 heads, C=128, D=1024.
// CSR-by-dst built once. Intermediates fp16; dense GEMMs on matrix cores with
// NON-ATOMIC score-partial epilogues + tiny reduce kernel (atomics to fabric
// were a 45 us/dispatch disaster in R6). Attention softmax fused wave-per-node.
// Aggregation head-partitioned (blockIdx%8 == head -> XCD-pinned L2 panel).

#define THREADS 256

typedef _Float16 f16x8 __attribute__((ext_vector_type(8)));
typedef float f32x4 __attribute__((ext_vector_type(4)));

struct __align__(8) Half4 { __half2 a, b; };

__device__ __forceinline__ float gelu_exact(float x) {
  return 0.5f * x * (1.0f + erff(x * 0.70710678118654752f));
}

__device__ __forceinline__ float4 h4_to_f4(float2 raw) {
  __half2 h01 = *(__half2*)&raw.x;
  __half2 h23 = *(__half2*)&raw.y;
  float2 f01 = __half22float2(h01);
  float2 f23 = __half22float2(h23);
  return make_float4(f01.x, f01.y, f23.x, f23.y);
}

// ---------------- CSR build ----------------

__global__ void hist_kernel(const int* __restrict__ ei, int E, int ET, int* __restrict__ counts) {
  int e = blockIdx.x * THREADS + threadIdx.x;
  if (e >= ET) return;
  int d = (e < E) ? ei[E + e] : (e - E);
  atomicAdd(&counts[d], 1);
}

__global__ __launch_bounds__(1024) void scan_kernel(const int* __restrict__ counts,
                                                    int* __restrict__ offsets,
                                                    int* __restrict__ cursor, int n) {
  __shared__ int sums[1024];
  int t = threadIdx.x;
  int per = (n + 1023) >> 10;
  int start = t * per; if (start > n) start = n;
  int end = start + per; if (end > n) end = n;
  int local = 0;
  for (int i = start; i < end; ++i) local += counts[i];
  sums[t] = local;
  __syncthreads();
  for (int off = 1; off < 1024; off <<= 1) {
    int add = (t >= off) ? sums[t - off] : 0;
    __syncthreads();
    sums[t] += add;
    __syncthreads();
  }
  int run = (t == 0) ? 0 : sums[t - 1];
  for (int i = start; i < end; ++i) {
    offsets[i] = run; cursor[i] = run; run += counts[i];
  }
  if (t == 1023) offsets[n] = run;
}

__global__ void scatter_kernel(const int* __restrict__ ei, int E, int ET,
                               int* __restrict__ cursor, int* __restrict__ srcs) {
  int e = blockIdx.x * THREADS + threadIdx.x;
  if (e >= ET) return;
  int s = (e < E) ? ei[e] : (e - E);
  int d = (e < E) ? ei[E + e] : (e - E);
  int pos = atomicAdd(&cursor[d], 1);
  srcs[pos] = s;
}

// ---------------- batched weight transpose + fp16 convert ----------------

__global__ __launch_bounds__(256) void wconv_all_kernel(
    const float* __restrict__ w2, const float* __restrict__ w3,
    const float* __restrict__ rw1, const float* __restrict__ rw2,
    const float* __restrict__ lw,
    __half* __restrict__ wt2, __half* __restrict__ wt3,
    __half* __restrict__ rwt1, __half* __restrict__ rwt2,
    __half* __restrict__ lwt) {
  const float* in; __half* out; int K, Ncol;
  switch (blockIdx.z) {
    case 0: in = w2;  out = wt2;  K = 128;  Ncol = 1024; break;
    case 1: in = w3;  out = wt3;  K = 128;  Ncol = 1024; break;
    case 2: in = rw1; out = rwt1; K = 1024; Ncol = 128;  break;
    case 3: in = rw2; out = rwt2; K = 1024; Ncol = 128;  break;
    default: in = lw; out = lwt;  K = 1024; Ncol = 128;  break;
  }
  int kb = blockIdx.y * 32, cb = blockIdx.x * 32;
  if (kb >= K || cb >= Ncol) return;
  __shared__ float tile[32][33];
  int t = threadIdx.x;
  int tc = t & 31, tr = t >> 5;
#pragma unroll
  for (int r = tr; r < 32; r += 8)
    tile[r][tc] = in[(size_t)(kb + r) * Ncol + cb + tc];
  __syncthreads();
#pragma unroll
  for (int r = tr; r < 32; r += 8)
    out[(size_t)(cb + r) * K + kb + tc] = __float2half_rn(tile[tc][r]);
}

// ---------------- layer 1 feature transform (K=4) + non-atomic score partials ----------------
// Wave = 64 consecutive d of one node (half a head): partial -> part[n*16 + (d>>6)].

__global__ void feat1_kernel(const float* __restrict__ x, const float* __restrict__ w,
                             const float* __restrict__ as, const float* __restrict__ ad,
                             __half* __restrict__ out,
                             float* __restrict__ s1part, float* __restrict__ s2part,
                             int total) {
  int idx = blockIdx.x * THREADS + threadIdx.x;
  if (idx >= total) return;
  int n = idx >> 10, d = idx & 1023;
  float4 xv = *(const float4*)&x[n * 4];
  float v = xv.x * w[d] + xv.y * w[1024 + d] + xv.z * w[2048 + d] + xv.w * w[3072 + d];
  out[idx] = __float2half_rn(v);
  float p1 = v * as[d];
  float p2 = v * ad[d];
#pragma unroll
  for (int mask = 1; mask <= 32; mask <<= 1) {
    p1 += __shfl_xor(p1, mask);
    p2 += __shfl_xor(p2, mask);
  }
  if ((d & 63) == 0) {
    int c = n * 16 + (d >> 6);
    s1part[c] = p1;
    s2part[c] = p2;
  }
}

// ---------------- MFMA GEMM + non-atomic score partials ----------------
// Wave = 16 cols (one chunk) x 16 rows; partial -> part[(r0+m)*64 + (c0>>4)].

__global__ __launch_bounds__(256) void gemm128_mfma(const __half* __restrict__ P16,
                                                    const __half* __restrict__ Wt,
                                                    const float* __restrict__ as,
                                                    const float* __restrict__ ad,
                                                    __half* __restrict__ A16,
                                                    float* __restrict__ s1part,
                                                    float* __restrict__ s2part) {
  int wave = threadIdx.x >> 6, lane = threadIdx.x & 63;
  int r0 = blockIdx.y * 16;
  int c0 = blockIdx.x * 64 + wave * 16;
  int m = lane & 15, quad = lane >> 4;
  const __half* pa = Wt + (size_t)(c0 + m) * 128 + quad * 8;
  const __half* pb = P16 + (size_t)(r0 + m) * 128 + quad * 8;
  f32x4 acc = {0.f, 0.f, 0.f, 0.f};
#pragma unroll
  for (int k = 0; k < 128; k += 32) {
    f16x8 a = *(const f16x8*)(pa + k);
    f16x8 b = *(const f16x8*)(pb + k);
    acc = __builtin_amdgcn_mfma_f32_16x16x32_f16(a, b, acc, 0, 0, 0);
  }
  Half4 p;
  p.a = __floats2half2_rn(acc[0], acc[1]);
  p.b = __floats2half2_rn(acc[2], acc[3]);
  *(Half4*)&A16[(size_t)(r0 + m) * 1024 + c0 + quad * 4] = p;
  // score partials over this wave's 16 columns (non-atomic: unique (row, chunk))
  float4 asv = *(const float4*)&as[c0 + quad * 4];
  float4 adv = *(const float4*)&ad[c0 + quad * 4];
  float s1 = acc[0] * asv.x + acc[1] * asv.y + acc[2] * asv.z + acc[3] * asv.w;
  float s2 = acc[0] * adv.x + acc[1] * adv.y + acc[2] * adv.z + acc[3] * adv.w;
  s1 += __shfl_xor(s1, 16); s1 += __shfl_xor(s1, 32);
  s2 += __shfl_xor(s2, 16); s2 += __shfl_xor(s2, 32);
  if (quad == 0) {
    int c = (r0 + m) * 64 + (c0 >> 4);
    s1part[c] = s1;
    s2part[c] = s2;
  }
}

// ---------------- score partial reduction: part[N][P] -> ssrc/sdst[N][8] ----------------
// pp = partials per head (P = 8*pp).

__global__ void reduce_scores_kernel(const float* __restrict__ s1part,
                                     const float* __restrict__ s2part,
                                     float* __restrict__ ssrc, float* __restrict__ sdst,
                                     int pp, int total) {
  int idx = blockIdx.x * THREADS + threadIdx.x;
  if (idx >= total) return;   // total = N*8
  int base = idx * pp;
  float a = 0.f, b = 0.f;
  for (int i = 0; i < pp; ++i) {
    a += s1part[base + i];
    b += s2part[base + i];
  }
  ssrc[idx] = a;
  sdst[idx] = b;
}

// ---------------- attention: logits + softmax + normalized alpha (one wave per node) ----------------

__global__ __launch_bounds__(256) void attn_kernel(const int* __restrict__ srcs,
                                                   const int* __restrict__ offsets,
                                                   const float* __restrict__ ssrc,
                                                   const float* __restrict__ sdst,
                                                   float* __restrict__ alpha) {
  int wave = threadIdx.x >> 6, lane = threadIdx.x & 63;
  int n = blockIdx.x * 4 + wave;
  int head = lane & 7, es = lane >> 3;
  int start = offsets[n];
  int deg = offsets[n + 1] - start;
  float sd = sdst[n * 8 + head];
  float m = -1e30f, s = 0.f;
  for (int i = es; i < deg; i += 8) {
    int sp = srcs[start + i];
    float v = ssrc[sp * 8 + head] + sd;
    v = (v > 0.f) ? v : 0.2f * v;
    if (v > m) { s = s * __expf(m - v) + 1.f; m = v; }
    else s += __expf(v - m);
  }
#pragma unroll
  for (int mask = 8; mask <= 32; mask <<= 1) {
    float m2 = __shfl_xor(m, mask);
    float s2 = __shfl_xor(s, mask);
    float M = fmaxf(m, m2);
    s = s * __expf(m - M) + s2 * __expf(m2 - M);
    m = M;
  }
  float zinv = 1.f / s;
  for (int i = es; i < deg; i += 8) {
    int sp = srcs[start + i];
    float v = ssrc[sp * 8 + head] + sd;
    v = (v > 0.f) ? v : 0.2f * v;
    alpha[(size_t)(start + i) * 8 + head] = __expf(v - m) * zinv;
  }
}

// ---------------- head-panel aggregation + bias + GELU (one wave per node) ----------------
// bid&7 = head (XCD-pinned panel); lane: cg = lane&15 (8 ch, 16 B), es = lane>>4.

__global__ __launch_bounds__(256) void aggh_kernel(const __half* __restrict__ H16,
                                                   const float* __restrict__ alpha,
                                                   const int* __restrict__ offsets,
                                                   const int* __restrict__ srcs,
                                                   const float* __restrict__ bias,
                                                   __half* __restrict__ G) {
  int bid = blockIdx.x;
  int head = bid & 7, ng = bid >> 3;
  int wave = threadIdx.x >> 6, lane = threadIdx.x & 63;
  int n = ng * 4 + wave;
  int cg = lane & 15, es = lane >> 4;
  int start = offsets[n];
  int deg = offsets[n + 1] - start;
  int base = head * 128 + cg * 8;
  float acc[8] = {};
  int i = es;
  for (; i + 4 < deg; i += 8) {
    int e0 = start + i, e1 = start + i + 4;
    int sp0 = srcs[e0], sp1 = srcs[e1];
    float a0 = alpha[(size_t)e0 * 8 + head];
    float a1 = alpha[(size_t)e1 * 8 + head];
    float4 r0 = *(const float4*)&H16[(size_t)sp0 * 1024 + base];
    float4 r1 = *(const float4*)&H16[(size_t)sp1 * 1024 + base];
    float4 f0 = h4_to_f4(make_float2(r0.x, r0.y));
    float4 f1 = h4_to_f4(make_float2(r0.z, r0.w));
    float4 f2 = h4_to_f4(make_float2(r1.x, r1.y));
    float4 f3 = h4_to_f4(make_float2(r1.z, r1.w));
    acc[0] += a0 * f0.x; acc[1] += a0 * f0.y; acc[2] += a0 * f0.z; acc[3] += a0 * f0.w;
    acc[4] += a0 * f1.x; acc[5] += a0 * f1.y; acc[6] += a0 * f1.z; acc[7] += a0 * f1.w;
    acc[0] += a1 * f2.x; acc[1] += a1 * f2.y; acc[2] += a1 * f2.z; acc[3] += a1 * f2.w;
    acc[4] += a1 * f3.x; acc[5] += a1 * f3.y; acc[6] += a1 * f3.z; acc[7] += a1 * f3.w;
  }
  for (; i < deg; i += 4) {
    int e0 = start + i;
    int sp0 = srcs[e0];
    float a0 = alpha[(size_t)e0 * 8 + head];
    float4 r0 = *(const float4*)&H16[(size_t)sp0 * 1024 + base];
    float4 f0 = h4_to_f4(make_float2(r0.x, r0.y));
    float4 f1 = h4_to_f4(make_float2(r0.z, r0.w));
    acc[0] += a0 * f0.x; acc[1] += a0 * f0.y; acc[2] += a0 * f0.z; acc[3] += a0 * f0.w;
    acc[4] += a0 * f1.x; acc[5] += a0 * f1.y; acc[6] += a0 * f1.z; acc[7] += a0 * f1.w;
  }
#pragma unroll
  for (int u = 0; u < 8; ++u) {
    acc[u] += __shfl_xor(acc[u], 16);
    acc[u] += __shfl_xor(acc[u], 32);
  }
  if (es == 0) {
    float4 b0 = *(const float4*)&bias[base];
    float4 b1 = *(const float4*)&bias[base + 4];
    float o[8];
    o[0] = gelu_exact(acc[0] + b0.x); o[1] = gelu_exact(acc[1] + b0.y);
    o[2] = gelu_exact(acc[2] + b0.z); o[3] = gelu_exact(acc[3] + b0.w);
    o[4] = gelu_exact(acc[4] + b1.x); o[5] = gelu_exact(acc[5] + b1.y);
    o[6] = gelu_exact(acc[6] + b1.z); o[7] = gelu_exact(acc[7] + b1.w);
    __half2 p[4];
    p[0] = __floats2half2_rn(o[0], o[1]); p[1] = __floats2half2_rn(o[2], o[3]);
    p[2] = __floats2half2_rn(o[4], o[5]); p[3] = __floats2half2_rn(o[6], o[7]);
    *(float4*)&G[(size_t)n * 1024 + base] = *(float4*)p;
  }
}

// ---------------- MFMA proj: G[N,1024] @ W[1024,128] + bias -> C[N,128] ----------------

template <typename OutT>
__global__ __launch_bounds__(256) void proj_mfma(const __half* __restrict__ G,
                                                 const __half* __restrict__ Wt,
                                                 const float* __restrict__ bias,
                                                 OutT* __restrict__ C) {
  int wave = threadIdx.x >> 6, lane = threadIdx.x & 63;
  int r0 = blockIdx.y * 16;
  int c0 = blockIdx.x * 64 + wave * 16;
  int m = lane & 15, quad = lane >> 4;
  const __half* pa = Wt + (size_t)(c0 + m) * 1024 + quad * 8;
  const __half* pb = G + (size_t)(r0 + m) * 1024 + quad * 8;
  f32x4 acc = {0.f, 0.f, 0.f, 0.f};
#pragma unroll 8
  for (int k = 0; k < 1024; k += 32) {
    f16x8 a = *(const f16x8*)(pa + k);
    f16x8 b = *(const f16x8*)(pb + k);
    acc = __builtin_amdgcn_mfma_f32_16x16x32_f16(a, b, acc, 0, 0, 0);
  }
  float4 b4 = *(const float4*)&bias[c0 + quad * 4];
  float v0 = acc[0] + b4.x, v1 = acc[1] + b4.y, v2 = acc[2] + b4.z, v3 = acc[3] + b4.w;
  if constexpr (__is_same(OutT, __half)) {
    Half4 p;
    p.a = __floats2half2_rn(v0, v1);
    p.b = __floats2half2_rn(v2, v3);
    *(Half4*)&C[(size_t)(r0 + m) * 128 + c0 + quad * 4] = p;
  } else {
    *(float4*)&C[(size_t)(r0 + m) * 128 + c0 + quad * 4] = make_float4(v0, v1, v2, v3);
  }
}

// ---------------- orchestration ----------------

extern "C" void kernel_launch(void* const* d_in, const int* in_sizes, int n_in,
                              void* d_out, int out_size, void* d_ws, size_t ws_size,
                              hipStream_t stream) {
  const float* x   = (const float*)d_in[0];
  const int*   ei  = (const int*)d_in[1];
  const float* w1  = (const float*)d_in[2];
  const float* as1 = (const float*)d_in[3];
  const float* ad1 = (const float*)d_in[4];
  const float* b1  = (const float*)d_in[5];
  const float* w2  = (const float*)d_in[6];
  const float* as2 = (const float*)d_in[7];
  const float* ad2 = (const float*)d_in[8];
  const float* b2  = (const float*)d_in[9];
  const float* w3  = (const float*)d_in[10];
  const float* as3 = (const float*)d_in[11];
  const float* ad3 = (const float*)d_in[12];
  const float* b3  = (const float*)d_in[13];
  const float* rw1 = (const float*)d_in[14];
  const float* rb1 = (const float*)d_in[15];
  const float* rw2 = (const float*)d_in[16];
  const float* rb2 = (const float*)d_in[17];
  const float* lw  = (const float*)d_in[18];
  const float* lb  = (const float*)d_in[19];

  int N = in_sizes[0] / 4;
  int E = in_sizes[1] / 2;
  int ET = E + N;
  (void)ws_size;

  char* wsb = (char*)d_ws;
  size_t off = 0;
  auto alloc = [&](size_t bytes) -> void* {
    void* p = wsb + off;
    off += (bytes + 255) & ~(size_t)255;
    return p;
  };
  __half* A16 = (__half*)alloc((size_t)N * 1024 * 2);  // h (pre-attention features)
  __half* G   = (__half*)alloc((size_t)N * 1024 * 2);  // gelu(GAT output)
  __half* P16 = (__half*)alloc((size_t)N * 128 * 2);   // projected features
  __half* wt2 = (__half*)alloc((size_t)1024 * 128 * 2);
  __half* wt3 = (__half*)alloc((size_t)1024 * 128 * 2);
  __half* rwt1 = (__half*)alloc((size_t)128 * 1024 * 2);
  __half* rwt2 = (__half*)alloc((size_t)128 * 1024 * 2);
  __half* lwt  = (__half*)alloc((size_t)128 * 1024 * 2);
  float* ssrc  = (float*)alloc((size_t)N * 8 * 4);
  float* sdst  = (float*)alloc((size_t)N * 8 * 4);
  float* s1part = (float*)alloc((size_t)N * 64 * 4);
  float* s2part = (float*)alloc((size_t)N * 64 * 4);
  float* alpha = (float*)alloc((size_t)ET * 8 * 4);
  int* counts  = (int*)alloc((size_t)N * 4);
  int* offsets = (int*)alloc((size_t)(N + 1) * 4);
  int* cursor  = (int*)alloc((size_t)N * 4);
  int* srcs    = (int*)alloc((size_t)ET * 4);

  dim3 blk(THREADS);

  // CSR build + weight conversions (once; graph/weights identical for all layers)
  hipMemsetAsync(counts, 0, (size_t)N * 4, stream);
  hist_kernel<<<dim3((ET + THREADS - 1) / THREADS), blk, 0, stream>>>(ei, E, ET, counts);
  wconv_all_kernel<<<dim3(32, 32, 5), blk, 0, stream>>>(w2, w3, rw1, rw2, lw,
                                                        wt2, wt3, rwt1, rwt2, lwt);
  scan_kernel<<<dim3(1), dim3(1024), 0, stream>>>(counts, offsets, cursor, N);
  scatter_kernel<<<dim3((ET + THREADS - 1) / THREADS), blk, 0, stream>>>(ei, E, ET, cursor, srcs);

  dim3 gRed((N * 8 + THREADS - 1) / THREADS);
  dim3 gAttn(N / 4);
  dim3 gAgg(N * 2);          // (N/4 node-groups) x 8 heads; bid&7 = head
  dim3 gGemm(16, N / 16);
  dim3 gProj(2, N / 16);

  // ---- layer 1 ----
  feat1_kernel<<<dim3((N * 1024 + THREADS - 1) / THREADS), blk, 0, stream>>>(
      x, w1, as1, ad1, A16, s1part, s2part, N * 1024);
  reduce_scores_kernel<<<gRed, blk, 0, stream>>>(s1part, s2part, ssrc, sdst, 2, N * 8);
  attn_kernel<<<gAttn, blk, 0, stream>>>(srcs, offsets, ssrc, sdst, alpha);
  aggh_kernel<<<gAgg, blk, 0, stream>>>(A16, alpha, offsets, srcs, b1, G);
  proj_mfma<__half><<<gProj, blk, 0, stream>>>(G, rwt1, rb1, P16);

  // ---- layer 2 ----
  gemm128_mfma<<<gGemm, blk, 0, stream>>>(P16, wt2, as2, ad2, A16, s1part, s2part);
  reduce_scores_kernel<<<gRed, blk, 0, stream>>>(s1part, s2part, ssrc, sdst, 8, N * 8);
  attn_kernel<<<gAttn, blk, 0, stream>>>(srcs, offsets, ssrc, sdst, alpha);
  aggh_kernel<<<gAgg, blk, 0, stream>>>(A16, alpha, offsets, srcs, b2, G);
  proj_mfma<__half><<<gProj, blk, 0, stream>>>(G, rwt2, rb2, P16);

  // ---- layer 3 ----
  gemm128_mfma<<<gGemm, blk, 0, stream>>>(P16, wt3, as3, ad3, A16, s1part, s2part);
  reduce_scores_kernel<<<gRed, blk, 0, stream>>>(s1part, s2part, ssrc, sdst, 8, N * 8);
  attn_kernel<<<gAttn, blk, 0, stream>>>(srcs, offsets, ssrc, sdst, alpha);
  aggh_kernel<<<gAgg, blk, 0, stream>>>(A16, alpha, offsets, srcs, b3, G);
  proj_mfma<float><<<gProj, blk, 0, stream>>>(G, lwt, lb, (float*)d_out);
}

// Round 9
// 523.048 us; speedup vs baseline: 1.2799x; 1.0148x over previous
//
#include <hip/hip_runtime.h>
#include <hip/hip_fp16.h>
#include <math.h>

// GAT encoder: N=10000, E=160000 (+N self loops), H=8 heads, C=128, D=1024.
// CSR-by-dst built once. Intermediates fp16; dense GEMMs on matrix cores with
// non-atomic score-partial epilogues + tiny reduce kernel. Attention softmax
// fused wave-per-node. Aggregation head-partitioned (blockIdx%8 == head ->
// XCD-pinned L2 panel), wave-per-node, v_fma_mix inner loop (f16 operand
// folded into fp32 FMA), full-width GELU epilogue.

#define THREADS 256

typedef _Float16 f16x8 __attribute__((ext_vector_type(8)));
typedef float f32x4 __attribute__((ext_vector_type(4)));

struct __align__(8) Half4 { __half2 a, b; };

__device__ __forceinline__ float gelu_exact(float x) {
  return 0.5f * x * (1.0f + erff(x * 0.70710678118654752f));
}

__device__ __forceinline__ float4 h4_to_f4(float2 raw) {
  __half2 h01 = *(__half2*)&raw.x;
  __half2 h23 = *(__half2*)&raw.y;
  float2 f01 = __half22float2(h01);
  float2 f23 = __half22float2(h23);
  return make_float4(f01.x, f01.y, f23.x, f23.y);
}

// ---------------- CSR build ----------------

__global__ void hist_kernel(const int* __restrict__ ei, int E, int ET, int* __restrict__ counts) {
  int e = blockIdx.x * THREADS + threadIdx.x;
  if (e >= ET) return;
  int d = (e < E) ? ei[E + e] : (e - E);
  atomicAdd(&counts[d], 1);
}

__global__ __launch_bounds__(1024) void scan_kernel(const int* __restrict__ counts,
                                                    int* __restrict__ offsets,
                                                    int* __restrict__ cursor, int n) {
  __shared__ int sums[1024];
  int t = threadIdx.x;
  int per = (n + 1023) >> 10;
  int start = t * per; if (start > n) start = n;
  int end = start + per; if (end > n) end = n;
  int local = 0;
  for (int i = start; i < end; ++i) local += counts[i];
  sums[t] = local;
  __syncthreads();
  for (int off = 1; off < 1024; off <<= 1) {
    int add = (t >= off) ? sums[t - off] : 0;
    __syncthreads();
    sums[t] += add;
    __syncthreads();
  }
  int run = (t == 0) ? 0 : sums[t - 1];
  for (int i = start; i < end; ++i) {
    offsets[i] = run; cursor[i] = run; run += counts[i];
  }
  if (t == 1023) offsets[n] = run;
}

__global__ void scatter_kernel(const int* __restrict__ ei, int E, int ET,
                               int* __restrict__ cursor, int* __restrict__ srcs) {
  int e = blockIdx.x * THREADS + threadIdx.x;
  if (e >= ET) return;
  int s = (e < E) ? ei[e] : (e - E);
  int d = (e < E) ? ei[E + e] : (e - E);
  int pos = atomicAdd(&cursor[d], 1);
  srcs[pos] = s;
}

// ---------------- batched weight transpose + fp16 convert ----------------

__global__ __launch_bounds__(256) void wconv_all_kernel(
    const float* __restrict__ w2, const float* __restrict__ w3,
    const float* __restrict__ rw1, const float* __restrict__ rw2,
    const float* __restrict__ lw,
    __half* __restrict__ wt2, __half* __restrict__ wt3,
    __half* __restrict__ rwt1, __half* __restrict__ rwt2,
    __half* __restrict__ lwt) {
  const float* in; __half* out; int K, Ncol;
  switch (blockIdx.z) {
    case 0: in = w2;  out = wt2;  K = 128;  Ncol = 1024; break;
    case 1: in = w3;  out = wt3;  K = 128;  Ncol = 1024; break;
    case 2: in = rw1; out = rwt1; K = 1024; Ncol = 128;  break;
    case 3: in = rw2; out = rwt2; K = 1024; Ncol = 128;  break;
    default: in = lw; out = lwt;  K = 1024; Ncol = 128;  break;
  }
  int kb = blockIdx.y * 32, cb = blockIdx.x * 32;
  if (kb >= K || cb >= Ncol) return;
  __shared__ float tile[32][33];
  int t = threadIdx.x;
  int tc = t & 31, tr = t >> 5;
#pragma unroll
  for (int r = tr; r < 32; r += 8)
    tile[r][tc] = in[(size_t)(kb + r) * Ncol + cb + tc];
  __syncthreads();
#pragma unroll
  for (int r = tr; r < 32; r += 8)
    out[(size_t)(cb + r) * K + kb + tc] = __float2half_rn(tile[tc][r]);
}

// ---------------- layer 1 feature transform (K=4) + non-atomic score partials ----------------

__global__ void feat1_kernel(const float* __restrict__ x, const float* __restrict__ w,
                             const float* __restrict__ as, const float* __restrict__ ad,
                             __half* __restrict__ out,
                             float* __restrict__ s1part, float* __restrict__ s2part,
                             int total) {
  int idx = blockIdx.x * THREADS + threadIdx.x;
  if (idx >= total) return;
  int n = idx >> 10, d = idx & 1023;
  float4 xv = *(const float4*)&x[n * 4];
  float v = xv.x * w[d] + xv.y * w[1024 + d] + xv.z * w[2048 + d] + xv.w * w[3072 + d];
  out[idx] = __float2half_rn(v);
  float p1 = v * as[d];
  float p2 = v * ad[d];
#pragma unroll
  for (int mask = 1; mask <= 32; mask <<= 1) {
    p1 += __shfl_xor(p1, mask);
    p2 += __shfl_xor(p2, mask);
  }
  if ((d & 63) == 0) {
    int c = n * 16 + (d >> 6);
    s1part[c] = p1;
    s2part[c] = p2;
  }
}

// ---------------- MFMA GEMM + non-atomic score partials ----------------

__global__ __launch_bounds__(256) void gemm128_mfma(const __half* __restrict__ P16,
                                                    const __half* __restrict__ Wt,
                                                    const float* __restrict__ as,
                                                    const float* __restrict__ ad,
                                                    __half* __restrict__ A16,
                                                    float* __restrict__ s1part,
                                                    float* __restrict__ s2part) {
  int wave = threadIdx.x >> 6, lane = threadIdx.x & 63;
  int r0 = blockIdx.y * 16;
  int c0 = blockIdx.x * 64 + wave * 16;
  int m = lane & 15, quad = lane >> 4;
  const __half* pa = Wt + (size_t)(c0 + m) * 128 + quad * 8;
  const __half* pb = P16 + (size_t)(r0 + m) * 128 + quad * 8;
  f32x4 acc = {0.f, 0.f, 0.f, 0.f};
#pragma unroll
  for (int k = 0; k < 128; k += 32) {
    f16x8 a = *(const f16x8*)(pa + k);
    f16x8 b = *(const f16x8*)(pb + k);
    acc = __builtin_amdgcn_mfma_f32_16x16x32_f16(a, b, acc, 0, 0, 0);
  }
  Half4 p;
  p.a = __floats2half2_rn(acc[0], acc[1]);
  p.b = __floats2half2_rn(acc[2], acc[3]);
  *(Half4*)&A16[(size_t)(r0 + m) * 1024 + c0 + quad * 4] = p;
  float4 asv = *(const float4*)&as[c0 + quad * 4];
  float4 adv = *(const float4*)&ad[c0 + quad * 4];
  float s1 = acc[0] * asv.x + acc[1] * asv.y + acc[2] * asv.z + acc[3] * asv.w;
  float s2 = acc[0] * adv.x + acc[1] * adv.y + acc[2] * adv.z + acc[3] * adv.w;
  s1 += __shfl_xor(s1, 16); s1 += __shfl_xor(s1, 32);
  s2 += __shfl_xor(s2, 16); s2 += __shfl_xor(s2, 32);
  if (quad == 0) {
    int c = (r0 + m) * 64 + (c0 >> 4);
    s1part[c] = s1;
    s2part[c] = s2;
  }
}

// ---------------- score partial reduction ----------------

__global__ void reduce_scores_kernel(const float* __restrict__ s1part,
                                     const float* __restrict__ s2part,
                                     float* __restrict__ ssrc, float* __restrict__ sdst,
                                     int pp, int total) {
  int idx = blockIdx.x * THREADS + threadIdx.x;
  if (idx >= total) return;
  int base = idx * pp;
  float a = 0.f, b = 0.f;
  for (int i = 0; i < pp; ++i) {
    a += s1part[base + i];
    b += s2part[base + i];
  }
  ssrc[idx] = a;
  sdst[idx] = b;
}

// ---------------- attention: logits + softmax + normalized alpha (one wave per node) ----------------

__global__ __launch_bounds__(256) void attn_kernel(const int* __restrict__ srcs,
                                                   const int* __restrict__ offsets,
                                                   const float* __restrict__ ssrc,
                                                   const float* __restrict__ sdst,
                                                   float* __restrict__ alpha) {
  int wave = threadIdx.x >> 6, lane = threadIdx.x & 63;
  int n = blockIdx.x * 4 + wave;
  int head = lane & 7, es = lane >> 3;
  int start = offsets[n];
  int deg = offsets[n + 1] - start;
  float sd = sdst[n * 8 + head];
  float m = -1e30f, s = 0.f;
  for (int i = es; i < deg; i += 8) {
    int sp = srcs[start + i];
    float v = ssrc[sp * 8 + head] + sd;
    v = (v > 0.f) ? v : 0.2f * v;
    if (v > m) { s = s * __expf(m - v) + 1.f; m = v; }
    else s += __expf(v - m);
  }
#pragma unroll
  for (int mask = 8; mask <= 32; mask <<= 1) {
    float m2 = __shfl_xor(m, mask);
    float s2 = __shfl_xor(s, mask);
    float M = fmaxf(m, m2);
    s = s * __expf(m - M) + s2 * __expf(m2 - M);
    m = M;
  }
  float zinv = 1.f / s;
  for (int i = es; i < deg; i += 8) {
    int sp = srcs[start + i];
    float v = ssrc[sp * 8 + head] + sd;
    v = (v > 0.f) ? v : 0.2f * v;
    alpha[(size_t)(start + i) * 8 + head] = __expf(v - m) * zinv;
  }
}

// ---------------- head-panel aggregation + bias + GELU (one wave per node) ----------------
// bid&7 = head (XCD-pinned panel); cg = lane&15 (8 ch, 16 B), es = lane>>4.
// Inner loop: acc += alpha * (float)h16 -> compiler emits v_fma_mix_f32 (no cvt).
// Epilogue: xor-16/32 reduce gives every lane all 8 sums; each lane GELUs its
// es-selected channel pair -> full 64-lane GELU width, 4B store per lane.

__global__ __launch_bounds__(256) void aggh_kernel(const __half* __restrict__ H16,
                                                   const float* __restrict__ alpha,
                                                   const int* __restrict__ offsets,
                                                   const int* __restrict__ srcs,
                                                   const float* __restrict__ bias,
                                                   __half* __restrict__ G) {
  int bid = blockIdx.x;
  int head = bid & 7, ng = bid >> 3;
  int wave = threadIdx.x >> 6, lane = threadIdx.x & 63;
  int n = ng * 4 + wave;
  int cg = lane & 15, es = lane >> 4;
  int start = offsets[n];
  int deg = offsets[n + 1] - start;
  int base = head * 128 + cg * 8;
  float acc[8] = {};
  int i = es;
  for (; i + 12 < deg; i += 16) {
    int sp[4]; float a[4];
#pragma unroll
    for (int u = 0; u < 4; ++u) {
      int e = start + i + 4 * u;
      sp[u] = srcs[e];
      a[u] = alpha[(size_t)e * 8 + head];
    }
    f16x8 hv[4];
#pragma unroll
    for (int u = 0; u < 4; ++u)
      hv[u] = *(const f16x8*)&H16[(size_t)sp[u] * 1024 + base];
#pragma unroll
    for (int u = 0; u < 4; ++u)
#pragma unroll
      for (int j = 0; j < 8; ++j)
        acc[j] += a[u] * (float)hv[u][j];
  }
  for (; i < deg; i += 4) {
    int e = start + i;
    int sp = srcs[e];
    float a = alpha[(size_t)e * 8 + head];
    f16x8 hv = *(const f16x8*)&H16[(size_t)sp * 1024 + base];
#pragma unroll
    for (int j = 0; j < 8; ++j)
      acc[j] += a * (float)hv[j];
  }
#pragma unroll
  for (int u = 0; u < 8; ++u) {
    acc[u] += __shfl_xor(acc[u], 16);
    acc[u] += __shfl_xor(acc[u], 32);
  }
  // every lane now holds all 8 channel sums of its cg group; pick pair by es
  float lo = (es & 2) ? ((es & 1) ? acc[6] : acc[4]) : ((es & 1) ? acc[2] : acc[0]);
  float hi = (es & 2) ? ((es & 1) ? acc[7] : acc[5]) : ((es & 1) ? acc[3] : acc[1]);
  int c0 = es * 2;
  float2 b2 = *(const float2*)&bias[base + c0];
  float o0 = gelu_exact(lo + b2.x);
  float o1 = gelu_exact(hi + b2.y);
  *(__half2*)&G[(size_t)n * 1024 + base + c0] = __floats2half2_rn(o0, o1);
}

// ---------------- MFMA proj: G[N,1024] @ W[1024,128] + bias -> C[N,128] ----------------

template <typename OutT>
__global__ __launch_bounds__(256) void proj_mfma(const __half* __restrict__ G,
                                                 const __half* __restrict__ Wt,
                                                 const float* __restrict__ bias,
                                                 OutT* __restrict__ C) {
  int wave = threadIdx.x >> 6, lane = threadIdx.x & 63;
  int r0 = blockIdx.y * 16;
  int c0 = blockIdx.x * 64 + wave * 16;
  int m = lane & 15, quad = lane >> 4;
  const __half* pa = Wt + (size_t)(c0 + m) * 1024 + quad * 8;
  const __half* pb = G + (size_t)(r0 + m) * 1024 + quad * 8;
  f32x4 acc = {0.f, 0.f, 0.f, 0.f};
#pragma unroll 8
  for (int k = 0; k < 1024; k += 32) {
    f16x8 a = *(const f16x8*)(pa + k);
    f16x8 b = *(const f16x8*)(pb + k);
    acc = __builtin_amdgcn_mfma_f32_16x16x32_f16(a, b, acc, 0, 0, 0);
  }
  float4 b4 = *(const float4*)&bias[c0 + quad * 4];
  float v0 = acc[0] + b4.x, v1 = acc[1] + b4.y, v2 = acc[2] + b4.z, v3 = acc[3] + b4.w;
  if constexpr (__is_same(OutT, __half)) {
    Half4 p;
    p.a = __floats2half2_rn(v0, v1);
    p.b = __floats2half2_rn(v2, v3);
    *(Half4*)&C[(size_t)(r0 + m) * 128 + c0 + quad * 4] = p;
  } else {
    *(float4*)&C[(size_t)(r0 + m) * 128 + c0 + quad * 4] = make_float4(v0, v1, v2, v3);
  }
}

// ---------------- orchestration ----------------

extern "C" void kernel_launch(void* const* d_in, const int* in_sizes, int n_in,
                              void* d_out, int out_size, void* d_ws, size_t ws_size,
                              hipStream_t stream) {
  const float* x   = (const float*)d_in[0];
  const int*   ei  = (const int*)d_in[1];
  const float* w1  = (const float*)d_in[2];
  const float* as1 = (const float*)d_in[3];
  const float* ad1 = (const float*)d_in[4];
  const float* b1  = (const float*)d_in[5];
  const float* w2  = (const float*)d_in[6];
  const float* as2 = (const float*)d_in[7];
  const float* ad2 = (const float*)d_in[8];
  const float* b2  = (const float*)d_in[9];
  const float* w3  = (const float*)d_in[10];
  const float* as3 = (const float*)d_in[11];
  const float* ad3 = (const float*)d_in[12];
  const float* b3  = (const float*)d_in[13];
  const float* rw1 = (const float*)d_in[14];
  const float* rb1 = (const float*)d_in[15];
  const float* rw2 = (const float*)d_in[16];
  const float* rb2 = (const float*)d_in[17];
  const float* lw  = (const float*)d_in[18];
  const float* lb  = (const float*)d_in[19];

  int N = in_sizes[0] / 4;
  int E = in_sizes[1] / 2;
  int ET = E + N;
  (void)ws_size;

  char* wsb = (char*)d_ws;
  size_t off = 0;
  auto alloc = [&](size_t bytes) -> void* {
    void* p = wsb + off;
    off += (bytes + 255) & ~(size_t)255;
    return p;
  };
  __half* A16 = (__half*)alloc((size_t)N * 1024 * 2);
  __half* G   = (__half*)alloc((size_t)N * 1024 * 2);
  __half* P16 = (__half*)alloc((size_t)N * 128 * 2);
  __half* wt2 = (__half*)alloc((size_t)1024 * 128 * 2);
  __half* wt3 = (__half*)alloc((size_t)1024 * 128 * 2);
  __half* rwt1 = (__half*)alloc((size_t)128 * 1024 * 2);
  __half* rwt2 = (__half*)alloc((size_t)128 * 1024 * 2);
  __half* lwt  = (__half*)alloc((size_t)128 * 1024 * 2);
  float* ssrc  = (float*)alloc((size_t)N * 8 * 4);
  float* sdst  = (float*)alloc((size_t)N * 8 * 4);
  float* s1part = (float*)alloc((size_t)N * 64 * 4);
  float* s2part = (float*)alloc((size_t)N * 64 * 4);
  float* alpha = (float*)alloc((size_t)ET * 8 * 4);
  int* counts  = (int*)alloc((size_t)N * 4);
  int* offsets = (int*)alloc((size_t)(N + 1) * 4);
  int* cursor  = (int*)alloc((size_t)N * 4);
  int* srcs    = (int*)alloc((size_t)ET * 4);

  dim3 blk(THREADS);

  hipMemsetAsync(counts, 0, (size_t)N * 4, stream);
  hist_kernel<<<dim3((ET + THREADS - 1) / THREADS), blk, 0, stream>>>(ei, E, ET, counts);
  wconv_all_kernel<<<dim3(32, 32, 5), blk, 0, stream>>>(w2, w3, rw1, rw2, lw,
                                                        wt2, wt3, rwt1, rwt2, lwt);
  scan_kernel<<<dim3(1), dim3(1024), 0, stream>>>(counts, offsets, cursor, N);
  scatter_kernel<<<dim3((ET + THREADS - 1) / THREADS), blk, 0, stream>>>(ei, E, ET, cursor, srcs);

  dim3 gRed((N * 8 + THREADS - 1) / THREADS);
  dim3 gAttn(N / 4);
  dim3 gAgg(N * 2);
  dim3 gGemm(16, N / 16);
  dim3 gProj(2, N / 16);

  // ---- layer 1 ----
  feat1_kernel<<<dim3((N * 1024 + THREADS - 1) / THREADS), blk, 0, stream>>>(
      x, w1, as1, ad1, A16, s1part, s2part, N * 1024);
  reduce_scores_kernel<<<gRed, blk, 0, stream>>>(s1part, s2part, ssrc, sdst, 2, N * 8);
  attn_kernel<<<gAttn, blk, 0, stream>>>(srcs, offsets, ssrc, sdst, alpha);
  aggh_kernel<<<gAgg, blk, 0, stream>>>(A16, alpha, offsets, srcs, b1, G);
  proj_mfma<__half><<<gProj, blk, 0, stream>>>(G, rwt1, rb1, P16);

  // ---- layer 2 ----
  gemm128_mfma<<<gGemm, blk, 0, stream>>>(P16, wt2, as2, ad2, A16, s1part, s2part);
  reduce_scores_kernel<<<gRed, blk, 0, stream>>>(s1part, s2part, ssrc, sdst, 8, N * 8);
  attn_kernel<<<gAttn, blk, 0, stream>>>(srcs, offsets, ssrc, sdst, alpha);
  aggh_kernel<<<gAgg, blk, 0, stream>>>(A16, alpha, offsets, srcs, b2, G);
  proj_mfma<__half><<<gProj, blk, 0, stream>>>(G, rwt2, rb2, P16);

  // ---- layer 3 ----
  gemm128_mfma<<<gGemm, blk, 0, stream>>>(P16, wt3, as3, ad3, A16, s1part, s2part);
  reduce_scores_kernel<<<gRed, blk, 0, stream>>>(s1part, s2part, ssrc, sdst, 8, N * 8);
  attn_kernel<<<gAttn, blk, 0, stream>>>(srcs, offsets, ssrc, sdst, alpha);
  aggh_kernel<<<gAgg, blk, 0, stream>>>(A16, alpha, offsets, srcs, b3, G);
  proj_mfma<float><<<gProj, blk, 0, stream>>>(G, lwt, lb, (float*)d_out);
}

// Round 10
// 467.784 us; speedup vs baseline: 1.4311x; 1.1181x over previous
//
#include <hip/hip_runtime.h>
#include <hip/hip_fp16.h>
#include <math.h>

// GAT encoder: N=10000, E=160000 (+N self loops), H=8 heads, C=128, D=1024.
// CSR-by-dst built once. Intermediates fp16. gemm128: row-tile MFMA (16 rows x
// 1024 cols per block), LDS-staged coalesced 2KB row stores, in-register score
// finalization (no partial arrays / reduce pass). Attention softmax wave-per-
// node. Aggregation head-partitioned (blockIdx%8 == head -> XCD-pinned L2
// panel), v_fma_mix inner loop, full-width GELU epilogue.

#define THREADS 256

typedef _Float16 f16x8 __attribute__((ext_vector_type(8)));
typedef float f32x4 __attribute__((ext_vector_type(4)));

struct __align__(8) Half4 { __half2 a, b; };

__device__ __forceinline__ float gelu_exact(float x) {
  return 0.5f * x * (1.0f + erff(x * 0.70710678118654752f));
}

// ---------------- CSR build ----------------

__global__ void hist_kernel(const int* __restrict__ ei, int E, int ET, int* __restrict__ counts) {
  int e = blockIdx.x * THREADS + threadIdx.x;
  if (e >= ET) return;
  int d = (e < E) ? ei[E + e] : (e - E);
  atomicAdd(&counts[d], 1);
}

__global__ __launch_bounds__(1024) void scan_kernel(const int* __restrict__ counts,
                                                    int* __restrict__ offsets,
                                                    int* __restrict__ cursor, int n) {
  __shared__ int sums[1024];
  int t = threadIdx.x;
  int per = (n + 1023) >> 10;
  int start = t * per; if (start > n) start = n;
  int end = start + per; if (end > n) end = n;
  int local = 0;
  for (int i = start; i < end; ++i) local += counts[i];
  sums[t] = local;
  __syncthreads();
  for (int off = 1; off < 1024; off <<= 1) {
    int add = (t >= off) ? sums[t - off] : 0;
    __syncthreads();
    sums[t] += add;
    __syncthreads();
  }
  int run = (t == 0) ? 0 : sums[t - 1];
  for (int i = start; i < end; ++i) {
    offsets[i] = run; cursor[i] = run; run += counts[i];
  }
  if (t == 1023) offsets[n] = run;
}

__global__ void scatter_kernel(const int* __restrict__ ei, int E, int ET,
                               int* __restrict__ cursor, int* __restrict__ srcs) {
  int e = blockIdx.x * THREADS + threadIdx.x;
  if (e >= ET) return;
  int s = (e < E) ? ei[e] : (e - E);
  int d = (e < E) ? ei[E + e] : (e - E);
  int pos = atomicAdd(&cursor[d], 1);
  srcs[pos] = s;
}

// ---------------- batched weight transpose + fp16 convert ----------------

__global__ __launch_bounds__(256) void wconv_all_kernel(
    const float* __restrict__ w2, const float* __restrict__ w3,
    const float* __restrict__ rw1, const float* __restrict__ rw2,
    const float* __restrict__ lw,
    __half* __restrict__ wt2, __half* __restrict__ wt3,
    __half* __restrict__ rwt1, __half* __restrict__ rwt2,
    __half* __restrict__ lwt) {
  const float* in; __half* out; int K, Ncol;
  switch (blockIdx.z) {
    case 0: in = w2;  out = wt2;  K = 128;  Ncol = 1024; break;
    case 1: in = w3;  out = wt3;  K = 128;  Ncol = 1024; break;
    case 2: in = rw1; out = rwt1; K = 1024; Ncol = 128;  break;
    case 3: in = rw2; out = rwt2; K = 1024; Ncol = 128;  break;
    default: in = lw; out = lwt;  K = 1024; Ncol = 128;  break;
  }
  int kb = blockIdx.y * 32, cb = blockIdx.x * 32;
  if (kb >= K || cb >= Ncol) return;
  __shared__ float tile[32][33];
  int t = threadIdx.x;
  int tc = t & 31, tr = t >> 5;
#pragma unroll
  for (int r = tr; r < 32; r += 8)
    tile[r][tc] = in[(size_t)(kb + r) * Ncol + cb + tc];
  __syncthreads();
#pragma unroll
  for (int r = tr; r < 32; r += 8)
    out[(size_t)(cb + r) * K + kb + tc] = __float2half_rn(tile[tc][r]);
}

// ---------------- layer 1: feature transform (K=4) + final scores, block per node ----------------
// 256 threads x 4 channels. Head = t>>5; in-wave 32-lane reduction -> direct ssrc/sdst.

__global__ __launch_bounds__(256) void feat1_kernel(const float* __restrict__ x,
                                                    const float* __restrict__ w,
                                                    const float* __restrict__ as,
                                                    const float* __restrict__ ad,
                                                    __half* __restrict__ out,
                                                    float* __restrict__ ssrc,
                                                    float* __restrict__ sdst) {
  int n = blockIdx.x;
  int t = threadIdx.x;
  int d0 = t * 4;
  float4 xv = *(const float4*)&x[n * 4];
  float4 wa = *(const float4*)&w[d0];
  float4 wb = *(const float4*)&w[1024 + d0];
  float4 wc = *(const float4*)&w[2048 + d0];
  float4 wd = *(const float4*)&w[3072 + d0];
  float v0 = xv.x * wa.x + xv.y * wb.x + xv.z * wc.x + xv.w * wd.x;
  float v1 = xv.x * wa.y + xv.y * wb.y + xv.z * wc.y + xv.w * wd.y;
  float v2 = xv.x * wa.z + xv.y * wb.z + xv.z * wc.z + xv.w * wd.z;
  float v3 = xv.x * wa.w + xv.y * wb.w + xv.z * wc.w + xv.w * wd.w;
  Half4 p;
  p.a = __floats2half2_rn(v0, v1);
  p.b = __floats2half2_rn(v2, v3);
  *(Half4*)&out[(size_t)n * 1024 + d0] = p;
  float4 asv = *(const float4*)&as[d0];
  float4 adv = *(const float4*)&ad[d0];
  float p1 = v0 * asv.x + v1 * asv.y + v2 * asv.z + v3 * asv.w;
  float p2 = v0 * adv.x + v1 * adv.y + v2 * adv.z + v3 * adv.w;
#pragma unroll
  for (int mask = 1; mask <= 16; mask <<= 1) {
    p1 += __shfl_xor(p1, mask);
    p2 += __shfl_xor(p2, mask);
  }
  if ((t & 31) == 0) {
    int head = t >> 5;
    ssrc[n * 8 + head] = p1;
    sdst[n * 8 + head] = p2;
  }
}

// ---------------- row-tile MFMA GEMM: P16[N,128] @ W[128,1024] -> A16 + final scores ----------------
// Block = 16 rows x 1024 cols, 4 waves (wave w -> cols w*256..w*256+255 = heads 2w, 2w+1).
// B-frag (P16 rows) loaded once; 16 col-tiles x 4 MFMAs; results staged in LDS,
// rows written as coalesced 2KB bursts. Scores finalized in-register (each head
// is wholly inside one wave) -> direct ssrc/sdst stores, no partial arrays.

__global__ __launch_bounds__(256) void gemm128_mfma(const __half* __restrict__ P16,
                                                    const __half* __restrict__ Wt,
                                                    const float* __restrict__ as,
                                                    const float* __restrict__ ad,
                                                    __half* __restrict__ A16,
                                                    float* __restrict__ ssrc,
                                                    float* __restrict__ sdst) {
  __shared__ __half tileC[16][1024 + 8];   // +8 halfs pad -> lane stride 2064B, 2-way banks (free)
  int wave = threadIdx.x >> 6, lane = threadIdx.x & 63;
  int r0 = blockIdx.x * 16;
  int m = lane & 15, quad = lane >> 4;
  const __half* pb = P16 + (size_t)(r0 + m) * 128 + quad * 8;
  f16x8 bfrag[4];
#pragma unroll
  for (int kk = 0; kk < 4; ++kk)
    bfrag[kk] = *(const f16x8*)(pb + kk * 32);
  int cbase = wave * 256;
  float s1h[2] = {0.f, 0.f}, s2h[2] = {0.f, 0.f};
#pragma unroll 4
  for (int tile = 0; tile < 16; ++tile) {
    int c0 = cbase + tile * 16;
    const __half* pa = Wt + (size_t)(c0 + m) * 128 + quad * 8;
    f32x4 acc = {0.f, 0.f, 0.f, 0.f};
#pragma unroll
    for (int kk = 0; kk < 4; ++kk) {
      f16x8 a = *(const f16x8*)(pa + kk * 32);
      acc = __builtin_amdgcn_mfma_f32_16x16x32_f16(a, bfrag[kk], acc, 0, 0, 0);
    }
    Half4 p;
    p.a = __floats2half2_rn(acc[0], acc[1]);
    p.b = __floats2half2_rn(acc[2], acc[3]);
    *(Half4*)&tileC[m][c0 + quad * 4] = p;
    float4 asv = *(const float4*)&as[c0 + quad * 4];
    float4 adv = *(const float4*)&ad[c0 + quad * 4];
    int hh = tile >> 3;
    s1h[hh] += acc[0] * asv.x + acc[1] * asv.y + acc[2] * asv.z + acc[3] * asv.w;
    s2h[hh] += acc[0] * adv.x + acc[1] * adv.y + acc[2] * adv.z + acc[3] * adv.w;
  }
#pragma unroll
  for (int hh = 0; hh < 2; ++hh) {
    s1h[hh] += __shfl_xor(s1h[hh], 16); s1h[hh] += __shfl_xor(s1h[hh], 32);
    s2h[hh] += __shfl_xor(s2h[hh], 16); s2h[hh] += __shfl_xor(s2h[hh], 32);
  }
  if (quad == 0) {
    int row = r0 + m;
    int head = wave * 2;
    ssrc[row * 8 + head] = s1h[0];
    ssrc[row * 8 + head + 1] = s1h[1];
    sdst[row * 8 + head] = s2h[0];
    sdst[row * 8 + head + 1] = s2h[1];
  }
  __syncthreads();
  int t = threadIdx.x;
#pragma unroll
  for (int r = 0; r < 16; ++r)
    *(Half4*)&A16[(size_t)(r0 + r) * 1024 + t * 4] = *(Half4*)&tileC[r][t * 4];
}

// ---------------- attention: logits + softmax + normalized alpha (one wave per node) ----------------

__global__ __launch_bounds__(256) void attn_kernel(const int* __restrict__ srcs,
                                                   const int* __restrict__ offsets,
                                                   const float* __restrict__ ssrc,
                                                   const float* __restrict__ sdst,
                                                   float* __restrict__ alpha) {
  int wave = threadIdx.x >> 6, lane = threadIdx.x & 63;
  int n = blockIdx.x * 4 + wave;
  int head = lane & 7, es = lane >> 3;
  int start = offsets[n];
  int deg = offsets[n + 1] - start;
  float sd = sdst[n * 8 + head];
  float m = -1e30f, s = 0.f;
  for (int i = es; i < deg; i += 8) {
    int sp = srcs[start + i];
    float v = ssrc[sp * 8 + head] + sd;
    v = (v > 0.f) ? v : 0.2f * v;
    if (v > m) { s = s * __expf(m - v) + 1.f; m = v; }
    else s += __expf(v - m);
  }
#pragma unroll
  for (int mask = 8; mask <= 32; mask <<= 1) {
    float m2 = __shfl_xor(m, mask);
    float s2 = __shfl_xor(s, mask);
    float M = fmaxf(m, m2);
    s = s * __expf(m - M) + s2 * __expf(m2 - M);
    m = M;
  }
  float zinv = 1.f / s;
  for (int i = es; i < deg; i += 8) {
    int sp = srcs[start + i];
    float v = ssrc[sp * 8 + head] + sd;
    v = (v > 0.f) ? v : 0.2f * v;
    alpha[(size_t)(start + i) * 8 + head] = __expf(v - m) * zinv;
  }
}

// ---------------- head-panel aggregation + bias + GELU (one wave per node) ----------------

__global__ __launch_bounds__(256) void aggh_kernel(const __half* __restrict__ H16,
                                                   const float* __restrict__ alpha,
                                                   const int* __restrict__ offsets,
                                                   const int* __restrict__ srcs,
                                                   const float* __restrict__ bias,
                                                   __half* __restrict__ G) {
  int bid = blockIdx.x;
  int head = bid & 7, ng = bid >> 3;
  int wave = threadIdx.x >> 6, lane = threadIdx.x & 63;
  int n = ng * 4 + wave;
  int cg = lane & 15, es = lane >> 4;
  int start = offsets[n];
  int deg = offsets[n + 1] - start;
  int base = head * 128 + cg * 8;
  float acc[8] = {};
  int i = es;
  for (; i + 12 < deg; i += 16) {
    int sp[4]; float a[4];
#pragma unroll
    for (int u = 0; u < 4; ++u) {
      int e = start + i + 4 * u;
      sp[u] = srcs[e];
      a[u] = alpha[(size_t)e * 8 + head];
    }
    f16x8 hv[4];
#pragma unroll
    for (int u = 0; u < 4; ++u)
      hv[u] = *(const f16x8*)&H16[(size_t)sp[u] * 1024 + base];
#pragma unroll
    for (int u = 0; u < 4; ++u)
#pragma unroll
      for (int j = 0; j < 8; ++j)
        acc[j] += a[u] * (float)hv[u][j];
  }
  for (; i < deg; i += 4) {
    int e = start + i;
    int sp = srcs[e];
    float a = alpha[(size_t)e * 8 + head];
    f16x8 hv = *(const f16x8*)&H16[(size_t)sp * 1024 + base];
#pragma unroll
    for (int j = 0; j < 8; ++j)
      acc[j] += a * (float)hv[j];
  }
#pragma unroll
  for (int u = 0; u < 8; ++u) {
    acc[u] += __shfl_xor(acc[u], 16);
    acc[u] += __shfl_xor(acc[u], 32);
  }
  float lo = (es & 2) ? ((es & 1) ? acc[6] : acc[4]) : ((es & 1) ? acc[2] : acc[0]);
  float hi = (es & 2) ? ((es & 1) ? acc[7] : acc[5]) : ((es & 1) ? acc[3] : acc[1]);
  int c0 = es * 2;
  float2 b2 = *(const float2*)&bias[base + c0];
  float o0 = gelu_exact(lo + b2.x);
  float o1 = gelu_exact(hi + b2.y);
  *(__half2*)&G[(size_t)n * 1024 + base + c0] = __floats2half2_rn(o0, o1);
}

// ---------------- MFMA proj: G[N,1024] @ W[1024,128] + bias -> C[N,128] ----------------

template <typename OutT>
__global__ __launch_bounds__(256) void proj_mfma(const __half* __restrict__ G,
                                                 const __half* __restrict__ Wt,
                                                 const float* __restrict__ bias,
                                                 OutT* __restrict__ C) {
  int wave = threadIdx.x >> 6, lane = threadIdx.x & 63;
  int r0 = blockIdx.y * 16;
  int c0 = blockIdx.x * 64 + wave * 16;
  int m = lane & 15, quad = lane >> 4;
  const __half* pa = Wt + (size_t)(c0 + m) * 1024 + quad * 8;
  const __half* pb = G + (size_t)(r0 + m) * 1024 + quad * 8;
  f32x4 acc = {0.f, 0.f, 0.f, 0.f};
#pragma unroll 8
  for (int k = 0; k < 1024; k += 32) {
    f16x8 a = *(const f16x8*)(pa + k);
    f16x8 b = *(const f16x8*)(pb + k);
    acc = __builtin_amdgcn_mfma_f32_16x16x32_f16(a, b, acc, 0, 0, 0);
  }
  float4 b4 = *(const float4*)&bias[c0 + quad * 4];
  float v0 = acc[0] + b4.x, v1 = acc[1] + b4.y, v2 = acc[2] + b4.z, v3 = acc[3] + b4.w;
  if constexpr (__is_same(OutT, __half)) {
    Half4 p;
    p.a = __floats2half2_rn(v0, v1);
    p.b = __floats2half2_rn(v2, v3);
    *(Half4*)&C[(size_t)(r0 + m) * 128 + c0 + quad * 4] = p;
  } else {
    *(float4*)&C[(size_t)(r0 + m) * 128 + c0 + quad * 4] = make_float4(v0, v1, v2, v3);
  }
}

// ---------------- orchestration ----------------

extern "C" void kernel_launch(void* const* d_in, const int* in_sizes, int n_in,
                              void* d_out, int out_size, void* d_ws, size_t ws_size,
                              hipStream_t stream) {
  const float* x   = (const float*)d_in[0];
  const int*   ei  = (const int*)d_in[1];
  const float* w1  = (const float*)d_in[2];
  const float* as1 = (const float*)d_in[3];
  const float* ad1 = (const float*)d_in[4];
  const float* b1  = (const float*)d_in[5];
  const float* w2  = (const float*)d_in[6];
  const float* as2 = (const float*)d_in[7];
  const float* ad2 = (const float*)d_in[8];
  const float* b2  = (const float*)d_in[9];
  const float* w3  = (const float*)d_in[10];
  const float* as3 = (const float*)d_in[11];
  const float* ad3 = (const float*)d_in[12];
  const float* b3  = (const float*)d_in[13];
  const float* rw1 = (const float*)d_in[14];
  const float* rb1 = (const float*)d_in[15];
  const float* rw2 = (const float*)d_in[16];
  const float* rb2 = (const float*)d_in[17];
  const float* lw  = (const float*)d_in[18];
  const float* lb  = (const float*)d_in[19];

  int N = in_sizes[0] / 4;
  int E = in_sizes[1] / 2;
  int ET = E + N;
  (void)ws_size;

  char* wsb = (char*)d_ws;
  size_t off = 0;
  auto alloc = [&](size_t bytes) -> void* {
    void* p = wsb + off;
    off += (bytes + 255) & ~(size_t)255;
    return p;
  };
  __half* A16 = (__half*)alloc((size_t)N * 1024 * 2);
  __half* G   = (__half*)alloc((size_t)N * 1024 * 2);
  __half* P16 = (__half*)alloc((size_t)N * 128 * 2);
  __half* wt2 = (__half*)alloc((size_t)1024 * 128 * 2);
  __half* wt3 = (__half*)alloc((size_t)1024 * 128 * 2);
  __half* rwt1 = (__half*)alloc((size_t)128 * 1024 * 2);
  __half* rwt2 = (__half*)alloc((size_t)128 * 1024 * 2);
  __half* lwt  = (__half*)alloc((size_t)128 * 1024 * 2);
  float* ssrc  = (float*)alloc((size_t)N * 8 * 4);
  float* sdst  = (float*)alloc((size_t)N * 8 * 4);
  float* alpha = (float*)alloc((size_t)ET * 8 * 4);
  int* counts  = (int*)alloc((size_t)N * 4);
  int* offsets = (int*)alloc((size_t)(N + 1) * 4);
  int* cursor  = (int*)alloc((size_t)N * 4);
  int* srcs    = (int*)alloc((size_t)ET * 4);

  dim3 blk(THREADS);

  hipMemsetAsync(counts, 0, (size_t)N * 4, stream);
  hist_kernel<<<dim3((ET + THREADS - 1) / THREADS), blk, 0, stream>>>(ei, E, ET, counts);
  wconv_all_kernel<<<dim3(32, 32, 5), blk, 0, stream>>>(w2, w3, rw1, rw2, lw,
                                                        wt2, wt3, rwt1, rwt2, lwt);
  scan_kernel<<<dim3(1), dim3(1024), 0, stream>>>(counts, offsets, cursor, N);
  scatter_kernel<<<dim3((ET + THREADS - 1) / THREADS), blk, 0, stream>>>(ei, E, ET, cursor, srcs);

  dim3 gAttn(N / 4);
  dim3 gAgg(N * 2);
  dim3 gGemm(N / 16);
  dim3 gProj(2, N / 16);

  // ---- layer 1 ----
  feat1_kernel<<<dim3(N), blk, 0, stream>>>(x, w1, as1, ad1, A16, ssrc, sdst);
  attn_kernel<<<gAttn, blk, 0, stream>>>(srcs, offsets, ssrc, sdst, alpha);
  aggh_kernel<<<gAgg, blk, 0, stream>>>(A16, alpha, offsets, srcs, b1, G);
  proj_mfma<__half><<<gProj, blk, 0, stream>>>(G, rwt1, rb1, P16);

  // ---- layer 2 ----
  gemm128_mfma<<<gGemm, blk, 0, stream>>>(P16, wt2, as2, ad2, A16, ssrc, sdst);
  attn_kernel<<<gAttn, blk, 0, stream>>>(srcs, offsets, ssrc, sdst, alpha);
  aggh_kernel<<<gAgg, blk, 0, stream>>>(A16, alpha, offsets, srcs, b2, G);
  proj_mfma<__half><<<gProj, blk, 0, stream>>>(G, rwt2, rb2, P16);

  // ---- layer 3 ----
  gemm128_mfma<<<gGemm, blk, 0, stream>>>(P16, wt3, as3, ad3, A16, ssrc, sdst);
  attn_kernel<<<gAttn, blk, 0, stream>>>(srcs, offsets, ssrc, sdst, alpha);
  aggh_kernel<<<gAgg, blk, 0, stream>>>(A16, alpha, offsets, srcs, b3, G);
  proj_mfma<float><<<gProj, blk, 0, stream>>>(G, lwt, lb, (float*)d_out);
}

// Round 11
// 465.593 us; speedup vs baseline: 1.4378x; 1.0047x over previous
//
#include <hip/hip_runtime.h>
#include <hip/hip_fp16.h>
#include <math.h>

// GAT encoder: N=10000, E=160000 (+N self loops), H=8 heads, C=128, D=1024.
// CSR-by-dst built once. Intermediates fp16. Dense GEMMs on matrix cores
// (row-tile, LDS-staged coalesced stores, in-register score finalization).
// Attention: single-pass exp-sum (no max shift -- logits bounded ~1), writes
// head-major edge records {exp(v), src}; normalization deferred to aggregation
// epilogue. Aggregation head-partitioned (blockIdx%8 == head -> XCD-pinned L2
// panel). Aggregation is gathered-bytes-bound (~7.2 TB/s random-gather): fp16
// H is the floor; structure shaping confirmed neutral (R4/R7/R8/R10 all 48.5us).

#define THREADS 256

typedef _Float16 f16x8 __attribute__((ext_vector_type(8)));
typedef float f32x4 __attribute__((ext_vector_type(4)));

struct __align__(8) Half4 { __half2 a, b; };

__device__ __forceinline__ float gelu_exact(float x) {
  return 0.5f * x * (1.0f + erff(x * 0.70710678118654752f));
}

// ---------------- CSR build ----------------

__global__ void hist_kernel(const int* __restrict__ ei, int E, int ET, int* __restrict__ counts) {
  int e = blockIdx.x * THREADS + threadIdx.x;
  if (e >= ET) return;
  int d = (e < E) ? ei[E + e] : (e - E);
  atomicAdd(&counts[d], 1);
}

__global__ __launch_bounds__(1024) void scan_kernel(const int* __restrict__ counts,
                                                    int* __restrict__ offsets,
                                                    int* __restrict__ cursor, int n) {
  __shared__ int sums[1024];
  int t = threadIdx.x;
  int per = (n + 1023) >> 10;
  int start = t * per; if (start > n) start = n;
  int end = start + per; if (end > n) end = n;
  int local = 0;
  for (int i = start; i < end; ++i) local += counts[i];
  sums[t] = local;
  __syncthreads();
  for (int off = 1; off < 1024; off <<= 1) {
    int add = (t >= off) ? sums[t - off] : 0;
    __syncthreads();
    sums[t] += add;
    __syncthreads();
  }
  int run = (t == 0) ? 0 : sums[t - 1];
  for (int i = start; i < end; ++i) {
    offsets[i] = run; cursor[i] = run; run += counts[i];
  }
  if (t == 1023) offsets[n] = run;
}

__global__ void scatter_kernel(const int* __restrict__ ei, int E, int ET,
                               int* __restrict__ cursor, int* __restrict__ srcs) {
  int e = blockIdx.x * THREADS + threadIdx.x;
  if (e >= ET) return;
  int s = (e < E) ? ei[e] : (e - E);
  int d = (e < E) ? ei[E + e] : (e - E);
  int pos = atomicAdd(&cursor[d], 1);
  srcs[pos] = s;
}

// ---------------- batched weight transpose + fp16 convert ----------------

__global__ __launch_bounds__(256) void wconv_all_kernel(
    const float* __restrict__ w2, const float* __restrict__ w3,
    const float* __restrict__ rw1, const float* __restrict__ rw2,
    const float* __restrict__ lw,
    __half* __restrict__ wt2, __half* __restrict__ wt3,
    __half* __restrict__ rwt1, __half* __restrict__ rwt2,
    __half* __restrict__ lwt) {
  const float* in; __half* out; int K, Ncol;
  switch (blockIdx.z) {
    case 0: in = w2;  out = wt2;  K = 128;  Ncol = 1024; break;
    case 1: in = w3;  out = wt3;  K = 128;  Ncol = 1024; break;
    case 2: in = rw1; out = rwt1; K = 1024; Ncol = 128;  break;
    case 3: in = rw2; out = rwt2; K = 1024; Ncol = 128;  break;
    default: in = lw; out = lwt;  K = 1024; Ncol = 128;  break;
  }
  int kb = blockIdx.y * 32, cb = blockIdx.x * 32;
  if (kb >= K || cb >= Ncol) return;
  __shared__ float tile[32][33];
  int t = threadIdx.x;
  int tc = t & 31, tr = t >> 5;
#pragma unroll
  for (int r = tr; r < 32; r += 8)
    tile[r][tc] = in[(size_t)(kb + r) * Ncol + cb + tc];
  __syncthreads();
#pragma unroll
  for (int r = tr; r < 32; r += 8)
    out[(size_t)(cb + r) * K + kb + tc] = __float2half_rn(tile[tc][r]);
}

// ---------------- layer 1: feature transform (K=4) + final scores, block per node ----------------

__global__ __launch_bounds__(256) void feat1_kernel(const float* __restrict__ x,
                                                    const float* __restrict__ w,
                                                    const float* __restrict__ as,
                                                    const float* __restrict__ ad,
                                                    __half* __restrict__ out,
                                                    float* __restrict__ ssrc,
                                                    float* __restrict__ sdst) {
  int n = blockIdx.x;
  int t = threadIdx.x;
  int d0 = t * 4;
  float4 xv = *(const float4*)&x[n * 4];
  float4 wa = *(const float4*)&w[d0];
  float4 wb = *(const float4*)&w[1024 + d0];
  float4 wc = *(const float4*)&w[2048 + d0];
  float4 wd = *(const float4*)&w[3072 + d0];
  float v0 = xv.x * wa.x + xv.y * wb.x + xv.z * wc.x + xv.w * wd.x;
  float v1 = xv.x * wa.y + xv.y * wb.y + xv.z * wc.y + xv.w * wd.y;
  float v2 = xv.x * wa.z + xv.y * wb.z + xv.z * wc.z + xv.w * wd.z;
  float v3 = xv.x * wa.w + xv.y * wb.w + xv.z * wc.w + xv.w * wd.w;
  Half4 p;
  p.a = __floats2half2_rn(v0, v1);
  p.b = __floats2half2_rn(v2, v3);
  *(Half4*)&out[(size_t)n * 1024 + d0] = p;
  float4 asv = *(const float4*)&as[d0];
  float4 adv = *(const float4*)&ad[d0];
  float p1 = v0 * asv.x + v1 * asv.y + v2 * asv.z + v3 * asv.w;
  float p2 = v0 * adv.x + v1 * adv.y + v2 * adv.z + v3 * adv.w;
#pragma unroll
  for (int mask = 1; mask <= 16; mask <<= 1) {
    p1 += __shfl_xor(p1, mask);
    p2 += __shfl_xor(p2, mask);
  }
  if ((t & 31) == 0) {
    int head = t >> 5;
    ssrc[n * 8 + head] = p1;
    sdst[n * 8 + head] = p2;
  }
}

// ---------------- row-tile MFMA GEMM: P16[N,128] @ W[128,1024] -> A16 + final scores ----------------

__global__ __launch_bounds__(256) void gemm128_mfma(const __half* __restrict__ P16,
                                                    const __half* __restrict__ Wt,
                                                    const float* __restrict__ as,
                                                    const float* __restrict__ ad,
                                                    __half* __restrict__ A16,
                                                    float* __restrict__ ssrc,
                                                    float* __restrict__ sdst) {
  __shared__ __half tileC[16][1024 + 8];
  int wave = threadIdx.x >> 6, lane = threadIdx.x & 63;
  int r0 = blockIdx.x * 16;
  int m = lane & 15, quad = lane >> 4;
  const __half* pb = P16 + (size_t)(r0 + m) * 128 + quad * 8;
  f16x8 bfrag[4];
#pragma unroll
  for (int kk = 0; kk < 4; ++kk)
    bfrag[kk] = *(const f16x8*)(pb + kk * 32);
  int cbase = wave * 256;
  float s1h[2] = {0.f, 0.f}, s2h[2] = {0.f, 0.f};
#pragma unroll 4
  for (int tile = 0; tile < 16; ++tile) {
    int c0 = cbase + tile * 16;
    const __half* pa = Wt + (size_t)(c0 + m) * 128 + quad * 8;
    f32x4 acc = {0.f, 0.f, 0.f, 0.f};
#pragma unroll
    for (int kk = 0; kk < 4; ++kk) {
      f16x8 a = *(const f16x8*)(pa + kk * 32);
      acc = __builtin_amdgcn_mfma_f32_16x16x32_f16(a, bfrag[kk], acc, 0, 0, 0);
    }
    Half4 p;
    p.a = __floats2half2_rn(acc[0], acc[1]);
    p.b = __floats2half2_rn(acc[2], acc[3]);
    *(Half4*)&tileC[m][c0 + quad * 4] = p;
    float4 asv = *(const float4*)&as[c0 + quad * 4];
    float4 adv = *(const float4*)&ad[c0 + quad * 4];
    int hh = tile >> 3;
    s1h[hh] += acc[0] * asv.x + acc[1] * asv.y + acc[2] * asv.z + acc[3] * asv.w;
    s2h[hh] += acc[0] * adv.x + acc[1] * adv.y + acc[2] * adv.z + acc[3] * adv.w;
  }
#pragma unroll
  for (int hh = 0; hh < 2; ++hh) {
    s1h[hh] += __shfl_xor(s1h[hh], 16); s1h[hh] += __shfl_xor(s1h[hh], 32);
    s2h[hh] += __shfl_xor(s2h[hh], 16); s2h[hh] += __shfl_xor(s2h[hh], 32);
  }
  if (quad == 0) {
    int row = r0 + m;
    int head = wave * 2;
    ssrc[row * 8 + head] = s1h[0];
    ssrc[row * 8 + head + 1] = s1h[1];
    sdst[row * 8 + head] = s2h[0];
    sdst[row * 8 + head + 1] = s2h[1];
  }
  __syncthreads();
  int t = threadIdx.x;
#pragma unroll
  for (int r = 0; r < 16; ++r)
    *(Half4*)&A16[(size_t)(r0 + r) * 1024 + t * 4] = *(Half4*)&tileC[r][t * 4];
}

// ---------------- attention: single-pass exp-sum -> head-major edge records ----------------
// Wave per node; lane&7 = head, lane>>3 = edge sublane. Logits bounded (~|1|):
// exp without max-shift is exact up to fp rounding. er[head][pos] = {exp(v), src};
// zinv[n*8+head] = 1/sum. Normalization applied in aggh epilogue.

__global__ __launch_bounds__(256) void attn_kernel(const int* __restrict__ srcs,
                                                   const int* __restrict__ offsets,
                                                   const float* __restrict__ ssrc,
                                                   const float* __restrict__ sdst,
                                                   float2* __restrict__ er,
                                                   float* __restrict__ zinv, int ET) {
  int wave = threadIdx.x >> 6, lane = threadIdx.x & 63;
  int n = blockIdx.x * 4 + wave;
  int head = lane & 7, es = lane >> 3;
  int start = offsets[n];
  int deg = offsets[n + 1] - start;
  float sd = sdst[n * 8 + head];
  float2* erh = er + (size_t)head * ET;
  float s = 0.f;
  for (int i = es; i < deg; i += 8) {
    int sp = srcs[start + i];
    float v = ssrc[sp * 8 + head] + sd;
    v = (v > 0.f) ? v : 0.2f * v;
    float e = __expf(v);
    erh[start + i] = make_float2(e, __int_as_float(sp));
    s += e;
  }
#pragma unroll
  for (int mask = 8; mask <= 32; mask <<= 1)
    s += __shfl_xor(s, mask);
  if (es == 0) zinv[n * 8 + head] = 1.f / s;
}

// ---------------- head-panel aggregation + zinv + bias + GELU (one wave per node) ----------------
// bid&7 = head (XCD-pinned panel); cg = lane&15 (8 ch, 16 B), es = lane>>4.
// er record = one 8B broadcast load (replaces srcs + strided alpha gather).

__global__ __launch_bounds__(256) void aggh_kernel(const __half* __restrict__ H16,
                                                   const float2* __restrict__ er,
                                                   const float* __restrict__ zinv,
                                                   const int* __restrict__ offsets,
                                                   const float* __restrict__ bias,
                                                   __half* __restrict__ G, int ET) {
  int bid = blockIdx.x;
  int head = bid & 7, ng = bid >> 3;
  int wave = threadIdx.x >> 6, lane = threadIdx.x & 63;
  int n = ng * 4 + wave;
  int cg = lane & 15, es = lane >> 4;
  int start = offsets[n];
  int deg = offsets[n + 1] - start;
  const float2* erh = er + (size_t)head * ET + start;
  int base = head * 128 + cg * 8;
  float zi = zinv[n * 8 + head];
  float acc[8] = {};
  int i = es;
  for (; i + 12 < deg; i += 16) {
    float2 rec[4];
#pragma unroll
    for (int u = 0; u < 4; ++u)
      rec[u] = erh[i + 4 * u];
    f16x8 hv[4];
#pragma unroll
    for (int u = 0; u < 4; ++u)
      hv[u] = *(const f16x8*)&H16[(size_t)__float_as_int(rec[u].y) * 1024 + base];
#pragma unroll
    for (int u = 0; u < 4; ++u)
#pragma unroll
      for (int j = 0; j < 8; ++j)
        acc[j] += rec[u].x * (float)hv[u][j];
  }
  for (; i < deg; i += 4) {
    float2 rec = erh[i];
    f16x8 hv = *(const f16x8*)&H16[(size_t)__float_as_int(rec.y) * 1024 + base];
#pragma unroll
    for (int j = 0; j < 8; ++j)
      acc[j] += rec.x * (float)hv[j];
  }
#pragma unroll
  for (int u = 0; u < 8; ++u) {
    acc[u] += __shfl_xor(acc[u], 16);
    acc[u] += __shfl_xor(acc[u], 32);
  }
  float lo = (es & 2) ? ((es & 1) ? acc[6] : acc[4]) : ((es & 1) ? acc[2] : acc[0]);
  float hi = (es & 2) ? ((es & 1) ? acc[7] : acc[5]) : ((es & 1) ? acc[3] : acc[1]);
  int c0 = es * 2;
  float2 b2 = *(const float2*)&bias[base + c0];
  float o0 = gelu_exact(lo * zi + b2.x);
  float o1 = gelu_exact(hi * zi + b2.y);
  *(__half2*)&G[(size_t)n * 1024 + base + c0] = __floats2half2_rn(o0, o1);
}

// ---------------- MFMA proj: G[N,1024] @ W[1024,128] + bias -> C[N,128] ----------------

template <typename OutT>
__global__ __launch_bounds__(256) void proj_mfma(const __half* __restrict__ G,
                                                 const __half* __restrict__ Wt,
                                                 const float* __restrict__ bias,
                                                 OutT* __restrict__ C) {
  int wave = threadIdx.x >> 6, lane = threadIdx.x & 63;
  int r0 = blockIdx.y * 16;
  int c0 = blockIdx.x * 64 + wave * 16;
  int m = lane & 15, quad = lane >> 4;
  const __half* pa = Wt + (size_t)(c0 + m) * 1024 + quad * 8;
  const __half* pb = G + (size_t)(r0 + m) * 1024 + quad * 8;
  f32x4 acc = {0.f, 0.f, 0.f, 0.f};
#pragma unroll 8
  for (int k = 0; k < 1024; k += 32) {
    f16x8 a = *(const f16x8*)(pa + k);
    f16x8 b = *(const f16x8*)(pb + k);
    acc = __builtin_amdgcn_mfma_f32_16x16x32_f16(a, b, acc, 0, 0, 0);
  }
  float4 b4 = *(const float4*)&bias[c0 + quad * 4];
  float v0 = acc[0] + b4.x, v1 = acc[1] + b4.y, v2 = acc[2] + b4.z, v3 = acc[3] + b4.w;
  if constexpr (__is_same(OutT, __half)) {
    Half4 p;
    p.a = __floats2half2_rn(v0, v1);
    p.b = __floats2half2_rn(v2, v3);
    *(Half4*)&C[(size_t)(r0 + m) * 128 + c0 + quad * 4] = p;
  } else {
    *(float4*)&C[(size_t)(r0 + m) * 128 + c0 + quad * 4] = make_float4(v0, v1, v2, v3);
  }
}

// ---------------- orchestration ----------------

extern "C" void kernel_launch(void* const* d_in, const int* in_sizes, int n_in,
                              void* d_out, int out_size, void* d_ws, size_t ws_size,
                              hipStream_t stream) {
  const float* x   = (const float*)d_in[0];
  const int*   ei  = (const int*)d_in[1];
  const float* w1  = (const float*)d_in[2];
  const float* as1 = (const float*)d_in[3];
  const float* ad1 = (const float*)d_in[4];
  const float* b1  = (const float*)d_in[5];
  const float* w2  = (const float*)d_in[6];
  const float* as2 = (const float*)d_in[7];
  const float* ad2 = (const float*)d_in[8];
  const float* b2  = (const float*)d_in[9];
  const float* w3  = (const float*)d_in[10];
  const float* as3 = (const float*)d_in[11];
  const float* ad3 = (const float*)d_in[12];
  const float* b3  = (const float*)d_in[13];
  const float* rw1 = (const float*)d_in[14];
  const float* rb1 = (const float*)d_in[15];
  const float* rw2 = (const float*)d_in[16];
  const float* rb2 = (const float*)d_in[17];
  const float* lw  = (const float*)d_in[18];
  const float* lb  = (const float*)d_in[19];

  int N = in_sizes[0] / 4;
  int E = in_sizes[1] / 2;
  int ET = E + N;
  (void)ws_size;

  char* wsb = (char*)d_ws;
  size_t off = 0;
  auto alloc = [&](size_t bytes) -> void* {
    void* p = wsb + off;
    off += (bytes + 255) & ~(size_t)255;
    return p;
  };
  __half* A16 = (__half*)alloc((size_t)N * 1024 * 2);
  __half* G   = (__half*)alloc((size_t)N * 1024 * 2);
  __half* P16 = (__half*)alloc((size_t)N * 128 * 2);
  __half* wt2 = (__half*)alloc((size_t)1024 * 128 * 2);
  __half* wt3 = (__half*)alloc((size_t)1024 * 128 * 2);
  __half* rwt1 = (__half*)alloc((size_t)128 * 1024 * 2);
  __half* rwt2 = (__half*)alloc((size_t)128 * 1024 * 2);
  __half* lwt  = (__half*)alloc((size_t)128 * 1024 * 2);
  float* ssrc  = (float*)alloc((size_t)N * 8 * 4);
  float* sdst  = (float*)alloc((size_t)N * 8 * 4);
  float* zinv  = (float*)alloc((size_t)N * 8 * 4);
  float2* er   = (float2*)alloc((size_t)ET * 8 * 8);
  int* counts  = (int*)alloc((size_t)N * 4);
  int* offsets = (int*)alloc((size_t)(N + 1) * 4);
  int* cursor  = (int*)alloc((size_t)N * 4);
  int* srcs    = (int*)alloc((size_t)ET * 4);

  dim3 blk(THREADS);

  hipMemsetAsync(counts, 0, (size_t)N * 4, stream);
  hist_kernel<<<dim3((ET + THREADS - 1) / THREADS), blk, 0, stream>>>(ei, E, ET, counts);
  wconv_all_kernel<<<dim3(32, 32, 5), blk, 0, stream>>>(w2, w3, rw1, rw2, lw,
                                                        wt2, wt3, rwt1, rwt2, lwt);
  scan_kernel<<<dim3(1), dim3(1024), 0, stream>>>(counts, offsets, cursor, N);
  scatter_kernel<<<dim3((ET + THREADS - 1) / THREADS), blk, 0, stream>>>(ei, E, ET, cursor, srcs);

  dim3 gAttn(N / 4);
  dim3 gAgg(N * 2);
  dim3 gGemm(N / 16);
  dim3 gProj(2, N / 16);

  // ---- layer 1 ----
  feat1_kernel<<<dim3(N), blk, 0, stream>>>(x, w1, as1, ad1, A16, ssrc, sdst);
  attn_kernel<<<gAttn, blk, 0, stream>>>(srcs, offsets, ssrc, sdst, er, zinv, ET);
  aggh_kernel<<<gAgg, blk, 0, stream>>>(A16, er, zinv, offsets, b1, G, ET);
  proj_mfma<__half><<<gProj, blk, 0, stream>>>(G, rwt1, rb1, P16);

  // ---- layer 2 ----
  gemm128_mfma<<<gGemm, blk, 0, stream>>>(P16, wt2, as2, ad2, A16, ssrc, sdst);
  attn_kernel<<<gAttn, blk, 0, stream>>>(srcs, offsets, ssrc, sdst, er, zinv, ET);
  aggh_kernel<<<gAgg, blk, 0, stream>>>(A16, er, zinv, offsets, b2, G, ET);
  proj_mfma<__half><<<gProj, blk, 0, stream>>>(G, rwt2, rb2, P16);

  // ---- layer 3 ----
  gemm128_mfma<<<gGemm, blk, 0, stream>>>(P16, wt3, as3, ad3, A16, ssrc, sdst);
  attn_kernel<<<gAttn, blk, 0, stream>>>(srcs, offsets, ssrc, sdst, er, zinv, ET);
  aggh_kernel<<<gAgg, blk, 0, stream>>>(A16, er, zinv, offsets, b3, G, ET);
  proj_mfma<float><<<gProj, blk, 0, stream>>>(G, lwt, lb, (float*)d_out);
}

// Round 12
// 426.560 us; speedup vs baseline: 1.5694x; 1.0915x over previous
//
#include <hip/hip_runtime.h>
#include <hip/hip_fp16.h>
#include <math.h>

// GAT encoder: N=10000, E=160000 (+N self loops), H=8 heads, C=128, D=1024.
// KEY RESTRUCTURE (R11): aggregation commutes with the feature transform:
//   out[d,hblk] = (sum_s alpha_{s,h} P[s]) @ W[:,hblk]
// so we gather 128-dim P rows ONCE per edge (256 B) instead of 1024-dim h per
// head (8x less gather: 348 MB -> 43.5 MB/layer), and apply W afterwards as 8
// per-head MFMA GEMMs (hgemm, same FLOPs the old gemm128 had). Scores use
// ws[h] = W[:,hblk] @ a_s[h] so h is never materialized. Layer 1 aggregates
// raw x (16 B/edge). Softmax without max-shift (logits bounded ~|1|).

#define THREADS 256

typedef _Float16 f16x8 __attribute__((ext_vector_type(8)));
typedef float f32x4 __attribute__((ext_vector_type(4)));

struct __align__(8) Half4 { __half2 a, b; };

__device__ __forceinline__ float gelu_exact(float x) {
  return 0.5f * x * (1.0f + erff(x * 0.70710678118654752f));
}

// ---------------- CSR build ----------------

__global__ void hist_kernel(const int* __restrict__ ei, int E, int ET, int* __restrict__ counts) {
  int e = blockIdx.x * THREADS + threadIdx.x;
  if (e >= ET) return;
  int d = (e < E) ? ei[E + e] : (e - E);
  atomicAdd(&counts[d], 1);
}

__global__ __launch_bounds__(1024) void scan_kernel(const int* __restrict__ counts,
                                                    int* __restrict__ offsets,
                                                    int* __restrict__ cursor, int n) {
  __shared__ int sums[1024];
  int t = threadIdx.x;
  int per = (n + 1023) >> 10;
  int start = t * per; if (start > n) start = n;
  int end = start + per; if (end > n) end = n;
  int local = 0;
  for (int i = start; i < end; ++i) local += counts[i];
  sums[t] = local;
  __syncthreads();
  for (int off = 1; off < 1024; off <<= 1) {
    int add = (t >= off) ? sums[t - off] : 0;
    __syncthreads();
    sums[t] += add;
    __syncthreads();
  }
  int run = (t == 0) ? 0 : sums[t - 1];
  for (int i = start; i < end; ++i) {
    offsets[i] = run; cursor[i] = run; run += counts[i];
  }
  if (t == 1023) offsets[n] = run;
}

__global__ void scatter_kernel(const int* __restrict__ ei, int E, int ET,
                               int* __restrict__ cursor, int* __restrict__ srcs) {
  int e = blockIdx.x * THREADS + threadIdx.x;
  if (e >= ET) return;
  int s = (e < E) ? ei[e] : (e - E);
  int d = (e < E) ? ei[E + e] : (e - E);
  int pos = atomicAdd(&cursor[d], 1);
  srcs[pos] = s;
}

// ---------------- batched weight transpose + fp16 convert ----------------

__global__ __launch_bounds__(256) void wconv_all_kernel(
    const float* __restrict__ w2, const float* __restrict__ w3,
    const float* __restrict__ rw1, const float* __restrict__ rw2,
    const float* __restrict__ lw,
    __half* __restrict__ wt2, __half* __restrict__ wt3,
    __half* __restrict__ rwt1, __half* __restrict__ rwt2,
    __half* __restrict__ lwt) {
  const float* in; __half* out; int K, Ncol;
  switch (blockIdx.z) {
    case 0: in = w2;  out = wt2;  K = 128;  Ncol = 1024; break;
    case 1: in = w3;  out = wt3;  K = 128;  Ncol = 1024; break;
    case 2: in = rw1; out = rwt1; K = 1024; Ncol = 128;  break;
    case 3: in = rw2; out = rwt2; K = 1024; Ncol = 128;  break;
    default: in = lw; out = lwt;  K = 1024; Ncol = 128;  break;
  }
  int kb = blockIdx.y * 32, cb = blockIdx.x * 32;
  if (kb >= K || cb >= Ncol) return;
  __shared__ float tile[32][33];
  int t = threadIdx.x;
  int tc = t & 31, tr = t >> 5;
#pragma unroll
  for (int r = tr; r < 32; r += 8)
    tile[r][tc] = in[(size_t)(kb + r) * Ncol + cb + tc];
  __syncthreads();
#pragma unroll
  for (int r = tr; r < 32; r += 8)
    out[(size_t)(cb + r) * K + kb + tc] = __float2half_rn(tile[tc][r]);
}

// ---------------- score-vector precompute: ws[h][k] = sum_c W[k][h*128+c]*a[h][c] ----------------

__global__ __launch_bounds__(256) void sconv_kernel(
    const float* __restrict__ w1, const float* __restrict__ as1, const float* __restrict__ ad1,
    const float* __restrict__ w2, const float* __restrict__ as2, const float* __restrict__ ad2,
    const float* __restrict__ w3, const float* __restrict__ as3, const float* __restrict__ ad3,
    float* __restrict__ ws1, float* __restrict__ wd1,
    float* __restrict__ ws2, float* __restrict__ wd2,
    float* __restrict__ ws3, float* __restrict__ wd3) {
  int h = blockIdx.x;
  int t = threadIdx.x;
  int sel = t >> 7;      // 0 -> ws, 1 -> wd
  int k = t & 127;
  const float* W; const float* av; float* out; int K;
  switch (blockIdx.y) {
    case 0: W = w2; av = sel ? ad2 : as2; out = sel ? wd2 : ws2; K = 128; break;
    case 1: W = w3; av = sel ? ad3 : as3; out = sel ? wd3 : ws3; K = 128; break;
    default: W = w1; av = sel ? ad1 : as1; out = sel ? wd1 : ws1; K = 4; break;
  }
  if (k >= K) return;
  const float* wrow = W + (size_t)k * 1024 + h * 128;
  const float* arow = av + h * 128;
  float s = 0.f;
  for (int c = 0; c < 128; c += 4) {
    float4 wv = *(const float4*)&wrow[c];
    float4 a4 = *(const float4*)&arow[c];
    s += wv.x * a4.x + wv.y * a4.y + wv.z * a4.z + wv.w * a4.w;
  }
  out[h * K + k] = s;
}

// ---------------- layer-1 scores: s[n,h] = x[n](4) . ws1[h](4) ----------------

__global__ void scoresX_kernel(const float* __restrict__ x,
                               const float* __restrict__ ws1, const float* __restrict__ wd1,
                               float* __restrict__ ssrc, float* __restrict__ sdst, int total) {
  int idx = blockIdx.x * THREADS + threadIdx.x;
  if (idx >= total) return;
  int n = idx >> 3, h = idx & 7;
  float4 xv = *(const float4*)&x[n * 4];
  float4 a = *(const float4*)&ws1[h * 4];
  float4 b = *(const float4*)&wd1[h * 4];
  ssrc[idx] = xv.x * a.x + xv.y * a.y + xv.z * a.z + xv.w * a.w;
  sdst[idx] = xv.x * b.x + xv.y * b.y + xv.z * b.z + xv.w * b.w;
}

// ---------------- layer-2/3 scores: s[n,h] = P16[n](128) . ws[h](128), wave per node ----------------

__global__ __launch_bounds__(256) void scoresP_kernel(const __half* __restrict__ P16,
                                                      const float* __restrict__ ws,
                                                      const float* __restrict__ wd,
                                                      float* __restrict__ ssrc,
                                                      float* __restrict__ sdst) {
  int wave = threadIdx.x >> 6, lane = threadIdx.x & 63;
  int n = blockIdx.x * 4 + wave;
  int head = lane & 7, es = lane >> 3;
  const __half* pp = P16 + (size_t)n * 128 + es * 16;
  f16x8 p0 = *(const f16x8*)pp;
  f16x8 p1 = *(const f16x8*)(pp + 8);
  const float* wsp = ws + head * 128 + es * 16;
  const float* wdp = wd + head * 128 + es * 16;
  float s1 = 0.f, s2 = 0.f;
#pragma unroll
  for (int j = 0; j < 8; ++j) {
    s1 += (float)p0[j] * wsp[j];
    s2 += (float)p0[j] * wdp[j];
  }
#pragma unroll
  for (int j = 0; j < 8; ++j) {
    s1 += (float)p1[j] * wsp[8 + j];
    s2 += (float)p1[j] * wdp[8 + j];
  }
#pragma unroll
  for (int mask = 8; mask <= 32; mask <<= 1) {
    s1 += __shfl_xor(s1, mask);
    s2 += __shfl_xor(s2, mask);
  }
  if (es == 0) { ssrc[n * 8 + head] = s1; sdst[n * 8 + head] = s2; }
}

// ---------------- attention: single-pass exp-sum -> alpha8[pos][8] + zinv ----------------

__global__ __launch_bounds__(256) void attn_kernel(const int* __restrict__ srcs,
                                                   const int* __restrict__ offsets,
                                                   const float* __restrict__ ssrc,
                                                   const float* __restrict__ sdst,
                                                   float* __restrict__ alpha8,
                                                   float* __restrict__ zinv) {
  int wave = threadIdx.x >> 6, lane = threadIdx.x & 63;
  int n = blockIdx.x * 4 + wave;
  int head = lane & 7, es = lane >> 3;
  int start = offsets[n];
  int deg = offsets[n + 1] - start;
  float sd = sdst[n * 8 + head];
  float s = 0.f;
  for (int i = es; i < deg; i += 8) {
    int sp = srcs[start + i];
    float v = ssrc[sp * 8 + head] + sd;
    v = (v > 0.f) ? v : 0.2f * v;
    float e = __expf(v);
    alpha8[(size_t)(start + i) * 8 + head] = e;
    s += e;
  }
#pragma unroll
  for (int mask = 8; mask <= 32; mask <<= 1)
    s += __shfl_xor(s, mask);
  if (es == 0) zinv[n * 8 + head] = 1.f / s;
}

// ---------------- layer-1 aggregation: y1[h][n][4] = zinv * sum_e alpha*x[src] ----------------
// Wave per node: lane = (eo<<5) | (h<<2) | ch  (2 edge sublanes x 8 heads x 4 ch).

__global__ __launch_bounds__(256) void aggX_kernel(const float* __restrict__ x,
                                                   const float* __restrict__ alpha8,
                                                   const int* __restrict__ offsets,
                                                   const int* __restrict__ srcs,
                                                   const float* __restrict__ zinv,
                                                   float* __restrict__ Y1, int N) {
  int wave = threadIdx.x >> 6, lane = threadIdx.x & 63;
  int n = blockIdx.x * 4 + wave;
  int h = (lane >> 2) & 7, ch = lane & 3, eo = lane >> 5;
  int start = offsets[n];
  int deg = offsets[n + 1] - start;
  float acc = 0.f;
  for (int i = eo; i < deg; i += 2) {
    int sp = srcs[start + i];
    float a = alpha8[(size_t)(start + i) * 8 + h];
    acc += a * x[sp * 4 + ch];
  }
  acc += __shfl_xor(acc, 32);
  if (lane < 32) {
    float zi = zinv[n * 8 + h];
    Y1[((size_t)h * N + n) * 4 + ch] = acc * zi;
  }
}

// ---------------- layer-1 feature transform of aggregated x: G = gelu(Y1@w1 + b) ----------------

__global__ void hgemm1_kernel(const float* __restrict__ Y1, const float* __restrict__ w,
                              const float* __restrict__ bias, __half* __restrict__ G,
                              int N, int total) {
  int idx = blockIdx.x * THREADS + threadIdx.x;
  if (idx >= total) return;   // total = N*256
  int n = idx >> 8, c0 = (idx & 255) * 4;
  int h = c0 >> 7;
  float4 yv = *(const float4*)&Y1[((size_t)h * N + n) * 4];
  float4 wa = *(const float4*)&w[c0];
  float4 wb = *(const float4*)&w[1024 + c0];
  float4 wc = *(const float4*)&w[2048 + c0];
  float4 wd = *(const float4*)&w[3072 + c0];
  float4 b4 = *(const float4*)&bias[c0];
  float o0 = gelu_exact(yv.x * wa.x + yv.y * wb.x + yv.z * wc.x + yv.w * wd.x + b4.x);
  float o1 = gelu_exact(yv.x * wa.y + yv.y * wb.y + yv.z * wc.y + yv.w * wd.y + b4.y);
  float o2 = gelu_exact(yv.x * wa.z + yv.y * wb.z + yv.z * wc.z + yv.w * wd.z + b4.z);
  float o3 = gelu_exact(yv.x * wa.w + yv.y * wb.w + yv.z * wc.w + yv.w * wd.w + b4.w);
  Half4 p;
  p.a = __floats2half2_rn(o0, o1);
  p.b = __floats2half2_rn(o2, o3);
  *(Half4*)&G[(size_t)n * 1024 + c0] = p;
}

// ---------------- layer-2/3 aggregation: Y16[h][n][128] = zinv * sum_e alpha*P16[src] ----------------
// Wave per node; lane = channel pair (64 x 2 = 128 ch). 256 B gather per edge TOTAL.

__global__ __launch_bounds__(256) void aggP_kernel(const __half* __restrict__ P16,
                                                   const float* __restrict__ alpha8,
                                                   const int* __restrict__ offsets,
                                                   const int* __restrict__ srcs,
                                                   const float* __restrict__ zinv,
                                                   __half* __restrict__ Y16, int N) {
  int wave = threadIdx.x >> 6, lane = threadIdx.x & 63;
  int n = blockIdx.x * 4 + wave;
  int start = offsets[n];
  int deg = offsets[n + 1] - start;
  int c2 = lane * 2;
  float accx[8] = {}, accy[8] = {};
  int i = 0;
  for (; i + 1 < deg; i += 2) {
    int e0 = start + i, e1 = e0 + 1;
    int sp0 = srcs[e0], sp1 = srcs[e1];
    float4 a00 = *(const float4*)&alpha8[(size_t)e0 * 8];
    float4 a01 = *(const float4*)&alpha8[(size_t)e0 * 8 + 4];
    float4 a10 = *(const float4*)&alpha8[(size_t)e1 * 8];
    float4 a11 = *(const float4*)&alpha8[(size_t)e1 * 8 + 4];
    float2 p0 = __half22float2(*(const __half2*)&P16[(size_t)sp0 * 128 + c2]);
    float2 p1 = __half22float2(*(const __half2*)&P16[(size_t)sp1 * 128 + c2]);
    float a0[8] = {a00.x, a00.y, a00.z, a00.w, a01.x, a01.y, a01.z, a01.w};
    float a1[8] = {a10.x, a10.y, a10.z, a10.w, a11.x, a11.y, a11.z, a11.w};
#pragma unroll
    for (int h = 0; h < 8; ++h) {
      accx[h] += a0[h] * p0.x; accy[h] += a0[h] * p0.y;
      accx[h] += a1[h] * p1.x; accy[h] += a1[h] * p1.y;
    }
  }
  if (i < deg) {
    int e0 = start + i;
    int sp0 = srcs[e0];
    float4 a00 = *(const float4*)&alpha8[(size_t)e0 * 8];
    float4 a01 = *(const float4*)&alpha8[(size_t)e0 * 8 + 4];
    float2 p0 = __half22float2(*(const __half2*)&P16[(size_t)sp0 * 128 + c2]);
    float a0[8] = {a00.x, a00.y, a00.z, a00.w, a01.x, a01.y, a01.z, a01.w};
#pragma unroll
    for (int h = 0; h < 8; ++h) {
      accx[h] += a0[h] * p0.x; accy[h] += a0[h] * p0.y;
    }
  }
#pragma unroll
  for (int h = 0; h < 8; ++h) {
    float zi = zinv[n * 8 + h];
    *(__half2*)&Y16[((size_t)h * N + n) * 128 + c2] =
        __floats2half2_rn(accx[h] * zi, accy[h] * zi);
  }
}

// ---------------- per-head MFMA: G[:, hblk] = gelu(Y16[h] @ W[:, hblk] + b) ----------------
// Block = 16 rows x one head's 128 cols; Wt[col][k] (K=128). LDS-staged coalesced store.

__global__ __launch_bounds__(256) void hgemm_kernel(const __half* __restrict__ Y16,
                                                    const __half* __restrict__ Wt,
                                                    const float* __restrict__ bias,
                                                    __half* __restrict__ G, int N) {
  __shared__ __half Gt[16][136];
  int h = blockIdx.x;
  int r0 = blockIdx.y * 16;
  int wave = threadIdx.x >> 6, lane = threadIdx.x & 63;
  int m = lane & 15, quad = lane >> 4;
  const __half* py = Y16 + ((size_t)h * N + r0 + m) * 128 + quad * 8;
  f16x8 bfrag[4];
#pragma unroll
  for (int kk = 0; kk < 4; ++kk)
    bfrag[kk] = *(const f16x8*)(py + kk * 32);
#pragma unroll
  for (int tile = 0; tile < 2; ++tile) {
    int cl = wave * 32 + tile * 16;
    int gc = h * 128 + cl;
    const __half* pa = Wt + (size_t)(gc + m) * 128 + quad * 8;
    f32x4 acc = {0.f, 0.f, 0.f, 0.f};
#pragma unroll
    for (int kk = 0; kk < 4; ++kk) {
      f16x8 a = *(const f16x8*)(pa + kk * 32);
      acc = __builtin_amdgcn_mfma_f32_16x16x32_f16(a, bfrag[kk], acc, 0, 0, 0);
    }
    float4 b4 = *(const float4*)&bias[gc + quad * 4];
    float o0 = gelu_exact(acc[0] + b4.x);
    float o1 = gelu_exact(acc[1] + b4.y);
    float o2 = gelu_exact(acc[2] + b4.z);
    float o3 = gelu_exact(acc[3] + b4.w);
    Half4 p;
    p.a = __floats2half2_rn(o0, o1);
    p.b = __floats2half2_rn(o2, o3);
    *(Half4*)&Gt[m][cl + quad * 4] = p;
  }
  __syncthreads();
  int t = threadIdx.x;
  int row = t >> 4, c8 = (t & 15) * 8;
  *(float4*)&G[(size_t)(r0 + row) * 1024 + h * 128 + c8] = *(float4*)&Gt[row][c8];
}

// ---------------- MFMA proj: G[N,1024] @ W[1024,128] + bias -> C[N,128] ----------------

template <typename OutT>
__global__ __launch_bounds__(256) void proj_mfma(const __half* __restrict__ G,
                                                 const __half* __restrict__ Wt,
                                                 const float* __restrict__ bias,
                                                 OutT* __restrict__ C) {
  int wave = threadIdx.x >> 6, lane = threadIdx.x & 63;
  int r0 = blockIdx.y * 16;
  int c0 = blockIdx.x * 64 + wave * 16;
  int m = lane & 15, quad = lane >> 4;
  const __half* pa = Wt + (size_t)(c0 + m) * 1024 + quad * 8;
  const __half* pb = G + (size_t)(r0 + m) * 1024 + quad * 8;
  f32x4 acc = {0.f, 0.f, 0.f, 0.f};
#pragma unroll 8
  for (int k = 0; k < 1024; k += 32) {
    f16x8 a = *(const f16x8*)(pa + k);
    f16x8 b = *(const f16x8*)(pb + k);
    acc = __builtin_amdgcn_mfma_f32_16x16x32_f16(a, b, acc, 0, 0, 0);
  }
  float4 b4 = *(const float4*)&bias[c0 + quad * 4];
  float v0 = acc[0] + b4.x, v1 = acc[1] + b4.y, v2 = acc[2] + b4.z, v3 = acc[3] + b4.w;
  if constexpr (__is_same(OutT, __half)) {
    Half4 p;
    p.a = __floats2half2_rn(v0, v1);
    p.b = __floats2half2_rn(v2, v3);
    *(Half4*)&C[(size_t)(r0 + m) * 128 + c0 + quad * 4] = p;
  } else {
    *(float4*)&C[(size_t)(r0 + m) * 128 + c0 + quad * 4] = make_float4(v0, v1, v2, v3);
  }
}

// ---------------- orchestration ----------------

extern "C" void kernel_launch(void* const* d_in, const int* in_sizes, int n_in,
                              void* d_out, int out_size, void* d_ws, size_t ws_size,
                              hipStream_t stream) {
  const float* x   = (const float*)d_in[0];
  const int*   ei  = (const int*)d_in[1];
  const float* w1  = (const float*)d_in[2];
  const float* as1 = (const float*)d_in[3];
  const float* ad1 = (const float*)d_in[4];
  const float* b1  = (const float*)d_in[5];
  const float* w2  = (const float*)d_in[6];
  const float* as2 = (const float*)d_in[7];
  const float* ad2 = (const float*)d_in[8];
  const float* b2  = (const float*)d_in[9];
  const float* w3  = (const float*)d_in[10];
  const float* as3 = (const float*)d_in[11];
  const float* ad3 = (const float*)d_in[12];
  const float* b3  = (const float*)d_in[13];
  const float* rw1 = (const float*)d_in[14];
  const float* rb1 = (const float*)d_in[15];
  const float* rw2 = (const float*)d_in[16];
  const float* rb2 = (const float*)d_in[17];
  const float* lw  = (const float*)d_in[18];
  const float* lb  = (const float*)d_in[19];

  int N = in_sizes[0] / 4;
  int E = in_sizes[1] / 2;
  int ET = E + N;
  (void)ws_size;

  char* wsb = (char*)d_ws;
  size_t off = 0;
  auto alloc = [&](size_t bytes) -> void* {
    void* p = wsb + off;
    off += (bytes + 255) & ~(size_t)255;
    return p;
  };
  __half* G    = (__half*)alloc((size_t)N * 1024 * 2);
  __half* P16  = (__half*)alloc((size_t)N * 128 * 2);
  __half* Y16  = (__half*)alloc((size_t)8 * N * 128 * 2);
  float*  Y1   = (float*)alloc((size_t)8 * N * 4 * 4);
  __half* wt2  = (__half*)alloc((size_t)1024 * 128 * 2);
  __half* wt3  = (__half*)alloc((size_t)1024 * 128 * 2);
  __half* rwt1 = (__half*)alloc((size_t)128 * 1024 * 2);
  __half* rwt2 = (__half*)alloc((size_t)128 * 1024 * 2);
  __half* lwt  = (__half*)alloc((size_t)128 * 1024 * 2);
  float* ws1 = (float*)alloc(8 * 4 * 4);
  float* wd1 = (float*)alloc(8 * 4 * 4);
  float* ws2 = (float*)alloc(8 * 128 * 4);
  float* wd2 = (float*)alloc(8 * 128 * 4);
  float* ws3 = (float*)alloc(8 * 128 * 4);
  float* wd3 = (float*)alloc(8 * 128 * 4);
  float* ssrc   = (float*)alloc((size_t)N * 8 * 4);
  float* sdst   = (float*)alloc((size_t)N * 8 * 4);
  float* zinv   = (float*)alloc((size_t)N * 8 * 4);
  float* alpha8 = (float*)alloc((size_t)ET * 8 * 4);
  int* counts  = (int*)alloc((size_t)N * 4);
  int* offsets = (int*)alloc((size_t)(N + 1) * 4);
  int* cursor  = (int*)alloc((size_t)N * 4);
  int* srcs    = (int*)alloc((size_t)ET * 4);

  dim3 blk(THREADS);

  // one-time: CSR + weight transposes + score-vector precompute
  hipMemsetAsync(counts, 0, (size_t)N * 4, stream);
  hist_kernel<<<dim3((ET + THREADS - 1) / THREADS), blk, 0, stream>>>(ei, E, ET, counts);
  wconv_all_kernel<<<dim3(32, 32, 5), blk, 0, stream>>>(w2, w3, rw1, rw2, lw,
                                                        wt2, wt3, rwt1, rwt2, lwt);
  sconv_kernel<<<dim3(8, 3), blk, 0, stream>>>(w1, as1, ad1, w2, as2, ad2, w3, as3, ad3,
                                               ws1, wd1, ws2, wd2, ws3, wd3);
  scan_kernel<<<dim3(1), dim3(1024), 0, stream>>>(counts, offsets, cursor, N);
  scatter_kernel<<<dim3((ET + THREADS - 1) / THREADS), blk, 0, stream>>>(ei, E, ET, cursor, srcs);

  dim3 gNode4(N / 4);
  dim3 gHg(8, N / 16);
  dim3 gProj(2, N / 16);

  // ---- layer 1 ----
  scoresX_kernel<<<dim3((N * 8 + THREADS - 1) / THREADS), blk, 0, stream>>>(
      x, ws1, wd1, ssrc, sdst, N * 8);
  attn_kernel<<<gNode4, blk, 0, stream>>>(srcs, offsets, ssrc, sdst, alpha8, zinv);
  aggX_kernel<<<gNode4, blk, 0, stream>>>(x, alpha8, offsets, srcs, zinv, Y1, N);
  hgemm1_kernel<<<dim3(N), blk, 0, stream>>>(Y1, w1, b1, G, N, N * 256);
  proj_mfma<__half><<<gProj, blk, 0, stream>>>(G, rwt1, rb1, P16);

  // ---- layer 2 ----
  scoresP_kernel<<<gNode4, blk, 0, stream>>>(P16, ws2, wd2, ssrc, sdst);
  attn_kernel<<<gNode4, blk, 0, stream>>>(srcs, offsets, ssrc, sdst, alpha8, zinv);
  aggP_kernel<<<gNode4, blk, 0, stream>>>(P16, alpha8, offsets, srcs, zinv, Y16, N);
  hgemm_kernel<<<gHg, blk, 0, stream>>>(Y16, wt2, b2, G, N);
  proj_mfma<__half><<<gProj, blk, 0, stream>>>(G, rwt2, rb2, P16);

  // ---- layer 3 ----
  scoresP_kernel<<<gNode4, blk, 0, stream>>>(P16, ws3, wd3, ssrc, sdst);
  attn_kernel<<<gNode4, blk, 0, stream>>>(srcs, offsets, ssrc, sdst, alpha8, zinv);
  aggP_kernel<<<gNode4, blk, 0, stream>>>(P16, alpha8, offsets, srcs, zinv, Y16, N);
  hgemm_kernel<<<gHg, blk, 0, stream>>>(Y16, wt3, b3, G, N);
  proj_mfma<float><<<gProj, blk, 0, stream>>>(G, lwt, lb, (float*)d_out);
}

// Round 13
// 356.714 us; speedup vs baseline: 1.8767x; 1.1958x over previous
//
#include <hip/hip_runtime.h>
#include <hip/hip_fp16.h>
#include <math.h>

// GAT encoder: N=10000, E=160000 (+N self loops), H=8 heads, C=128, D=1024.
// R11 commute restructure: out = (sum alpha*P) @ W -> gather 128-dim P once per
// edge. R12 fusions: (a) attn+agg fused per wave (alpha staged in LDS, no global
// alpha8, no separate attn dispatch); (b) hgemm+gelu+proj fused per 16-row block
// (G-tile lives in LDS only -- 40 MB/layer round-trip removed).

#define THREADS 256
#define CAP 128   // max in-degree handled per chunk (Poisson(16) max ~45; chunk loop covers more)

typedef _Float16 f16x8 __attribute__((ext_vector_type(8)));
typedef float f32x4 __attribute__((ext_vector_type(4)));

struct __align__(8) Half4 { __half2 a, b; };

__device__ __forceinline__ float gelu_exact(float x) {
  return 0.5f * x * (1.0f + erff(x * 0.70710678118654752f));
}

// ---------------- CSR build ----------------

__global__ void hist_kernel(const int* __restrict__ ei, int E, int ET, int* __restrict__ counts) {
  int e = blockIdx.x * THREADS + threadIdx.x;
  if (e >= ET) return;
  int d = (e < E) ? ei[E + e] : (e - E);
  atomicAdd(&counts[d], 1);
}

__global__ __launch_bounds__(1024) void scan_kernel(const int* __restrict__ counts,
                                                    int* __restrict__ offsets,
                                                    int* __restrict__ cursor, int n) {
  __shared__ int sums[1024];
  int t = threadIdx.x;
  int per = (n + 1023) >> 10;
  int start = t * per; if (start > n) start = n;
  int end = start + per; if (end > n) end = n;
  int local = 0;
  for (int i = start; i < end; ++i) local += counts[i];
  sums[t] = local;
  __syncthreads();
  for (int off = 1; off < 1024; off <<= 1) {
    int add = (t >= off) ? sums[t - off] : 0;
    __syncthreads();
    sums[t] += add;
    __syncthreads();
  }
  int run = (t == 0) ? 0 : sums[t - 1];
  for (int i = start; i < end; ++i) {
    offsets[i] = run; cursor[i] = run; run += counts[i];
  }
  if (t == 1023) offsets[n] = run;
}

__global__ void scatter_kernel(const int* __restrict__ ei, int E, int ET,
                               int* __restrict__ cursor, int* __restrict__ srcs) {
  int e = blockIdx.x * THREADS + threadIdx.x;
  if (e >= ET) return;
  int s = (e < E) ? ei[e] : (e - E);
  int d = (e < E) ? ei[E + e] : (e - E);
  int pos = atomicAdd(&cursor[d], 1);
  srcs[pos] = s;
}

// ---------------- batched weight transpose + fp16 convert ----------------

__global__ __launch_bounds__(256) void wconv_all_kernel(
    const float* __restrict__ w2, const float* __restrict__ w3,
    const float* __restrict__ rw1, const float* __restrict__ rw2,
    const float* __restrict__ lw,
    __half* __restrict__ wt2, __half* __restrict__ wt3,
    __half* __restrict__ rwt1, __half* __restrict__ rwt2,
    __half* __restrict__ lwt) {
  const float* in; __half* out; int K, Ncol;
  switch (blockIdx.z) {
    case 0: in = w2;  out = wt2;  K = 128;  Ncol = 1024; break;
    case 1: in = w3;  out = wt3;  K = 128;  Ncol = 1024; break;
    case 2: in = rw1; out = rwt1; K = 1024; Ncol = 128;  break;
    case 3: in = rw2; out = rwt2; K = 1024; Ncol = 128;  break;
    default: in = lw; out = lwt;  K = 1024; Ncol = 128;  break;
  }
  int kb = blockIdx.y * 32, cb = blockIdx.x * 32;
  if (kb >= K || cb >= Ncol) return;
  __shared__ float tile[32][33];
  int t = threadIdx.x;
  int tc = t & 31, tr = t >> 5;
#pragma unroll
  for (int r = tr; r < 32; r += 8)
    tile[r][tc] = in[(size_t)(kb + r) * Ncol + cb + tc];
  __syncthreads();
#pragma unroll
  for (int r = tr; r < 32; r += 8)
    out[(size_t)(cb + r) * K + kb + tc] = __float2half_rn(tile[tc][r]);
}

// ---------------- score-vector precompute: ws[h][k] = sum_c W[k][h*128+c]*a[h][c] ----------------

__global__ __launch_bounds__(256) void sconv_kernel(
    const float* __restrict__ w1, const float* __restrict__ as1, const float* __restrict__ ad1,
    const float* __restrict__ w2, const float* __restrict__ as2, const float* __restrict__ ad2,
    const float* __restrict__ w3, const float* __restrict__ as3, const float* __restrict__ ad3,
    float* __restrict__ ws1, float* __restrict__ wd1,
    float* __restrict__ ws2, float* __restrict__ wd2,
    float* __restrict__ ws3, float* __restrict__ wd3) {
  int h = blockIdx.x;
  int t = threadIdx.x;
  int sel = t >> 7;
  int k = t & 127;
  const float* W; const float* av; float* out; int K;
  switch (blockIdx.y) {
    case 0: W = w2; av = sel ? ad2 : as2; out = sel ? wd2 : ws2; K = 128; break;
    case 1: W = w3; av = sel ? ad3 : as3; out = sel ? wd3 : ws3; K = 128; break;
    default: W = w1; av = sel ? ad1 : as1; out = sel ? wd1 : ws1; K = 4; break;
  }
  if (k >= K) return;
  const float* wrow = W + (size_t)k * 1024 + h * 128;
  const float* arow = av + h * 128;
  float s = 0.f;
  for (int c = 0; c < 128; c += 4) {
    float4 wv = *(const float4*)&wrow[c];
    float4 a4 = *(const float4*)&arow[c];
    s += wv.x * a4.x + wv.y * a4.y + wv.z * a4.z + wv.w * a4.w;
  }
  out[h * K + k] = s;
}

// ---------------- layer-1 scores: s[n,h] = x[n](4) . ws1[h](4) ----------------

__global__ void scoresX_kernel(const float* __restrict__ x,
                               const float* __restrict__ ws1, const float* __restrict__ wd1,
                               float* __restrict__ ssrc, float* __restrict__ sdst, int total) {
  int idx = blockIdx.x * THREADS + threadIdx.x;
  if (idx >= total) return;
  int n = idx >> 3, h = idx & 7;
  float4 xv = *(const float4*)&x[n * 4];
  float4 a = *(const float4*)&ws1[h * 4];
  float4 b = *(const float4*)&wd1[h * 4];
  ssrc[idx] = xv.x * a.x + xv.y * a.y + xv.z * a.z + xv.w * a.w;
  sdst[idx] = xv.x * b.x + xv.y * b.y + xv.z * b.z + xv.w * b.w;
}

// ---------------- layer-2/3 scores: s[n,h] = P16[n](128) . ws[h](128) ----------------

__global__ __launch_bounds__(256) void scoresP_kernel(const __half* __restrict__ P16,
                                                      const float* __restrict__ ws,
                                                      const float* __restrict__ wd,
                                                      float* __restrict__ ssrc,
                                                      float* __restrict__ sdst) {
  int wave = threadIdx.x >> 6, lane = threadIdx.x & 63;
  int n = blockIdx.x * 4 + wave;
  int head = lane & 7, es = lane >> 3;
  const __half* pp = P16 + (size_t)n * 128 + es * 16;
  f16x8 p0 = *(const f16x8*)pp;
  f16x8 p1 = *(const f16x8*)(pp + 8);
  const float* wsp = ws + head * 128 + es * 16;
  const float* wdp = wd + head * 128 + es * 16;
  float s1 = 0.f, s2 = 0.f;
#pragma unroll
  for (int j = 0; j < 8; ++j) {
    s1 += (float)p0[j] * wsp[j];
    s2 += (float)p0[j] * wdp[j];
  }
#pragma unroll
  for (int j = 0; j < 8; ++j) {
    s1 += (float)p1[j] * wsp[8 + j];
    s2 += (float)p1[j] * wdp[8 + j];
  }
#pragma unroll
  for (int mask = 8; mask <= 32; mask <<= 1) {
    s1 += __shfl_xor(s1, mask);
    s2 += __shfl_xor(s2, mask);
  }
  if (es == 0) { ssrc[n * 8 + head] = s1; sdst[n * 8 + head] = s2; }
}

// ---------------- fused attention + aggregation (P16), wave per node ----------------
// Phase A (lane = head + 8*es): exp(leaky(logit)) -> LDS lal[i][head], sum s.
// Phase B (lane = channel pair): gather P16 rows, accumulate 8-head accs.
// Wave-internal LDS exchange (no barrier -- lockstep wave, compiler orders lgkmcnt).
// zinv applied once in epilogue. Y16[h][n][128] fp16 out.

__global__ __launch_bounds__(256) void attnagg_p(const __half* __restrict__ P16,
                                                 const int* __restrict__ srcs,
                                                 const int* __restrict__ offsets,
                                                 const float* __restrict__ ssrc,
                                                 const float* __restrict__ sdst,
                                                 __half* __restrict__ Y16, int N) {
  __shared__ float lal[4][CAP][8];
  __shared__ int ls[4][CAP];
  __shared__ float szinv[4][8];
  int w = threadIdx.x >> 6, lane = threadIdx.x & 63;
  int n = blockIdx.x * 4 + w;
  int start = offsets[n], deg = offsets[n + 1] - start;
  int head = lane & 7, es = lane >> 3;
  float sd = sdst[n * 8 + head];
  int c2 = lane * 2;
  float accx[8] = {}, accy[8] = {};
  float s = 0.f;
  for (int cc = 0; cc < deg; cc += CAP) {
    int cm = min(CAP, deg - cc);
    // phase A
    for (int i = es; i < cm; i += 8) {
      int sp = srcs[start + cc + i];
      float v = ssrc[sp * 8 + head] + sd;
      v = (v > 0.f) ? v : 0.2f * v;
      float e = __expf(v);
      lal[w][i][head] = e;
      if (head == 0) ls[w][i] = sp;
      s += e;
    }
    // phase B
    int i = 0;
    for (; i + 1 < cm; i += 2) {
      int sp0 = ls[w][i], sp1 = ls[w][i + 1];
      float4 a00 = *(float4*)&lal[w][i][0];
      float4 a01 = *(float4*)&lal[w][i][4];
      float4 a10 = *(float4*)&lal[w][i + 1][0];
      float4 a11 = *(float4*)&lal[w][i + 1][4];
      float2 p0 = __half22float2(*(const __half2*)&P16[(size_t)sp0 * 128 + c2]);
      float2 p1 = __half22float2(*(const __half2*)&P16[(size_t)sp1 * 128 + c2]);
      float a0[8] = {a00.x, a00.y, a00.z, a00.w, a01.x, a01.y, a01.z, a01.w};
      float a1[8] = {a10.x, a10.y, a10.z, a10.w, a11.x, a11.y, a11.z, a11.w};
#pragma unroll
      for (int h = 0; h < 8; ++h) {
        accx[h] += a0[h] * p0.x; accy[h] += a0[h] * p0.y;
        accx[h] += a1[h] * p1.x; accy[h] += a1[h] * p1.y;
      }
    }
    if (i < cm) {
      int sp0 = ls[w][i];
      float4 a00 = *(float4*)&lal[w][i][0];
      float4 a01 = *(float4*)&lal[w][i][4];
      float2 p0 = __half22float2(*(const __half2*)&P16[(size_t)sp0 * 128 + c2]);
      float a0[8] = {a00.x, a00.y, a00.z, a00.w, a01.x, a01.y, a01.z, a01.w};
#pragma unroll
      for (int h = 0; h < 8; ++h) {
        accx[h] += a0[h] * p0.x; accy[h] += a0[h] * p0.y;
      }
    }
  }
#pragma unroll
  for (int mask = 8; mask <= 32; mask <<= 1)
    s += __shfl_xor(s, mask);
  if (es == 0) szinv[w][head] = 1.f / s;
#pragma unroll
  for (int h = 0; h < 8; ++h) {
    float zi = szinv[w][h];
    *(__half2*)&Y16[((size_t)h * N + n) * 128 + c2] =
        __floats2half2_rn(accx[h] * zi, accy[h] * zi);
  }
}

// ---------------- fused attention + aggregation (layer 1, raw x), wave per node ----------------
// Phase B lane map: eo = lane>>5 (2 edge sublanes), h = (lane>>2)&7, ch = lane&3.

__global__ __launch_bounds__(256) void attnagg_x(const float* __restrict__ x,
                                                 const int* __restrict__ srcs,
                                                 const int* __restrict__ offsets,
                                                 const float* __restrict__ ssrc,
                                                 const float* __restrict__ sdst,
                                                 float* __restrict__ Y1, int N) {
  __shared__ float lal[4][CAP][8];
  __shared__ int ls[4][CAP];
  __shared__ float szinv[4][8];
  int w = threadIdx.x >> 6, lane = threadIdx.x & 63;
  int n = blockIdx.x * 4 + w;
  int start = offsets[n], deg = offsets[n + 1] - start;
  int head = lane & 7, es = lane >> 3;
  float sd = sdst[n * 8 + head];
  int eo = lane >> 5, hb = (lane >> 2) & 7, ch = lane & 3;
  float acc = 0.f;
  float s = 0.f;
  for (int cc = 0; cc < deg; cc += CAP) {
    int cm = min(CAP, deg - cc);
    for (int i = es; i < cm; i += 8) {
      int sp = srcs[start + cc + i];
      float v = ssrc[sp * 8 + head] + sd;
      v = (v > 0.f) ? v : 0.2f * v;
      float e = __expf(v);
      lal[w][i][head] = e;
      if (head == 0) ls[w][i] = sp;
      s += e;
    }
    for (int i = eo; i < cm; i += 2) {
      int sp = ls[w][i];
      float a = lal[w][i][hb];
      acc += a * x[sp * 4 + ch];
    }
  }
#pragma unroll
  for (int mask = 8; mask <= 32; mask <<= 1)
    s += __shfl_xor(s, mask);
  if (es == 0) szinv[w][head] = 1.f / s;
  acc += __shfl_xor(acc, 32);
  if (lane < 32) {
    float zi = szinv[w][hb];
    Y1[((size_t)hb * N + n) * 4 + ch] = acc * zi;
  }
}

// ---------------- fused tail (layers 2/3): per-head MFMA + gelu -> LDS -> proj MFMA ----------------
// Block = 16 rows. Stage 1: 8 head GEMMs (K=128) + bias + gelu into Gt[16][1032] LDS.
// Stage 2: proj (K=1024) with B-fragments from LDS; + biasP; store 16x128.

template <typename OutT>
__global__ __launch_bounds__(256) void tail_mfma(const __half* __restrict__ Y16,
                                                 const __half* __restrict__ WtA,
                                                 const float* __restrict__ biasA,
                                                 const __half* __restrict__ WtP,
                                                 const float* __restrict__ biasP,
                                                 OutT* __restrict__ out, int N) {
  __shared__ __half Gt[16][1032];
  int w = threadIdx.x >> 6, lane = threadIdx.x & 63;
  int r0 = blockIdx.x * 16;
  int m = lane & 15, quad = lane >> 4;
#pragma unroll 2
  for (int h = 0; h < 8; ++h) {
    const __half* py = Y16 + ((size_t)h * N + r0 + m) * 128 + quad * 8;
    f16x8 bf[4];
#pragma unroll
    for (int kk = 0; kk < 4; ++kk)
      bf[kk] = *(const f16x8*)(py + kk * 32);
#pragma unroll
    for (int tile = 0; tile < 2; ++tile) {
      int gc = h * 128 + (w * 2 + tile) * 16;
      const __half* pa = WtA + (size_t)(gc + m) * 128 + quad * 8;
      f32x4 acc = {0.f, 0.f, 0.f, 0.f};
#pragma unroll
      for (int kk = 0; kk < 4; ++kk) {
        f16x8 a = *(const f16x8*)(pa + kk * 32);
        acc = __builtin_amdgcn_mfma_f32_16x16x32_f16(a, bf[kk], acc, 0, 0, 0);
      }
      float4 b4 = *(const float4*)&biasA[gc + quad * 4];
      float o0 = gelu_exact(acc[0] + b4.x);
      float o1 = gelu_exact(acc[1] + b4.y);
      float o2 = gelu_exact(acc[2] + b4.z);
      float o3 = gelu_exact(acc[3] + b4.w);
      Half4 p;
      p.a = __floats2half2_rn(o0, o1);
      p.b = __floats2half2_rn(o2, o3);
      *(Half4*)&Gt[m][gc + quad * 4] = p;
    }
  }
  __syncthreads();
#pragma unroll
  for (int tt = 0; tt < 2; ++tt) {
    int c0 = (w * 2 + tt) * 16;
    const __half* pa = WtP + (size_t)(c0 + m) * 1024 + quad * 8;
    f32x4 acc = {0.f, 0.f, 0.f, 0.f};
#pragma unroll 8
    for (int k = 0; k < 1024; k += 32) {
      f16x8 a = *(const f16x8*)(pa + k);
      f16x8 b = *(const f16x8*)&Gt[m][quad * 8 + k];
      acc = __builtin_amdgcn_mfma_f32_16x16x32_f16(a, b, acc, 0, 0, 0);
    }
    float4 b4 = *(const float4*)&biasP[c0 + quad * 4];
    float v0 = acc[0] + b4.x, v1 = acc[1] + b4.y, v2 = acc[2] + b4.z, v3 = acc[3] + b4.w;
    if constexpr (__is_same(OutT, __half)) {
      Half4 p;
      p.a = __floats2half2_rn(v0, v1);
      p.b = __floats2half2_rn(v2, v3);
      *(Half4*)&out[(size_t)(r0 + m) * 128 + c0 + quad * 4] = p;
    } else {
      *(float4*)&out[(size_t)(r0 + m) * 128 + c0 + quad * 4] = make_float4(v0, v1, v2, v3);
    }
  }
}

// ---------------- fused tail (layer 1): VALU K=4 transform + gelu -> LDS -> proj MFMA ----------------

template <typename OutT>
__global__ __launch_bounds__(256) void tail1_kernel(const float* __restrict__ Y1,
                                                    const float* __restrict__ w,
                                                    const float* __restrict__ biasA,
                                                    const __half* __restrict__ WtP,
                                                    const float* __restrict__ biasP,
                                                    OutT* __restrict__ out, int N) {
  __shared__ __half Gt[16][1032];
  int t = threadIdx.x;
  int r0 = blockIdx.x * 16;
  int c0 = t * 4;
  int h = t >> 5;
  float4 wa = *(const float4*)&w[c0];
  float4 wb = *(const float4*)&w[1024 + c0];
  float4 wc = *(const float4*)&w[2048 + c0];
  float4 wd = *(const float4*)&w[3072 + c0];
  float4 b4 = *(const float4*)&biasA[c0];
#pragma unroll 4
  for (int r = 0; r < 16; ++r) {
    float4 yv = *(const float4*)&Y1[((size_t)h * N + r0 + r) * 4];
    float o0 = gelu_exact(yv.x * wa.x + yv.y * wb.x + yv.z * wc.x + yv.w * wd.x + b4.x);
    float o1 = gelu_exact(yv.x * wa.y + yv.y * wb.y + yv.z * wc.y + yv.w * wd.y + b4.y);
    float o2 = gelu_exact(yv.x * wa.z + yv.y * wb.z + yv.z * wc.z + yv.w * wd.z + b4.z);
    float o3 = gelu_exact(yv.x * wa.w + yv.y * wb.w + yv.z * wc.w + yv.w * wd.w + b4.w);
    Half4 p;
    p.a = __floats2half2_rn(o0, o1);
    p.b = __floats2half2_rn(o2, o3);
    *(Half4*)&Gt[r][c0] = p;
  }
  __syncthreads();
  int wv = t >> 6, lane = t & 63;
  int m = lane & 15, quad = lane >> 4;
#pragma unroll
  for (int tt = 0; tt < 2; ++tt) {
    int cc = (wv * 2 + tt) * 16;
    const __half* pa = WtP + (size_t)(cc + m) * 1024 + quad * 8;
    f32x4 acc = {0.f, 0.f, 0.f, 0.f};
#pragma unroll 8
    for (int k = 0; k < 1024; k += 32) {
      f16x8 a = *(const f16x8*)(pa + k);
      f16x8 b = *(const f16x8*)&Gt[m][quad * 8 + k];
      acc = __builtin_amdgcn_mfma_f32_16x16x32_f16(a, b, acc, 0, 0, 0);
    }
    float4 bp = *(const float4*)&biasP[cc + quad * 4];
    float v0 = acc[0] + bp.x, v1 = acc[1] + bp.y, v2 = acc[2] + bp.z, v3 = acc[3] + bp.w;
    if constexpr (__is_same(OutT, __half)) {
      Half4 p;
      p.a = __floats2half2_rn(v0, v1);
      p.b = __floats2half2_rn(v2, v3);
      *(Half4*)&out[(size_t)(r0 + m) * 128 + cc + quad * 4] = p;
    } else {
      *(float4*)&out[(size_t)(r0 + m) * 128 + cc + quad * 4] = make_float4(v0, v1, v2, v3);
    }
  }
}

// ---------------- orchestration ----------------

extern "C" void kernel_launch(void* const* d_in, const int* in_sizes, int n_in,
                              void* d_out, int out_size, void* d_ws, size_t ws_size,
                              hipStream_t stream) {
  const float* x   = (const float*)d_in[0];
  const int*   ei  = (const int*)d_in[1];
  const float* w1  = (const float*)d_in[2];
  const float* as1 = (const float*)d_in[3];
  const float* ad1 = (const float*)d_in[4];
  const float* b1  = (const float*)d_in[5];
  const float* w2  = (const float*)d_in[6];
  const float* as2 = (const float*)d_in[7];
  const float* ad2 = (const float*)d_in[8];
  const float* b2  = (const float*)d_in[9];
  const float* w3  = (const float*)d_in[10];
  const float* as3 = (const float*)d_in[11];
  const float* ad3 = (const float*)d_in[12];
  const float* b3  = (const float*)d_in[13];
  const float* rw1 = (const float*)d_in[14];
  const float* rb1 = (const float*)d_in[15];
  const float* rw2 = (const float*)d_in[16];
  const float* rb2 = (const float*)d_in[17];
  const float* lw  = (const float*)d_in[18];
  const float* lb  = (const float*)d_in[19];

  int N = in_sizes[0] / 4;
  int E = in_sizes[1] / 2;
  int ET = E + N;
  (void)ws_size;

  char* wsb = (char*)d_ws;
  size_t off = 0;
  auto alloc = [&](size_t bytes) -> void* {
    void* p = wsb + off;
    off += (bytes + 255) & ~(size_t)255;
    return p;
  };
  __half* P16  = (__half*)alloc((size_t)N * 128 * 2);
  __half* Y16  = (__half*)alloc((size_t)8 * N * 128 * 2);
  float*  Y1   = (float*)alloc((size_t)8 * N * 4 * 4);
  __half* wt2  = (__half*)alloc((size_t)1024 * 128 * 2);
  __half* wt3  = (__half*)alloc((size_t)1024 * 128 * 2);
  __half* rwt1 = (__half*)alloc((size_t)128 * 1024 * 2);
  __half* rwt2 = (__half*)alloc((size_t)128 * 1024 * 2);
  __half* lwt  = (__half*)alloc((size_t)128 * 1024 * 2);
  float* ws1 = (float*)alloc(8 * 4 * 4);
  float* wd1 = (float*)alloc(8 * 4 * 4);
  float* ws2 = (float*)alloc(8 * 128 * 4);
  float* wd2 = (float*)alloc(8 * 128 * 4);
  float* ws3 = (float*)alloc(8 * 128 * 4);
  float* wd3 = (float*)alloc(8 * 128 * 4);
  float* ssrc   = (float*)alloc((size_t)N * 8 * 4);
  float* sdst   = (float*)alloc((size_t)N * 8 * 4);
  int* counts  = (int*)alloc((size_t)N * 4);
  int* offsets = (int*)alloc((size_t)(N + 1) * 4);
  int* cursor  = (int*)alloc((size_t)N * 4);
  int* srcs    = (int*)alloc((size_t)ET * 4);

  dim3 blk(THREADS);

  // one-time: CSR + weight transposes + score-vector precompute
  hipMemsetAsync(counts, 0, (size_t)N * 4, stream);
  hist_kernel<<<dim3((ET + THREADS - 1) / THREADS), blk, 0, stream>>>(ei, E, ET, counts);
  wconv_all_kernel<<<dim3(32, 32, 5), blk, 0, stream>>>(w2, w3, rw1, rw2, lw,
                                                        wt2, wt3, rwt1, rwt2, lwt);
  sconv_kernel<<<dim3(8, 3), blk, 0, stream>>>(w1, as1, ad1, w2, as2, ad2, w3, as3, ad3,
                                               ws1, wd1, ws2, wd2, ws3, wd3);
  scan_kernel<<<dim3(1), dim3(1024), 0, stream>>>(counts, offsets, cursor, N);
  scatter_kernel<<<dim3((ET + THREADS - 1) / THREADS), blk, 0, stream>>>(ei, E, ET, cursor, srcs);

  dim3 gNode4(N / 4);
  dim3 gRow16(N / 16);

  // ---- layer 1 ----
  scoresX_kernel<<<dim3((N * 8 + THREADS - 1) / THREADS), blk, 0, stream>>>(
      x, ws1, wd1, ssrc, sdst, N * 8);
  attnagg_x<<<gNode4, blk, 0, stream>>>(x, srcs, offsets, ssrc, sdst, Y1, N);
  tail1_kernel<__half><<<gRow16, blk, 0, stream>>>(Y1, w1, b1, rwt1, rb1, P16, N);

  // ---- layer 2 ----
  scoresP_kernel<<<gNode4, blk, 0, stream>>>(P16, ws2, wd2, ssrc, sdst);
  attnagg_p<<<gNode4, blk, 0, stream>>>(P16, srcs, offsets, ssrc, sdst, Y16, N);
  tail_mfma<__half><<<gRow16, blk, 0, stream>>>(Y16, wt2, b2, rwt2, rb2, P16, N);

  // ---- layer 3 ----
  scoresP_kernel<<<gNode4, blk, 0, stream>>>(P16, ws3, wd3, ssrc, sdst);
  attnagg_p<<<gNode4, blk, 0, stream>>>(P16, srcs, offsets, ssrc, sdst, Y16, N);
  tail_mfma<float><<<gRow16, blk, 0, stream>>>(Y16, wt3, b3, lwt, lb, (float*)d_out, N);
}

// Round 14
// 341.551 us; speedup vs baseline: 1.9600x; 1.0444x over previous
//
#include <hip/hip_runtime.h>
#include <hip/hip_fp16.h>
#include <math.h>

// GAT encoder: N=10000, E=160000 (+N self loops), H=8 heads, C=128, D=1024.
// R11 commute restructure: out = (sum alpha*P) @ W -> gather 128-dim P once per
// edge. R12 fusions: attn+agg fused per wave; hgemm+gelu+proj fused per block.
// R13: tail kernels widened to 512 threads / 8 waves (wave = head in stage 1,
// wave = col-tile in stage 2) -- 2x occupancy, half the per-wave serial MFMA
// chain, 4x less redundant Y16 re-loading (R13 profile: 625x4-wave blocks were
// grid-limited at 2.4 waves/SIMD, MfmaUtil 3%).

#define THREADS 256
#define CAP 128

typedef _Float16 f16x8 __attribute__((ext_vector_type(8)));
typedef float f32x4 __attribute__((ext_vector_type(4)));

struct __align__(8) Half4 { __half2 a, b; };

__device__ __forceinline__ float gelu_exact(float x) {
  return 0.5f * x * (1.0f + erff(x * 0.70710678118654752f));
}

// ---------------- CSR build ----------------

__global__ void hist_kernel(const int* __restrict__ ei, int E, int ET, int* __restrict__ counts) {
  int e = blockIdx.x * THREADS + threadIdx.x;
  if (e >= ET) return;
  int d = (e < E) ? ei[E + e] : (e - E);
  atomicAdd(&counts[d], 1);
}

__global__ __launch_bounds__(1024) void scan_kernel(const int* __restrict__ counts,
                                                    int* __restrict__ offsets,
                                                    int* __restrict__ cursor, int n) {
  __shared__ int sums[1024];
  int t = threadIdx.x;
  int per = (n + 1023) >> 10;
  int start = t * per; if (start > n) start = n;
  int end = start + per; if (end > n) end = n;
  int local = 0;
  for (int i = start; i < end; ++i) local += counts[i];
  sums[t] = local;
  __syncthreads();
  for (int off = 1; off < 1024; off <<= 1) {
    int add = (t >= off) ? sums[t - off] : 0;
    __syncthreads();
    sums[t] += add;
    __syncthreads();
  }
  int run = (t == 0) ? 0 : sums[t - 1];
  for (int i = start; i < end; ++i) {
    offsets[i] = run; cursor[i] = run; run += counts[i];
  }
  if (t == 1023) offsets[n] = run;
}

__global__ void scatter_kernel(const int* __restrict__ ei, int E, int ET,
                               int* __restrict__ cursor, int* __restrict__ srcs) {
  int e = blockIdx.x * THREADS + threadIdx.x;
  if (e >= ET) return;
  int s = (e < E) ? ei[e] : (e - E);
  int d = (e < E) ? ei[E + e] : (e - E);
  int pos = atomicAdd(&cursor[d], 1);
  srcs[pos] = s;
}

// ---------------- batched weight transpose + fp16 convert ----------------

__global__ __launch_bounds__(256) void wconv_all_kernel(
    const float* __restrict__ w2, const float* __restrict__ w3,
    const float* __restrict__ rw1, const float* __restrict__ rw2,
    const float* __restrict__ lw,
    __half* __restrict__ wt2, __half* __restrict__ wt3,
    __half* __restrict__ rwt1, __half* __restrict__ rwt2,
    __half* __restrict__ lwt) {
  const float* in; __half* out; int K, Ncol;
  switch (blockIdx.z) {
    case 0: in = w2;  out = wt2;  K = 128;  Ncol = 1024; break;
    case 1: in = w3;  out = wt3;  K = 128;  Ncol = 1024; break;
    case 2: in = rw1; out = rwt1; K = 1024; Ncol = 128;  break;
    case 3: in = rw2; out = rwt2; K = 1024; Ncol = 128;  break;
    default: in = lw; out = lwt;  K = 1024; Ncol = 128;  break;
  }
  int kb = blockIdx.y * 32, cb = blockIdx.x * 32;
  if (kb >= K || cb >= Ncol) return;
  __shared__ float tile[32][33];
  int t = threadIdx.x;
  int tc = t & 31, tr = t >> 5;
#pragma unroll
  for (int r = tr; r < 32; r += 8)
    tile[r][tc] = in[(size_t)(kb + r) * Ncol + cb + tc];
  __syncthreads();
#pragma unroll
  for (int r = tr; r < 32; r += 8)
    out[(size_t)(cb + r) * K + kb + tc] = __float2half_rn(tile[tc][r]);
}

// ---------------- score-vector precompute ----------------

__global__ __launch_bounds__(256) void sconv_kernel(
    const float* __restrict__ w1, const float* __restrict__ as1, const float* __restrict__ ad1,
    const float* __restrict__ w2, const float* __restrict__ as2, const float* __restrict__ ad2,
    const float* __restrict__ w3, const float* __restrict__ as3, const float* __restrict__ ad3,
    float* __restrict__ ws1, float* __restrict__ wd1,
    float* __restrict__ ws2, float* __restrict__ wd2,
    float* __restrict__ ws3, float* __restrict__ wd3) {
  int h = blockIdx.x;
  int t = threadIdx.x;
  int sel = t >> 7;
  int k = t & 127;
  const float* W; const float* av; float* out; int K;
  switch (blockIdx.y) {
    case 0: W = w2; av = sel ? ad2 : as2; out = sel ? wd2 : ws2; K = 128; break;
    case 1: W = w3; av = sel ? ad3 : as3; out = sel ? wd3 : ws3; K = 128; break;
    default: W = w1; av = sel ? ad1 : as1; out = sel ? wd1 : ws1; K = 4; break;
  }
  if (k >= K) return;
  const float* wrow = W + (size_t)k * 1024 + h * 128;
  const float* arow = av + h * 128;
  float s = 0.f;
  for (int c = 0; c < 128; c += 4) {
    float4 wv = *(const float4*)&wrow[c];
    float4 a4 = *(const float4*)&arow[c];
    s += wv.x * a4.x + wv.y * a4.y + wv.z * a4.z + wv.w * a4.w;
  }
  out[h * K + k] = s;
}

// ---------------- layer-1 scores ----------------

__global__ void scoresX_kernel(const float* __restrict__ x,
                               const float* __restrict__ ws1, const float* __restrict__ wd1,
                               float* __restrict__ ssrc, float* __restrict__ sdst, int total) {
  int idx = blockIdx.x * THREADS + threadIdx.x;
  if (idx >= total) return;
  int n = idx >> 3, h = idx & 7;
  float4 xv = *(const float4*)&x[n * 4];
  float4 a = *(const float4*)&ws1[h * 4];
  float4 b = *(const float4*)&wd1[h * 4];
  ssrc[idx] = xv.x * a.x + xv.y * a.y + xv.z * a.z + xv.w * a.w;
  sdst[idx] = xv.x * b.x + xv.y * b.y + xv.z * b.z + xv.w * b.w;
}

// ---------------- layer-2/3 scores ----------------

__global__ __launch_bounds__(256) void scoresP_kernel(const __half* __restrict__ P16,
                                                      const float* __restrict__ ws,
                                                      const float* __restrict__ wd,
                                                      float* __restrict__ ssrc,
                                                      float* __restrict__ sdst) {
  int wave = threadIdx.x >> 6, lane = threadIdx.x & 63;
  int n = blockIdx.x * 4 + wave;
  int head = lane & 7, es = lane >> 3;
  const __half* pp = P16 + (size_t)n * 128 + es * 16;
  f16x8 p0 = *(const f16x8*)pp;
  f16x8 p1 = *(const f16x8*)(pp + 8);
  const float* wsp = ws + head * 128 + es * 16;
  const float* wdp = wd + head * 128 + es * 16;
  float s1 = 0.f, s2 = 0.f;
#pragma unroll
  for (int j = 0; j < 8; ++j) {
    s1 += (float)p0[j] * wsp[j];
    s2 += (float)p0[j] * wdp[j];
  }
#pragma unroll
  for (int j = 0; j < 8; ++j) {
    s1 += (float)p1[j] * wsp[8 + j];
    s2 += (float)p1[j] * wdp[8 + j];
  }
#pragma unroll
  for (int mask = 8; mask <= 32; mask <<= 1) {
    s1 += __shfl_xor(s1, mask);
    s2 += __shfl_xor(s2, mask);
  }
  if (es == 0) { ssrc[n * 8 + head] = s1; sdst[n * 8 + head] = s2; }
}

// ---------------- fused attention + aggregation (P16), wave per node ----------------

__global__ __launch_bounds__(256) void attnagg_p(const __half* __restrict__ P16,
                                                 const int* __restrict__ srcs,
                                                 const int* __restrict__ offsets,
                                                 const float* __restrict__ ssrc,
                                                 const float* __restrict__ sdst,
                                                 __half* __restrict__ Y16, int N) {
  __shared__ float lal[4][CAP][8];
  __shared__ int ls[4][CAP];
  __shared__ float szinv[4][8];
  int w = threadIdx.x >> 6, lane = threadIdx.x & 63;
  int n = blockIdx.x * 4 + w;
  int start = offsets[n], deg = offsets[n + 1] - start;
  int head = lane & 7, es = lane >> 3;
  float sd = sdst[n * 8 + head];
  int c2 = lane * 2;
  float accx[8] = {}, accy[8] = {};
  float s = 0.f;
  for (int cc = 0; cc < deg; cc += CAP) {
    int cm = min(CAP, deg - cc);
    for (int i = es; i < cm; i += 8) {
      int sp = srcs[start + cc + i];
      float v = ssrc[sp * 8 + head] + sd;
      v = (v > 0.f) ? v : 0.2f * v;
      float e = __expf(v);
      lal[w][i][head] = e;
      if (head == 0) ls[w][i] = sp;
      s += e;
    }
    int i = 0;
    for (; i + 1 < cm; i += 2) {
      int sp0 = ls[w][i], sp1 = ls[w][i + 1];
      float4 a00 = *(float4*)&lal[w][i][0];
      float4 a01 = *(float4*)&lal[w][i][4];
      float4 a10 = *(float4*)&lal[w][i + 1][0];
      float4 a11 = *(float4*)&lal[w][i + 1][4];
      float2 p0 = __half22float2(*(const __half2*)&P16[(size_t)sp0 * 128 + c2]);
      float2 p1 = __half22float2(*(const __half2*)&P16[(size_t)sp1 * 128 + c2]);
      float a0[8] = {a00.x, a00.y, a00.z, a00.w, a01.x, a01.y, a01.z, a01.w};
      float a1[8] = {a10.x, a10.y, a10.z, a10.w, a11.x, a11.y, a11.z, a11.w};
#pragma unroll
      for (int h = 0; h < 8; ++h) {
        accx[h] += a0[h] * p0.x; accy[h] += a0[h] * p0.y;
        accx[h] += a1[h] * p1.x; accy[h] += a1[h] * p1.y;
      }
    }
    if (i < cm) {
      int sp0 = ls[w][i];
      float4 a00 = *(float4*)&lal[w][i][0];
      float4 a01 = *(float4*)&lal[w][i][4];
      float2 p0 = __half22float2(*(const __half2*)&P16[(size_t)sp0 * 128 + c2]);
      float a0[8] = {a00.x, a00.y, a00.z, a00.w, a01.x, a01.y, a01.z, a01.w};
#pragma unroll
      for (int h = 0; h < 8; ++h) {
        accx[h] += a0[h] * p0.x; accy[h] += a0[h] * p0.y;
      }
    }
  }
#pragma unroll
  for (int mask = 8; mask <= 32; mask <<= 1)
    s += __shfl_xor(s, mask);
  if (es == 0) szinv[w][head] = 1.f / s;
#pragma unroll
  for (int h = 0; h < 8; ++h) {
    float zi = szinv[w][h];
    *(__half2*)&Y16[((size_t)h * N + n) * 128 + c2] =
        __floats2half2_rn(accx[h] * zi, accy[h] * zi);
  }
}

// ---------------- fused attention + aggregation (layer 1, raw x) ----------------

__global__ __launch_bounds__(256) void attnagg_x(const float* __restrict__ x,
                                                 const int* __restrict__ srcs,
                                                 const int* __restrict__ offsets,
                                                 const float* __restrict__ ssrc,
                                                 const float* __restrict__ sdst,
                                                 float* __restrict__ Y1, int N) {
  __shared__ float lal[4][CAP][8];
  __shared__ int ls[4][CAP];
  __shared__ float szinv[4][8];
  int w = threadIdx.x >> 6, lane = threadIdx.x & 63;
  int n = blockIdx.x * 4 + w;
  int start = offsets[n], deg = offsets[n + 1] - start;
  int head = lane & 7, es = lane >> 3;
  float sd = sdst[n * 8 + head];
  int eo = lane >> 5, hb = (lane >> 2) & 7, ch = lane & 3;
  float acc = 0.f;
  float s = 0.f;
  for (int cc = 0; cc < deg; cc += CAP) {
    int cm = min(CAP, deg - cc);
    for (int i = es; i < cm; i += 8) {
      int sp = srcs[start + cc + i];
      float v = ssrc[sp * 8 + head] + sd;
      v = (v > 0.f) ? v : 0.2f * v;
      float e = __expf(v);
      lal[w][i][head] = e;
      if (head == 0) ls[w][i] = sp;
      s += e;
    }
    for (int i = eo; i < cm; i += 2) {
      int sp = ls[w][i];
      float a = lal[w][i][hb];
      acc += a * x[sp * 4 + ch];
    }
  }
#pragma unroll
  for (int mask = 8; mask <= 32; mask <<= 1)
    s += __shfl_xor(s, mask);
  if (es == 0) szinv[w][head] = 1.f / s;
  acc += __shfl_xor(acc, 32);
  if (lane < 32) {
    float zi = szinv[w][hb];
    Y1[((size_t)hb * N + n) * 4 + ch] = acc * zi;
  }
}

// ---------------- fused tail (layers 2/3), 512 threads / 8 waves ----------------
// Stage 1: wave w = head w -- loads its Y16 B-frag once, 8 col-tiles x 4 MFMAs,
// + bias + gelu into Gt LDS. Stage 2: wave w = col-tile w (16 cols), K=1024
// proj MFMA with B-fragments from LDS.

template <typename OutT>
__global__ __launch_bounds__(512) void tail_mfma(const __half* __restrict__ Y16,
                                                 const __half* __restrict__ WtA,
                                                 const float* __restrict__ biasA,
                                                 const __half* __restrict__ WtP,
                                                 const float* __restrict__ biasP,
                                                 OutT* __restrict__ out, int N) {
  __shared__ __half Gt[16][1032];
  int w = threadIdx.x >> 6, lane = threadIdx.x & 63;
  int r0 = blockIdx.x * 16;
  int m = lane & 15, quad = lane >> 4;
  // stage 1: wave w handles head h = w
  {
    int h = w;
    const __half* py = Y16 + ((size_t)h * N + r0 + m) * 128 + quad * 8;
    f16x8 bf[4];
#pragma unroll
    for (int kk = 0; kk < 4; ++kk)
      bf[kk] = *(const f16x8*)(py + kk * 32);
#pragma unroll
    for (int tile = 0; tile < 8; ++tile) {
      int gc = h * 128 + tile * 16;
      const __half* pa = WtA + (size_t)(gc + m) * 128 + quad * 8;
      f32x4 acc = {0.f, 0.f, 0.f, 0.f};
#pragma unroll
      for (int kk = 0; kk < 4; ++kk) {
        f16x8 a = *(const f16x8*)(pa + kk * 32);
        acc = __builtin_amdgcn_mfma_f32_16x16x32_f16(a, bf[kk], acc, 0, 0, 0);
      }
      float4 b4 = *(const float4*)&biasA[gc + quad * 4];
      float o0 = gelu_exact(acc[0] + b4.x);
      float o1 = gelu_exact(acc[1] + b4.y);
      float o2 = gelu_exact(acc[2] + b4.z);
      float o3 = gelu_exact(acc[3] + b4.w);
      Half4 p;
      p.a = __floats2half2_rn(o0, o1);
      p.b = __floats2half2_rn(o2, o3);
      *(Half4*)&Gt[m][gc + quad * 4] = p;
    }
  }
  __syncthreads();
  // stage 2: wave w = col tile w
  {
    int c0 = w * 16;
    const __half* pa = WtP + (size_t)(c0 + m) * 1024 + quad * 8;
    f32x4 acc = {0.f, 0.f, 0.f, 0.f};
#pragma unroll 8
    for (int k = 0; k < 1024; k += 32) {
      f16x8 a = *(const f16x8*)(pa + k);
      f16x8 b = *(const f16x8*)&Gt[m][quad * 8 + k];
      acc = __builtin_amdgcn_mfma_f32_16x16x32_f16(a, b, acc, 0, 0, 0);
    }
    float4 b4 = *(const float4*)&biasP[c0 + quad * 4];
    float v0 = acc[0] + b4.x, v1 = acc[1] + b4.y, v2 = acc[2] + b4.z, v3 = acc[3] + b4.w;
    if constexpr (__is_same(OutT, __half)) {
      Half4 p;
      p.a = __floats2half2_rn(v0, v1);
      p.b = __floats2half2_rn(v2, v3);
      *(Half4*)&out[(size_t)(r0 + m) * 128 + c0 + quad * 4] = p;
    } else {
      *(float4*)&out[(size_t)(r0 + m) * 128 + c0 + quad * 4] = make_float4(v0, v1, v2, v3);
    }
  }
}

// ---------------- fused tail (layer 1), 512 threads ----------------

template <typename OutT>
__global__ __launch_bounds__(512) void tail1_kernel(const float* __restrict__ Y1,
                                                    const float* __restrict__ w,
                                                    const float* __restrict__ biasA,
                                                    const __half* __restrict__ WtP,
                                                    const float* __restrict__ biasP,
                                                    OutT* __restrict__ out, int N) {
  __shared__ __half Gt[16][1032];
  int t = threadIdx.x;
  int r0 = blockIdx.x * 16;
  {
    int c0 = (t & 255) * 4;
    int h = c0 >> 7;
    float4 wa = *(const float4*)&w[c0];
    float4 wb = *(const float4*)&w[1024 + c0];
    float4 wc = *(const float4*)&w[2048 + c0];
    float4 wd = *(const float4*)&w[3072 + c0];
    float4 b4 = *(const float4*)&biasA[c0];
#pragma unroll 4
    for (int r = t >> 8; r < 16; r += 2) {
      float4 yv = *(const float4*)&Y1[((size_t)h * N + r0 + r) * 4];
      float o0 = gelu_exact(yv.x * wa.x + yv.y * wb.x + yv.z * wc.x + yv.w * wd.x + b4.x);
      float o1 = gelu_exact(yv.x * wa.y + yv.y * wb.y + yv.z * wc.y + yv.w * wd.y + b4.y);
      float o2 = gelu_exact(yv.x * wa.z + yv.y * wb.z + yv.z * wc.z + yv.w * wd.z + b4.z);
      float o3 = gelu_exact(yv.x * wa.w + yv.y * wb.w + yv.z * wc.w + yv.w * wd.w + b4.w);
      Half4 p;
      p.a = __floats2half2_rn(o0, o1);
      p.b = __floats2half2_rn(o2, o3);
      *(Half4*)&Gt[r][c0] = p;
    }
  }
  __syncthreads();
  int wv = t >> 6, lane = t & 63;
  int m = lane & 15, quad = lane >> 4;
  {
    int cc = wv * 16;
    const __half* pa = WtP + (size_t)(cc + m) * 1024 + quad * 8;
    f32x4 acc = {0.f, 0.f, 0.f, 0.f};
#pragma unroll 8
    for (int k = 0; k < 1024; k += 32) {
      f16x8 a = *(const f16x8*)(pa + k);
      f16x8 b = *(const f16x8*)&Gt[m][quad * 8 + k];
      acc = __builtin_amdgcn_mfma_f32_16x16x32_f16(a, b, acc, 0, 0, 0);
    }
    float4 bp = *(const float4*)&biasP[cc + quad * 4];
    float v0 = acc[0] + bp.x, v1 = acc[1] + bp.y, v2 = acc[2] + bp.z, v3 = acc[3] + bp.w;
    if constexpr (__is_same(OutT, __half)) {
      Half4 p;
      p.a = __floats2half2_rn(v0, v1);
      p.b = __floats2half2_rn(v2, v3);
      *(Half4*)&out[(size_t)(r0 + m) * 128 + cc + quad * 4] = p;
    } else {
      *(float4*)&out[(size_t)(r0 + m) * 128 + cc + quad * 4] = make_float4(v0, v1, v2, v3);
    }
  }
}

// ---------------- orchestration ----------------

extern "C" void kernel_launch(void* const* d_in, const int* in_sizes, int n_in,
                              void* d_out, int out_size, void* d_ws, size_t ws_size,
                              hipStream_t stream) {
  const float* x   = (const float*)d_in[0];
  const int*   ei  = (const int*)d_in[1];
  const float* w1  = (const float*)d_in[2];
  const float* as1 = (const float*)d_in[3];
  const float* ad1 = (const float*)d_in[4];
  const float* b1  = (const float*)d_in[5];
  const float* w2  = (const float*)d_in[6];
  const float* as2 = (const float*)d_in[7];
  const float* ad2 = (const float*)d_in[8];
  const float* b2  = (const float*)d_in[9];
  const float* w3  = (const float*)d_in[10];
  const float* as3 = (const float*)d_in[11];
  const float* ad3 = (const float*)d_in[12];
  const float* b3  = (const float*)d_in[13];
  const float* rw1 = (const float*)d_in[14];
  const float* rb1 = (const float*)d_in[15];
  const float* rw2 = (const float*)d_in[16];
  const float* rb2 = (const float*)d_in[17];
  const float* lw  = (const float*)d_in[18];
  const float* lb  = (const float*)d_in[19];

  int N = in_sizes[0] / 4;
  int E = in_sizes[1] / 2;
  int ET = E + N;
  (void)ws_size;

  char* wsb = (char*)d_ws;
  size_t off = 0;
  auto alloc = [&](size_t bytes) -> void* {
    void* p = wsb + off;
    off += (bytes + 255) & ~(size_t)255;
    return p;
  };
  __half* P16  = (__half*)alloc((size_t)N * 128 * 2);
  __half* Y16  = (__half*)alloc((size_t)8 * N * 128 * 2);
  float*  Y1   = (float*)alloc((size_t)8 * N * 4 * 4);
  __half* wt2  = (__half*)alloc((size_t)1024 * 128 * 2);
  __half* wt3  = (__half*)alloc((size_t)1024 * 128 * 2);
  __half* rwt1 = (__half*)alloc((size_t)128 * 1024 * 2);
  __half* rwt2 = (__half*)alloc((size_t)128 * 1024 * 2);
  __half* lwt  = (__half*)alloc((size_t)128 * 1024 * 2);
  float* ws1 = (float*)alloc(8 * 4 * 4);
  float* wd1 = (float*)alloc(8 * 4 * 4);
  float* ws2 = (float*)alloc(8 * 128 * 4);
  float* wd2 = (float*)alloc(8 * 128 * 4);
  float* ws3 = (float*)alloc(8 * 128 * 4);
  float* wd3 = (float*)alloc(8 * 128 * 4);
  float* ssrc   = (float*)alloc((size_t)N * 8 * 4);
  float* sdst   = (float*)alloc((size_t)N * 8 * 4);
  int* counts  = (int*)alloc((size_t)N * 4);
  int* offsets = (int*)alloc((size_t)(N + 1) * 4);
  int* cursor  = (int*)alloc((size_t)N * 4);
  int* srcs    = (int*)alloc((size_t)ET * 4);

  dim3 blk(THREADS);
  dim3 blk512(512);

  hipMemsetAsync(counts, 0, (size_t)N * 4, stream);
  hist_kernel<<<dim3((ET + THREADS - 1) / THREADS), blk, 0, stream>>>(ei, E, ET, counts);
  wconv_all_kernel<<<dim3(32, 32, 5), blk, 0, stream>>>(w2, w3, rw1, rw2, lw,
                                                        wt2, wt3, rwt1, rwt2, lwt);
  sconv_kernel<<<dim3(8, 3), blk, 0, stream>>>(w1, as1, ad1, w2, as2, ad2, w3, as3, ad3,
                                               ws1, wd1, ws2, wd2, ws3, wd3);
  scan_kernel<<<dim3(1), dim3(1024), 0, stream>>>(counts, offsets, cursor, N);
  scatter_kernel<<<dim3((ET + THREADS - 1) / THREADS), blk, 0, stream>>>(ei, E, ET, cursor, srcs);

  dim3 gNode4(N / 4);
  dim3 gRow16(N / 16);

  // ---- layer 1 ----
  scoresX_kernel<<<dim3((N * 8 + THREADS - 1) / THREADS), blk, 0, stream>>>(
      x, ws1, wd1, ssrc, sdst, N * 8);
  attnagg_x<<<gNode4, blk, 0, stream>>>(x, srcs, offsets, ssrc, sdst, Y1, N);
  tail1_kernel<__half><<<gRow16, blk512, 0, stream>>>(Y1, w1, b1, rwt1, rb1, P16, N);

  // ---- layer 2 ----
  scoresP_kernel<<<gNode4, blk, 0, stream>>>(P16, ws2, wd2, ssrc, sdst);
  attnagg_p<<<gNode4, blk, 0, stream>>>(P16, srcs, offsets, ssrc, sdst, Y16, N);
  tail_mfma<__half><<<gRow16, blk512, 0, stream>>>(Y16, wt2, b2, rwt2, rb2, P16, N);

  // ---- layer 3 ----
  scoresP_kernel<<<gNode4, blk, 0, stream>>>(P16, ws3, wd3, ssrc, sdst);
  attnagg_p<<<gNode4, blk, 0, stream>>>(P16, srcs, offsets, ssrc, sdst, Y16, N);
  tail_mfma<float><<<gRow16, blk512, 0, stream>>>(Y16, wt3, b3, lwt, lb, (float*)d_out, N);
}